// Round 6
// baseline (427.466 us; speedup 1.0000x reference)
//
#include <hip/hip_runtime.h>
#include <hip/hip_bf16.h>
#include <math.h>

// Problem constants
#define Bd 32
#define Sd 32
#define Ld 64
#define Ed 128
#define Hd 128
#define MW 65536   // B*S*L tokens
#define MS 1024    // B*S sentences

// ws layout (float offsets)
#define OFF_WIHT_S   0          // [k=256][g=768] sentence input-proj weights (fp32)
#define OFF_WFW_W    196608     // 131072 u16: word attn Ww B-frags hi/lo
#define OFF_WFW_S    262144     // 131072 u16: sent attn Ws B-frags hi/lo
#define OFF_W6       327680     // 6 sets x float4[k4=32][g=384] (sets 4,5 used: sentence GRU)
#define OFF_BIH_W    622592     // (unused, kept)
#define OFF_BIH_S    623360
#define OFF_BHH_W    624128     // (unused, kept)
#define OFF_BHH_S    624896
#define OFF_WFX      625664     // 196608 u16: word xp w_ih B-frags [dir][half][nt24][q4][l][e]
#define OFF_HW       723968     // 1024 sents x [t64][hilo2][k256] u16 = 33.5M u16
#define OFF_SENTS    17763328   // 1024 x 256
#define OFF_XP_S     18025472   // 1024 x 768
#define OFF_HS       18811904   // 1024 x 256
#define OFF_DOC      19078144   // 32 x 256
#define OFF_WFHH     19086336   // 196608 u16: W_hh MFMA B-frags hi/lo
#define WS_FLOATS    19184640   // 76.7 MB

typedef __attribute__((ext_vector_type(8))) short sh8;
typedef __attribute__((ext_vector_type(4))) float f32x4;
typedef unsigned short u16;
typedef unsigned int u32;

#define GLD  384   // G stride: 4 rows (seqs, hi+lo pre-summed); writes 32-bank clean
#define XPLD 384   // xp_lds stride: write conflicts are 2-way (free, m136); reads clean
#define HPLD 520   // h_pk per-q stride in u16 (q-pad spreads banks)

// Raw workgroup barrier: waits LDS/shfl (lgkmcnt) only, deliberately NOT vmcnt
// (hout stores are never read back in-kernel). Perf-neutral vs __syncthreads
// (round-18 A/B) but keeps fewer drain instructions.
__device__ __forceinline__ void barrier_lds_only() {
    asm volatile("s_waitcnt lgkmcnt(0)\n\ts_barrier" ::: "memory");
}

__device__ __forceinline__ float sigmoidf_(float x) {
    return __fdividef(1.0f, 1.0f + __expf(-x));
}
__device__ __forceinline__ float tanhf_(float x) {
    float t = __expf(-2.0f * fabsf(x));
    float r = __fdividef(1.0f - t, 1.0f + t);
    return copysignf(r, x);
}
__device__ __forceinline__ u16 bf16_hi(float f) {
    u32 x = __float_as_uint(f);
    return (u16)((x + 0x7fffu + ((x >> 16) & 1u)) >> 16);
}
__device__ __forceinline__ float bf16_f(u16 u) { return __uint_as_float(((u32)u) << 16); }
__device__ __forceinline__ void bf16_split(float f, u16& hi, u16& lo) {
    hi = bf16_hi(f);
    lo = bf16_hi(f - bf16_f(hi));
}

// ---------------- weight prep ----------------
__global__ void prep(const float* __restrict__ s_ih_f, const float* __restrict__ s_ih_b,
                     const float* __restrict__ w_ih_f, const float* __restrict__ w_ih_b,
                     const float* __restrict__ w_hh_f, const float* __restrict__ w_hh_b,
                     const float* __restrict__ s_hh_f, const float* __restrict__ s_hh_b,
                     const float* __restrict__ b_ih_f, const float* __restrict__ b_ih_b,
                     const float* __restrict__ sb_ih_f, const float* __restrict__ sb_ih_b,
                     const float* __restrict__ b_hh_f, const float* __restrict__ b_hh_b,
                     const float* __restrict__ sb_hh_f, const float* __restrict__ sb_hh_b,
                     float* __restrict__ ws)
{
    int i = blockIdx.x * 256 + threadIdx.x;
    if (i < 196608) {  // WIHT_S [k=256][768]
        int k = i / 768, g = i % 768;
        ws[OFF_WIHT_S + i] = (g < 384) ? s_ih_f[g*256 + k] : s_ih_b[(g-384)*256 + k];
        return;
    }
    i -= 196608;
    if (i < 131072) return;   // frag buffers written by prep3
    i -= 131072;
    if (i < 294912) {  // W6 (sets 4,5 used by sentence GRU)
        int set = i / 49152, rem = i % 49152;
        int k4 = rem / 1536, r2 = rem % 1536, g = r2 >> 2, sub = r2 & 3;
        const float* w = (set==0) ? w_ih_f : (set==1) ? w_ih_b : (set==2) ? w_hh_f
                       : (set==3) ? w_hh_b : (set==4) ? s_hh_f : s_hh_b;
        ws[OFF_W6 + i] = w[g*128 + k4*4 + sub];
        return;
    }
    i -= 294912;
    if (i < 768) { ws[OFF_BIH_W + i] = (i<384) ? b_ih_f[i] : b_ih_b[i-384]; return; }
    i -= 768;
    if (i < 768) { ws[OFF_BIH_S + i] = (i<384) ? sb_ih_f[i] : sb_ih_b[i-384]; return; }
    i -= 768;
    if (i < 768) { ws[OFF_BHH_W + i] = (i<384) ? b_hh_f[i] : b_hh_b[i-384]; return; }
    i -= 768;
    if (i < 768) { ws[OFF_BHH_S + i] = (i<384) ? sb_hh_f[i] : sb_hh_b[i-384]; return; }
}

// ---------------- prep2: W_hh into MFMA B-frag order, bf16 hi/lo ----------------
// layout: [dir2][half2][nt24][q4][lane64][elem8] ushort
__global__ void prep2(const float* __restrict__ w_hh_f, const float* __restrict__ w_hh_b,
                      u16* __restrict__ WFo)
{
    int i = blockIdx.x * 256 + threadIdx.x;   // < 196608
    int within = i % 49152;
    int combo  = i / 49152;      // dir*2 + half
    int half = combo & 1, dir = combo >> 1;
    int nt  = within / 2048;
    int r2  = within % 2048;
    int q   = r2 >> 9;
    int r3  = r2 & 511;
    int l   = r3 >> 3, e = r3 & 7;
    int n = nt*16 + (l & 15);
    int k = q*32 + ((l >> 4) << 3) + e;
    const float* src = dir ? w_hh_b : w_hh_f;
    float v = src[n*128 + k];
    u16 hi = bf16_hi(v);
    WFo[i] = half ? bf16_hi(v - bf16_f(hi)) : hi;
}

// ---------------- prep3: attn (Ww,Ws) and xp (w_ih) weights into B-frag hi/lo ---------
// WFW_*: [half2][nt16][q8][l64][e8]; WFX: [dir2][half2][nt24][q4][l64][e8]
__global__ void prep3(const float* __restrict__ Ww, const float* __restrict__ Ws,
                      const float* __restrict__ w_ih_f, const float* __restrict__ w_ih_b,
                      u16* __restrict__ WFW_W, u16* __restrict__ WFW_S,
                      u16* __restrict__ WFX)
{
    int i = blockIdx.x * 256 + threadIdx.x;   // < 458752
    if (i < 262144) {
        int which = i / 131072;       // 0=Ww, 1=Ws
        int w = i % 131072;
        int half = w / 65536;
        int r = w % 65536;
        int nt = r / 4096;
        int r2 = r % 4096;
        int q = r2 / 512;
        int l = (r2 % 512) >> 3, e = r2 & 7;
        int n = nt*16 + (l & 15);
        int k = q*32 + ((l >> 4) << 3) + e;
        const float* src = which ? Ws : Ww;
        float v = src[n*256 + k];
        u16 hi = bf16_hi(v);
        u16 o = half ? bf16_hi(v - bf16_f(hi)) : hi;
        (which ? WFW_S : WFW_W)[w] = o;
        return;
    }
    i -= 262144;
    if (i < 196608) {
        int w = i % 98304;
        int dir = i / 98304;
        int half = w / 49152;
        int r = w % 49152;
        int nt = r / 2048;
        int r2 = r % 2048;
        int q = r2 / 512;
        int l = (r2 % 512) >> 3, e = r2 & 7;
        int n = nt*16 + (l & 15);
        int k = q*32 + ((l >> 4) << 3) + e;
        const float* src = dir ? w_ih_b : w_ih_f;
        float v = src[n*128 + k];
        u16 hi = bf16_hi(v);
        WFX[i] = half ? bf16_hi(v - bf16_f(hi)) : hi;
        return;
    }
}

// ---- staging helper: one (token, k-pair) item of embedding gather -> a_pk half ----
// idx in [0,1024): [1:0]=cc [4:2]=rm [6:5]=subk [8:7]=q [9]=ml (local seq in half)
__device__ __forceinline__ void stage_emb2(int idx, int half, int c, int dir,
                                           const float* __restrict__ emb,
                                           const int (*ids_s)[64],
                                           u16* __restrict__ a_pk)
{
    int cc = idx & 3, rm = (idx >> 2) & 7, subk = (idx >> 5) & 3;
    int q = (idx >> 7) & 3, ml = (idx >> 9) & 1;
    int mfs = half*2 + ml;
    int ts = c*8 + rm;
    int t = dir ? 63 - ts : ts;
    int kk = q*32 + subk*8 + cc*2;
    int id = ids_s[mfs][t];
    float2 v = make_float2(0.f, 0.f);
    if (id != 0) v = *(const float2*)&emb[(long)id*128 + kk];
    u16 h0,l0,h1,l1; bf16_split(v.x,h0,l0); bf16_split(v.y,h1,l1);
    int lh = subk*16 + rm;
    *(u32*)&a_pk[(ml*4 + q)*512 + lh*8 + cc*2]       = (u32)h0 | ((u32)h1 << 16);
    *(u32*)&a_pk[(ml*4 + q)*512 + (lh+8)*8 + cc*2]   = (u32)l0 | ((u32)l1 << 16);
}

// ---------------- fused word pipeline: gather + xp-GEMM (LDS) + recurrence ----------
// ROUND-20: co-residency boundary test. r19 (4-seq, LDS 71.2KB) did NOT co-reside
// (occupancy 34.7%, dur = 2x130.5us sequential rounds) despite fitting on paper
// (142.3KB<=160KB LDS, 68 VGPR, 1536 thr). Known-good datapoint: 64KB-LDS kernels DO
// co-reside 2/CU (learn_hip m132). Boundary is in (64KB, 71.2KB] -> this round pins
// LDS at 62.5KB (< 64KB) via three standalone wins:
//  * summed-G: recurrence MFMA hi rows (lanes 0-15) and lo rows (lanes 16-31) for the
//    same seq sit in the SAME reg of paired lanes -> shfl_xor(16) sums them BEFORE the
//    G write. G: 8x388 -> 4x384 floats (12.4->6.1KB); gate phase reads 3 G values
//    instead of 6; G write = 4 conflict-free ds_writes.
//  * half-staging: stage seqs{0,1} -> xp mf0,1 -> stage{2,3} -> xp mf2,3. a_pk halves
//    to 8KB (union w/ G). +2 barriers/chunk.
//  * pad trims XPLD/GLD->384 (write conflicts become 2-way = free, m136).
// LDS: xp 49152 + union 8192 + h_pk 4160 + ids 1024 = 62528 B.
// Decisive counter: OccupancyPercent >=60 -> co-residency (expect dur ~130-160);
// ~35 -> hypothesis dead, next round banks these wins into 8-seq geometry.
__global__ __launch_bounds__(768)
void gru_word_full(const int* __restrict__ X, const float* __restrict__ emb,
                   const u16* __restrict__ WFX, const u16* __restrict__ WFHH,
                   const float* __restrict__ b_ih_f, const float* __restrict__ b_ih_b,
                   const float* __restrict__ b_hh_f, const float* __restrict__ b_hh_b,
                   u16* __restrict__ houtp)
{
    const int bx = blockIdx.x;
    const int dir = bx >> 8;             // 512 blocks: 256 per dir
    const int blk = bx & 255;
    const int seq0 = blk * 4;
    const int tid = threadIdx.x;
    const int lane = tid & 63;
    const int wid = tid >> 6;            // 0..11

    __shared__ float xp_lds[32 * XPLD];      // 49152 B (rows = s*8 + tt, s<4)
    __shared__ f32x4 uni4[512];              // 8192 B union: a_pk half (8KB) / G (6.1KB)
    __shared__ u16 h_pk[4 * HPLD];           // 4160 B (hi rows 0-3, lo rows 4-7)
    __shared__ int ids_s[4][64];             // 1024 B
    float* G = (float*)uni4;                 // [4 seqs][GLD] (hi+lo pre-summed)
    u16* a_pk = (u16*)uni4;                  // [2 ml][4 q][512] u16

    const int j = tid & 127;
    const int sg = tid >> 7;             // 0..3 gate threads: s = sg (one seq each)
    const bool gthread = tid < 512;
    const float* bih = dir ? b_ih_b : b_ih_f;
    const float* bhh = dir ? b_hh_b : b_hh_f;
    float bhr = 0.f, bhz = 0.f, bhn = 0.f;
    if (gthread) { bhr = bhh[j]; bhz = bhh[128 + j]; bhn = bhh[256 + j]; }

    const u16* WXbase = WFX + (long)dir * 98304;
    const u16* WHbase = WFHH + (long)dir * 98304;
    const int nt0 = wid*2, nt1 = wid*2 + 1;
    const int c0 = nt0*16 + (lane & 15);
    const int c1 = nt1*16 + (lane & 15);
    // gate-thread h_pk write decomposition for k = j
    const int qj = j >> 5, subkj = (j >> 3) & 3, ej = j & 7;

    for (int i = tid; i < 256; i += 768)
        ids_s[i >> 6][i & 63] = X[(long)(seq0 + (i >> 6))*64 + (i & 63)];
    for (int i = tid; i < 4*HPLD; i += 768) h_pk[i] = 0;
    __syncthreads();

    float hprev0 = 0.f;
    for (int c = 0; c < 8; ++c) {
        asm volatile("" ::: "memory");   // no cross-chunk hoisting of weight loads
        // ---- load W_ih frags (this chunk only) ----
        sh8 xh0[4], xl0[4], xh1[4], xl1[4];
#pragma unroll
        for (int q = 0; q < 4; ++q) {
            xh0[q] = *(const sh8*)(WXbase + (nt0*4 + q)*512 + lane*8);
            xl0[q] = *(const sh8*)(WXbase + 49152 + (nt0*4 + q)*512 + lane*8);
            xh1[q] = *(const sh8*)(WXbase + (nt1*4 + q)*512 + lane*8);
            xl1[q] = *(const sh8*)(WXbase + 49152 + (nt1*4 + q)*512 + lane*8);
        }
        const float bv0 = bih[c0], bv1 = bih[c1];
        // ---- two half-chunks: stage 2 seqs -> xp MFMA for those 2 seqs ----
#pragma unroll
        for (int half = 0; half < 2; ++half) {
            for (int idx = tid; idx < 1024; idx += 768)
                stage_emb2(idx, half, c, dir, emb, ids_s, a_pk);
            barrier_lds_only();
#pragma unroll
            for (int ml = 0; ml < 2; ++ml) {
                const int mf = half*2 + ml;
                f32x4 A0 = (f32x4){0.f,0.f,0.f,0.f};
                f32x4 A1 = (f32x4){0.f,0.f,0.f,0.f};
#pragma unroll
                for (int q = 0; q < 4; ++q) {
                    sh8 a = *(const sh8*)&a_pk[(ml*4 + q)*512 + lane*8];
                    A0 = __builtin_amdgcn_mfma_f32_16x16x32_bf16(a, xh0[q], A0, 0,0,0);
                    A0 = __builtin_amdgcn_mfma_f32_16x16x32_bf16(a, xl0[q], A0, 0,0,0);
                    A1 = __builtin_amdgcn_mfma_f32_16x16x32_bf16(a, xh1[q], A1, 0,0,0);
                    A1 = __builtin_amdgcn_mfma_f32_16x16x32_bf16(a, xl1[q], A1, 0,0,0);
                }
                float g0[4], g1[4];
#pragma unroll
                for (int r = 0; r < 4; ++r) {
                    g0[r] = A0[r] + __shfl_xor(A0[r], 32);
                    g1[r] = A1[r] + __shfl_xor(A1[r], 32);
                }
                if ((lane >= 32) == (mf & 1)) {
                    int row = mf*8 + ((lane >> 4) & 1)*4;
#pragma unroll
                    for (int r = 0; r < 4; ++r) {
                        xp_lds[(row+r)*XPLD + c0] = g0[r] + bv0;
                        xp_lds[(row+r)*XPLD + c1] = g1[r] + bv1;
                    }
                }
            }
            barrier_lds_only();   // xp half done; a_pk free (next half or -> G)
        }
        asm volatile("" ::: "memory");
        // ---- load W_hh frags ----
        sh8 wh0[4], wl0[4], wh1[4], wl1[4];
#pragma unroll
        for (int q = 0; q < 4; ++q) {
            wh0[q] = *(const sh8*)(WHbase + (nt0*4 + q)*512 + lane*8);
            wl0[q] = *(const sh8*)(WHbase + 49152 + (nt0*4 + q)*512 + lane*8);
            wh1[q] = *(const sh8*)(WHbase + (nt1*4 + q)*512 + lane*8);
            wl1[q] = *(const sh8*)(WHbase + 49152 + (nt1*4 + q)*512 + lane*8);
        }
        // ---- 8 recurrence steps ----
        for (int tt = 0; tt < 8; ++tt) {
            const int ts = c*8 + tt;
            const int t = dir ? 63 - ts : ts;
            f32x4 acc0 = (f32x4){0.f,0.f,0.f,0.f};
            f32x4 acc1 = (f32x4){0.f,0.f,0.f,0.f};
#pragma unroll
            for (int q = 0; q < 4; ++q) {
                sh8 hp = *(const sh8*)&h_pk[q*HPLD + lane*8];
                acc0 = __builtin_amdgcn_mfma_f32_16x16x32_bf16(hp, wh0[q], acc0, 0,0,0);
                acc0 = __builtin_amdgcn_mfma_f32_16x16x32_bf16(hp, wl0[q], acc0, 0,0,0);
                acc1 = __builtin_amdgcn_mfma_f32_16x16x32_bf16(hp, wh1[q], acc1, 0,0,0);
                acc1 = __builtin_amdgcn_mfma_f32_16x16x32_bf16(hp, wl1[q], acc1, 0,0,0);
            }
            // summed-G: hi (lanes 0-15) + lo (lanes 16-31) of the same seq share a reg
            {
                float sg0[4], sg1[4];
#pragma unroll
                for (int r = 0; r < 4; ++r) {
                    sg0[r] = acc0[r] + __shfl_xor(acc0[r], 16);
                    sg1[r] = acc1[r] + __shfl_xor(acc1[r], 16);
                }
                if (lane < 32) {
                    const int col = ((lane & 16) ? nt1 : nt0)*16 + (lane & 15);
#pragma unroll
                    for (int r = 0; r < 4; ++r)
                        G[r*GLD + col] = (lane & 16) ? sg1[r] : sg0[r];
                }
            }
            barrier_lds_only();
            if (gthread) {
                const int s = sg;                        // one seq per gate thread
                float gr  = G[s*GLD + j]       + bhr;
                float gz  = G[s*GLD + 128 + j] + bhz;
                float gnh = G[s*GLD + 256 + j] + bhn;
                const float* xrow = &xp_lds[(s*8 + tt)*XPLD];
                float r  = sigmoidf_(xrow[j] + gr);
                float z  = sigmoidf_(xrow[128 + j] + gz);
                float nv = tanhf_(xrow[256 + j] + r * gnh);
                float hnew = (1.f - z) * nv + z * hprev0;
                hprev0 = hnew;
                u16 hh, hl; bf16_split(hnew, hh, hl);
                // paired u32 writes: even j handles the hi row pair, odd j the lo
                u16 ohh = (u16)__shfl_xor((int)hh, 1);
                u16 ohl = (u16)__shfl_xor((int)hl, 1);
                const long tbase = ((long)(seq0 + s)*64 + t)*512 + dir*128;
                if ((j & 1) == 0) {
                    u32 w = (u32)hh | ((u32)ohh << 16);
                    *(u32*)&h_pk[qj*HPLD + (subkj*16 + s)*8 + ej] = w;
                    *(u32*)&houtp[tbase + j] = w;
                } else {
                    u32 w = (u32)ohl | ((u32)hl << 16);
                    *(u32*)&h_pk[qj*HPLD + (subkj*16 + s + 4)*8 + (ej - 1)] = w;
                    *(u32*)&houtp[tbase + 256 + (j - 1)] = w;
                }
            }
            barrier_lds_only();
        }
    }
}

// ---------------- fused attention: score MFMA + tanh/ctx + softmax + pool ----------
// PACKED=true: A = hout u16 [sent][t][hilo][k256]; staged via decode-permute copy.
// PACKED=false: A is fp32 [M][256], staged with bf16 split (sentence level).
template<int T, bool PACKED>
__global__ __launch_bounds__(1024)
void attn_fused(const float* __restrict__ A, const u16* __restrict__ WF,
                const float* __restrict__ bias, const float* __restrict__ ctx,
                float* __restrict__ outp)
{
    __shared__ u16 a_pk[8][8][512];    // 64 KB
    __shared__ float pscore[8][8][17];
    __shared__ float aw[64];
    __shared__ float red[4][256];
    const int tid = threadIdx.x;
    const int lane = tid & 63;
    const int wid = tid >> 6;   // 0..15
    const int m0 = blockIdx.x * 64;

    sh8 bh[8], bl[8];
#pragma unroll
    for (int q = 0; q < 8; ++q) {
        bh[q] = *(const sh8*)(WF + (wid*8 + q)*512 + lane*8);
        bl[q] = *(const sh8*)(WF + 65536 + (wid*8 + q)*512 + lane*8);
    }
    const int colg = wid*16 + (lane & 15);
    const float bwv = bias[colg];
    const float cxv = ctx[colg];

    if (PACKED) {
        const u32* src32 = (const u32*)A + (long)blockIdx.x * 16384;
        u32* dst = (u32*)a_pk;
        for (int idx = tid; idx < 16384; idx += 1024) {
            int mf = idx >> 11, q = (idx >> 8) & 7, l = (idx >> 2) & 63, c2 = idx & 3;
            int row16 = l & 15, hilo = row16 >> 3, rm = row16 & 7;
            int t = mf*8 + rm;
            int k = q*32 + (l >> 4)*8 + c2*2;
            dst[idx] = src32[(t*2 + hilo)*128 + (k >> 1)];
        }
    } else {
        for (int idx = tid; idx < 8192; idx += 1024) {
            int row = idx >> 7;            // 0..63
            int k   = (idx & 127) << 1;
            float2 v = *(const float2*)&A[(long)(m0 + row)*256 + k];
            u16 h0,l0,h1,l1; bf16_split(v.x,h0,l0); bf16_split(v.y,h1,l1);
            int mf = row >> 3, rm = row & 7;
            int q = k >> 5;
            int lh = (((k & 31) >> 3) << 4) | rm;
            int e = k & 7;
            *(u32*)&a_pk[mf][q][lh*8 + e]     = (u32)h0 | ((u32)h1 << 16);
            *(u32*)&a_pk[mf][q][(lh+8)*8 + e] = (u32)l0 | ((u32)l1 << 16);
        }
    }
    __syncthreads();

#pragma unroll
    for (int mf = 0; mf < 8; ++mf) {
        f32x4 acc = (f32x4){0.f,0.f,0.f,0.f};
#pragma unroll
        for (int q = 0; q < 8; ++q) {
            sh8 a = *(const sh8*)&a_pk[mf][q][lane*8];
            acc = __builtin_amdgcn_mfma_f32_16x16x32_bf16(a, bh[q], acc, 0,0,0);
            acc = __builtin_amdgcn_mfma_f32_16x16x32_bf16(a, bl[q], acc, 0,0,0);
        }
        float g[4];
#pragma unroll
        for (int r = 0; r < 4; ++r) g[r] = acc[r] + __shfl_xor(acc[r], 32);
        if ((lane >= 32) == (mf & 1)) {    // half-dedup: each half handles 4 mf
            float p[4];
#pragma unroll
            for (int r = 0; r < 4; ++r) p[r] = tanhf_(g[r] + bwv) * cxv;
#pragma unroll
            for (int r = 0; r < 4; ++r) {
                p[r] += __shfl_xor(p[r], 1);
                p[r] += __shfl_xor(p[r], 2);
                p[r] += __shfl_xor(p[r], 4);
                p[r] += __shfl_xor(p[r], 8);
            }
            if ((lane & 15) == 0) {
#pragma unroll
                for (int r = 0; r < 4; ++r)
                    pscore[mf][((lane >> 4) & 1)*4 + r][wid] = p[r];
            }
        }
    }
    __syncthreads();

    // softmax over T (per sentence group) in wave 0
    if (tid < 64) {
        float sc = 0.f;
#pragma unroll
        for (int w = 0; w < 16; ++w) sc += pscore[tid >> 3][tid & 7][w];
        float mx = sc;
#pragma unroll
        for (int m = 1; m < T; m <<= 1) mx = fmaxf(mx, __shfl_xor(mx, m));
        float e = __expf(sc - mx);
        float den = e;
#pragma unroll
        for (int m = 1; m < T; m <<= 1) den += __shfl_xor(den, m);
        aw[tid] = __fdividef(e, den);
    }
    __syncthreads();

    // weighted sum: h reconstructed from a_pk (hi+lo); thread -> (d-pair, t-group)
    if (tid < 512) {
        const int dp = (tid & 127) << 1;
        const int tg = tid >> 7;          // 0..3
        const int q = dp >> 5, lhb = ((dp & 31) >> 3) << 4, e = dp & 7;
        float acc0 = 0.f, acc1 = 0.f;
#pragma unroll
        for (int i = 0; i < 16; ++i) {
            int t = tg*16 + i;
            int mf = t >> 3, rm = t & 7;
            const u16* base = &a_pk[mf][q][(lhb | rm)*8 + e];
            u32 hh = *(const u32*)base;
            u32 ll = *(const u32*)(base + 64);
            float h0 = bf16_f((u16)hh) + bf16_f((u16)ll);
            float h1 = bf16_f((u16)(hh >> 16)) + bf16_f((u16)(ll >> 16));
            float w = aw[t];
            acc0 = fmaf(w, h0, acc0);
            acc1 = fmaf(w, h1, acc1);
        }
        red[tg][dp] = acc0; red[tg][dp + 1] = acc1;
    }
    __syncthreads();
    if (T == 64) {
        if (tid < 256)
            outp[(long)blockIdx.x*256 + tid] = red[0][tid] + red[1][tid] + red[2][tid] + red[3][tid];
    } else {
        if (tid < 512) {
            int sent = tid >> 8, dd = tid & 255;
            outp[((long)blockIdx.x*2 + sent)*256 + dd] = red[sent*2][dd] + red[sent*2 + 1][dd];
        }
    }
}

// ---------------- tiled GEMM (+bias) for sentence xp ----------------
__global__ __launch_bounds__(256)
void gemm_xp(const float* __restrict__ A,
             const float* __restrict__ WT, const float* __restrict__ bias,
             float* __restrict__ out, int N, int K)
{
    __shared__ float As[64*128];
    __shared__ float Bs[128*64];
    const int tid = threadIdx.x;
    const int m0 = blockIdx.x * 64;
    const int n0 = blockIdx.y * 64;
    const int tx = tid & 15, ty = tid >> 4;
    float acc[4][4];
#pragma unroll
    for (int i=0;i<4;i++)
#pragma unroll
        for (int c=0;c<4;c++) acc[i][c]=0.f;

    for (int kc = 0; kc < K; kc += 128) {
        if (kc) __syncthreads();
#pragma unroll
        for (int it = 0; it < 8; ++it) {
            int idx = tid + it*256;
            int r = idx >> 5, c4 = idx & 31;
            float4 v = *(const float4*)&A[(long)(m0 + r)*K + kc + (c4<<2)];
            *(float4*)&As[r*128 + ((c4 ^ (r & 7)) << 2)] = v;
        }
#pragma unroll
        for (int it = 0; it < 8; ++it) {
            int idx = tid + it*256;
            int k = idx >> 4, c4 = idx & 15;
            float4 v = *(const float4*)&WT[(long)(kc + k)*N + n0 + (c4<<2)];
            *(float4*)&Bs[k*64 + ((c4 ^ (k & 7)) << 2)] = v;
        }
        __syncthreads();
        const int swzA = (ty & 7) << 2;
#pragma unroll 4
        for (int k = 0; k < 128; ++k) {
            float4 b = *(const float4*)&Bs[k*64 + ((tx ^ (k & 7)) << 2)];
            int kx = k ^ swzA;
#pragma unroll
            for (int i=0;i<4;i++) {
                float a = As[(ty + 16*i)*128 + kx];
                acc[i][0] = fmaf(a, b.x, acc[i][0]);
                acc[i][1] = fmaf(a, b.y, acc[i][1]);
                acc[i][2] = fmaf(a, b.z, acc[i][2]);
                acc[i][3] = fmaf(a, b.w, acc[i][3]);
            }
        }
    }
    float4 bia = *(const float4*)&bias[n0 + (tx<<2)];
#pragma unroll
    for (int i=0;i<4;i++) {
        float4 res = make_float4(acc[i][0]+bia.x, acc[i][1]+bia.y, acc[i][2]+bia.z, acc[i][3]+bia.w);
        *(float4*)&out[(long)(m0 + ty + 16*i)*N + n0 + (tx<<2)] = res;
    }
}

// ---------------- sentence GRU (streamed weights; small) ----------------
template<int NSEQ, int T>
__global__ __launch_bounds__(512)
void gru_fused(const float* __restrict__ xp, const float4* __restrict__ whh4,
               const float* __restrict__ bhh, float* __restrict__ hout,
               int blocks_per_dir)
{
    const int bx = blockIdx.x;
    const int dir = bx / blocks_per_dir;
    const int blk = bx % blocks_per_dir;
    const int seq0 = blk * NSEQ;
    const int tid = threadIdx.x;
    const int kq = tid & 3;
    const int j  = tid >> 2;
    const float4* W = whh4 + (long)dir * 12288;
    __shared__ float h_lds[NSEQ][128];
    for (int idx = tid; idx < NSEQ*128; idx += 512) ((float*)h_lds)[idx] = 0.f;
    const float bhr = bhh[dir*384 + j];
    const float bhz = bhh[dir*384 + 128 + j];
    const float bhn = bhh[dir*384 + 256 + j];
    __syncthreads();

    for (int ts = 0; ts < T; ++ts) {
        const int t = dir ? (T - 1 - ts) : ts;
        float a0[NSEQ], a1[NSEQ], a2[NSEQ];
#pragma unroll
        for (int s=0;s<NSEQ;s++){a0[s]=0.f;a1[s]=0.f;a2[s]=0.f;}
#pragma unroll
        for (int ii = 0; ii < 8; ++ii) {
            const int k4 = kq + (ii << 2);
            float4 w0 = W[k4*384 + j];
            float4 w1 = W[k4*384 + 128 + j];
            float4 w2 = W[k4*384 + 256 + j];
#pragma unroll
            for (int s=0;s<NSEQ;s++) {
                float4 h4 = *(const float4*)&h_lds[s][k4 << 2];
                a0[s] = fmaf(w0.x,h4.x, fmaf(w0.y,h4.y, fmaf(w0.z,h4.z, fmaf(w0.w,h4.w, a0[s]))));
                a1[s] = fmaf(w1.x,h4.x, fmaf(w1.y,h4.y, fmaf(w1.z,h4.z, fmaf(w1.w,h4.w, a1[s]))));
                a2[s] = fmaf(w2.x,h4.x, fmaf(w2.y,h4.y, fmaf(w2.z,h4.z, fmaf(w2.w,h4.w, a2[s]))));
            }
        }
#pragma unroll
        for (int s=0;s<NSEQ;s++) {
            a0[s] += __shfl_xor(a0[s], 1); a0[s] += __shfl_xor(a0[s], 2);
            a1[s] += __shfl_xor(a1[s], 1); a1[s] += __shfl_xor(a1[s], 2);
            a2[s] += __shfl_xor(a2[s], 1); a2[s] += __shfl_xor(a2[s], 2);
        }
        __syncthreads();
        if (kq == 0) {
#pragma unroll
            for (int s=0;s<NSEQ;s++) {
                const float* xr = &xp[((long)(seq0+s)*T + t)*768 + dir*384];
                float r = sigmoidf_(xr[j]       + a0[s] + bhr);
                float z = sigmoidf_(xr[128 + j] + a1[s] + bhz);
                float nv = tanhf_(xr[256 + j] + r * (a2[s] + bhn));
                float hold = h_lds[s][j];
                float hnew = (1.f - z) * nv + z * hold;
                h_lds[s][j] = hnew;
                hout[((long)(seq0+s)*T + t)*256 + dir*128 + j] = hnew;
            }
        }
        __syncthreads();
    }
}

// ---------------- classifier ----------------
__global__ void classifier(const float* __restrict__ doc, const float* __restrict__ Wc,
                           const float* __restrict__ bc, float* __restrict__ out)
{
    int tid = threadIdx.x;
    if (tid < 320) {
        int b = tid / 10, c = tid % 10;
        float s = bc[c];
        for (int d = 0; d < 256; ++d) s = fmaf(doc[b*256 + d], Wc[c*256 + d], s);
        out[tid] = s;
    }
}

extern "C" void kernel_launch(void* const* d_in, const int* in_sizes, int n_in,
                              void* d_out, int out_size, void* d_ws, size_t ws_size,
                              hipStream_t stream) {
    const int*   X       = (const int*)  d_in[0];
    const float* emb     = (const float*)d_in[1];
    const float* w_ih_f  = (const float*)d_in[2];
    const float* w_hh_f  = (const float*)d_in[3];
    const float* b_ih_f  = (const float*)d_in[4];
    const float* b_hh_f  = (const float*)d_in[5];
    const float* w_ih_b  = (const float*)d_in[6];
    const float* w_hh_b  = (const float*)d_in[7];
    const float* b_ih_b  = (const float*)d_in[8];
    const float* b_hh_b  = (const float*)d_in[9];
    const float* Ww      = (const float*)d_in[10];
    const float* bw      = (const float*)d_in[11];
    const float* ctx_w   = (const float*)d_in[12];
    const float* s_ih_f  = (const float*)d_in[13];
    const float* s_hh_f  = (const float*)d_in[14];
    const float* sb_ih_f = (const float*)d_in[15];
    const float* sb_hh_f = (const float*)d_in[16];
    const float* s_ih_b  = (const float*)d_in[17];
    const float* s_hh_b  = (const float*)d_in[18];
    const float* sb_ih_b = (const float*)d_in[19];
    const float* sb_hh_b = (const float*)d_in[20];
    const float* Ws      = (const float*)d_in[21];
    const float* bs      = (const float*)d_in[22];
    const float* ctx_s   = (const float*)d_in[23];
    const float* Wc      = (const float*)d_in[24];
    const float* bc      = (const float*)d_in[25];
    float* ws  = (float*)d_ws;
    float* out = (float*)d_out;

    if (ws_size < (size_t)WS_FLOATS * 4) return;   // fail cleanly if scratch too small

    // 1. weight prep
    prep<<<2444, 256, 0, stream>>>(s_ih_f, s_ih_b, w_ih_f, w_ih_b,
                                   w_hh_f, w_hh_b, s_hh_f, s_hh_b,
                                   b_ih_f, b_ih_b, sb_ih_f, sb_ih_b,
                                   b_hh_f, b_hh_b, sb_hh_f, sb_hh_b, ws);
    prep2<<<768, 256, 0, stream>>>(w_hh_f, w_hh_b, (u16*)(ws + OFF_WFHH));
    prep3<<<1792, 256, 0, stream>>>(Ww, Ws, w_ih_f, w_ih_b,
                                    (u16*)(ws + OFF_WFW_W), (u16*)(ws + OFF_WFW_S),
                                    (u16*)(ws + OFF_WFX));

    // 2. fused word pipeline (round-20: 4 seqs/block, LDS 62.5KB <= 64KB co-res test)
    gru_word_full<<<512, 768, 0, stream>>>(
        X, emb, (const u16*)(ws + OFF_WFX), (const u16*)(ws + OFF_WFHH),
        b_ih_f, b_ih_b, b_hh_f, b_hh_b, (u16*)(ws + OFF_HW));

    // 3. fused word attention (decode-permute staging) -> sents
    attn_fused<64, true><<<1024, 1024, 0, stream>>>(
        ws + OFF_HW, (const u16*)(ws + OFF_WFW_W), bw, ctx_w, ws + OFF_SENTS);

    // 4. sentence xp
    gemm_xp<<<dim3(16, 12), 256, 0, stream>>>(
        ws + OFF_SENTS, ws + OFF_WIHT_S, ws + OFF_BIH_S, ws + OFF_XP_S, 768, 256);
    // 5. sentence GRU
    gru_fused<1, 32><<<64, 512, 0, stream>>>(
        ws + OFF_XP_S, (const float4*)(ws + OFF_W6) + 4*12288, ws + OFF_BHH_S, ws + OFF_HS, 32);
    // 6. fused sentence attention -> doc
    attn_fused<32, false><<<16, 1024, 0, stream>>>(
        ws + OFF_HS, (const u16*)(ws + OFF_WFW_S), bs, ctx_s, ws + OFF_DOC);
    // 7. classifier
    classifier<<<1, 320, 0, stream>>>(ws + OFF_DOC, Wc, bc, out);
}

// Round 7
// 351.265 us; speedup vs baseline: 1.2169x; 1.2169x over previous
//
#include <hip/hip_runtime.h>
#include <hip/hip_bf16.h>
#include <math.h>

// Problem constants
#define Bd 32
#define Sd 32
#define Ld 64
#define Ed 128
#define Hd 128
#define MW 65536   // B*S*L tokens
#define MS 1024    // B*S sentences

// ws layout (float offsets)
#define OFF_WIHT_S   0          // [k=256][g=768] sentence input-proj weights (fp32)
#define OFF_WFW_W    196608     // 131072 u16: word attn Ww B-frags hi/lo
#define OFF_WFW_S    262144     // 131072 u16: sent attn Ws B-frags hi/lo
#define OFF_W6       327680     // 6 sets x float4[k4=32][g=384] (sets 4,5 used: sentence GRU)
#define OFF_BIH_W    622592     // (unused, kept)
#define OFF_BIH_S    623360
#define OFF_BHH_W    624128     // (unused, kept)
#define OFF_BHH_S    624896
#define OFF_WFX      625664     // 196608 u16: word xp w_ih B-frags [dir][half][nt24][q4][l][e]
#define OFF_HW       723968     // 1024 sents x [t64][hilo2][k256] u16 = 33.5M u16
#define OFF_SENTS    17763328   // 1024 x 256
#define OFF_XP_S     18025472   // 1024 x 768
#define OFF_HS       18811904   // 1024 x 256
#define OFF_DOC      19078144   // 32 x 256
#define OFF_WFHH     19086336   // 196608 u16: W_hh MFMA B-frags hi/lo
#define WS_FLOATS    19184640   // 76.7 MB

typedef __attribute__((ext_vector_type(8))) short sh8;
typedef __attribute__((ext_vector_type(4))) float f32x4;
typedef unsigned short u16;
typedef unsigned int u32;

#define GLD  388   // G stride, 8 rows (seqs 0-7, hi+lo pre-summed)
#define XPLD 385   // xp_lds stride (mod 32 = 1 -> banks spread)
#define HPLD 520   // h_pk per-q stride in u16 (q-pad spreads banks)

// Raw workgroup barrier: waits LDS/shfl (lgkmcnt) only, deliberately NOT vmcnt
// (hout stores are never read back in-kernel). Perf-neutral vs __syncthreads
// (round-18 A/B) but keeps fewer drain instructions.
__device__ __forceinline__ void barrier_lds_only() {
    asm volatile("s_waitcnt lgkmcnt(0)\n\ts_barrier" ::: "memory");
}

__device__ __forceinline__ float sigmoidf_(float x) {
    return __fdividef(1.0f, 1.0f + __expf(-x));
}
__device__ __forceinline__ float tanhf_(float x) {
    float t = __expf(-2.0f * fabsf(x));
    float r = __fdividef(1.0f - t, 1.0f + t);
    return copysignf(r, x);
}
__device__ __forceinline__ u16 bf16_hi(float f) {
    u32 x = __float_as_uint(f);
    return (u16)((x + 0x7fffu + ((x >> 16) & 1u)) >> 16);
}
__device__ __forceinline__ float bf16_f(u16 u) { return __uint_as_float(((u32)u) << 16); }
__device__ __forceinline__ void bf16_split(float f, u16& hi, u16& lo) {
    hi = bf16_hi(f);
    lo = bf16_hi(f - bf16_f(hi));
}

// ---------------- weight prep ----------------
__global__ void prep(const float* __restrict__ s_ih_f, const float* __restrict__ s_ih_b,
                     const float* __restrict__ w_ih_f, const float* __restrict__ w_ih_b,
                     const float* __restrict__ w_hh_f, const float* __restrict__ w_hh_b,
                     const float* __restrict__ s_hh_f, const float* __restrict__ s_hh_b,
                     const float* __restrict__ b_ih_f, const float* __restrict__ b_ih_b,
                     const float* __restrict__ sb_ih_f, const float* __restrict__ sb_ih_b,
                     const float* __restrict__ b_hh_f, const float* __restrict__ b_hh_b,
                     const float* __restrict__ sb_hh_f, const float* __restrict__ sb_hh_b,
                     float* __restrict__ ws)
{
    int i = blockIdx.x * 256 + threadIdx.x;
    if (i < 196608) {  // WIHT_S [k=256][768]
        int k = i / 768, g = i % 768;
        ws[OFF_WIHT_S + i] = (g < 384) ? s_ih_f[g*256 + k] : s_ih_b[(g-384)*256 + k];
        return;
    }
    i -= 196608;
    if (i < 131072) return;   // frag buffers written by prep3
    i -= 131072;
    if (i < 294912) {  // W6 (sets 4,5 used by sentence GRU)
        int set = i / 49152, rem = i % 49152;
        int k4 = rem / 1536, r2 = rem % 1536, g = r2 >> 2, sub = r2 & 3;
        const float* w = (set==0) ? w_ih_f : (set==1) ? w_ih_b : (set==2) ? w_hh_f
                       : (set==3) ? w_hh_b : (set==4) ? s_hh_f : s_hh_b;
        ws[OFF_W6 + i] = w[g*128 + k4*4 + sub];
        return;
    }
    i -= 294912;
    if (i < 768) { ws[OFF_BIH_W + i] = (i<384) ? b_ih_f[i] : b_ih_b[i-384]; return; }
    i -= 768;
    if (i < 768) { ws[OFF_BIH_S + i] = (i<384) ? sb_ih_f[i] : sb_ih_b[i-384]; return; }
    i -= 768;
    if (i < 768) { ws[OFF_BHH_W + i] = (i<384) ? b_hh_f[i] : b_hh_b[i-384]; return; }
    i -= 768;
    if (i < 768) { ws[OFF_BHH_S + i] = (i<384) ? sb_hh_f[i] : sb_hh_b[i-384]; return; }
}

// ---------------- prep2: W_hh into MFMA B-frag order, bf16 hi/lo ----------------
// layout: [dir2][half2][nt24][q4][lane64][elem8] ushort
__global__ void prep2(const float* __restrict__ w_hh_f, const float* __restrict__ w_hh_b,
                      u16* __restrict__ WFo)
{
    int i = blockIdx.x * 256 + threadIdx.x;   // < 196608
    int within = i % 49152;
    int combo  = i / 49152;      // dir*2 + half
    int half = combo & 1, dir = combo >> 1;
    int nt  = within / 2048;
    int r2  = within % 2048;
    int q   = r2 >> 9;
    int r3  = r2 & 511;
    int l   = r3 >> 3, e = r3 & 7;
    int n = nt*16 + (l & 15);
    int k = q*32 + ((l >> 4) << 3) + e;
    const float* src = dir ? w_hh_b : w_hh_f;
    float v = src[n*128 + k];
    u16 hi = bf16_hi(v);
    WFo[i] = half ? bf16_hi(v - bf16_f(hi)) : hi;
}

// ---------------- prep3: attn (Ww,Ws) and xp (w_ih) weights into B-frag hi/lo ---------
// WFW_*: [half2][nt16][q8][l64][e8]; WFX: [dir2][half2][nt24][q4][l64][e8]
__global__ void prep3(const float* __restrict__ Ww, const float* __restrict__ Ws,
                      const float* __restrict__ w_ih_f, const float* __restrict__ w_ih_b,
                      u16* __restrict__ WFW_W, u16* __restrict__ WFW_S,
                      u16* __restrict__ WFX)
{
    int i = blockIdx.x * 256 + threadIdx.x;   // < 458752
    if (i < 262144) {
        int which = i / 131072;       // 0=Ww, 1=Ws
        int w = i % 131072;
        int half = w / 65536;
        int r = w % 65536;
        int nt = r / 4096;
        int r2 = r % 4096;
        int q = r2 / 512;
        int l = (r2 % 512) >> 3, e = r2 & 7;
        int n = nt*16 + (l & 15);
        int k = q*32 + ((l >> 4) << 3) + e;
        const float* src = which ? Ws : Ww;
        float v = src[n*256 + k];
        u16 hi = bf16_hi(v);
        u16 o = half ? bf16_hi(v - bf16_f(hi)) : hi;
        (which ? WFW_S : WFW_W)[w] = o;
        return;
    }
    i -= 262144;
    if (i < 196608) {
        int w = i % 98304;
        int dir = i / 98304;
        int half = w / 49152;
        int r = w % 49152;
        int nt = r / 2048;
        int r2 = r % 2048;
        int q = r2 / 512;
        int l = (r2 % 512) >> 3, e = r2 & 7;
        int n = nt*16 + (l & 15);
        int k = q*32 + ((l >> 4) << 3) + e;
        const float* src = dir ? w_ih_b : w_ih_f;
        float v = src[n*128 + k];
        u16 hi = bf16_hi(v);
        WFX[i] = half ? bf16_hi(v - bf16_f(hi)) : hi;
        return;
    }
}

// ---------------- fused word pipeline: gather + xp-GEMM (LDS) + recurrence ----------
// ROUND-21: 8-seq round-18 base (195.8us verified) + the two wins proven harmless in
// r19/r20, dropped the loss-makers:
//  * summed-G (kept): recurrence hi rows (lanes 0-31) and lo rows (lanes 32-63) of the
//    same seq share a register -> shfl_xor(32) sums BEFORE the G write. G: 16->8 rows;
//    gate phase reads 3 G floats instead of 6 (saves 6 LDS reads + 6 adds per gthread
//    per step); G write traffic halves.
//  * float4 staging (new): 2048 items x 4 elems instead of 4096 x 2 - halves gather
//    loads, index decode, and LDS write instructions (paired u32 hi/lo words; 4-way
//    b64 write aliasing = hardware minimum for 512B/wave).
//  * half-staging DROPPED (r20: its 2 extra barriers/chunk cost more than it saved).
//  * 2-block co-residency DEAD (r19: 71KB, r20: 62.5KB both refused; not LDS-gated).
__global__ __launch_bounds__(768)
void gru_word_full(const int* __restrict__ X, const float* __restrict__ emb,
                   const u16* __restrict__ WFX, const u16* __restrict__ WFHH,
                   const float* __restrict__ b_ih_f, const float* __restrict__ b_ih_b,
                   const float* __restrict__ b_hh_f, const float* __restrict__ b_hh_b,
                   u16* __restrict__ houtp)
{
    const int bx = blockIdx.x;
    const int dir = bx >> 7;
    const int blk = bx & 127;
    const int seq0 = blk * 8;
    const int tid = threadIdx.x;
    const int lane = tid & 63;
    const int wid = tid >> 6;            // 0..11

    __shared__ float xp_lds[64 * XPLD];      // 98560 B (rows = s*8 + tt)
    __shared__ f32x4 uni4[2048];             // 32768 B union: a_pk (32 KB) / G (12.4 KB)
    __shared__ u16 h_pk[4 * HPLD];           // 4160 B (hi rows 0-7, lo rows 8-15)
    __shared__ int ids_s[8][64];             // 2048 B
    float* G = (float*)uni4;                 // [8][GLD] (hi+lo pre-summed)
    u16* a_pk = (u16*)uni4;                  // [8 mf][4 q][512] u16

    const int j = tid & 127;
    const int sg = tid >> 7;             // 0..3 gate threads (s = sg, sg+4)
    const bool gthread = tid < 512;
    const float* bih = dir ? b_ih_b : b_ih_f;
    const float* bhh = dir ? b_hh_b : b_hh_f;
    float bhr = 0.f, bhz = 0.f, bhn = 0.f;
    if (gthread) { bhr = bhh[j]; bhz = bhh[128 + j]; bhn = bhh[256 + j]; }

    const u16* WXbase = WFX + (long)dir * 98304;
    const u16* WHbase = WFHH + (long)dir * 98304;
    const int nt0 = wid*2, nt1 = wid*2 + 1;
    const int c0 = nt0*16 + (lane & 15);
    const int c1 = nt1*16 + (lane & 15);
    // gate-thread h_pk write decomposition for k = j
    const int qj = j >> 5, subkj = (j >> 3) & 3, ej = j & 7;

    for (int i = tid; i < 512; i += 768)
        ids_s[i >> 6][i & 63] = X[(long)(seq0 + (i >> 6))*64 + (i & 63)];
    for (int i = tid; i < 4*HPLD; i += 768) h_pk[i] = 0;
    __syncthreads();

    float hprev0 = 0.f, hprev1 = 0.f;
    for (int c = 0; c < 8; ++c) {
        asm volatile("" ::: "memory");   // no cross-chunk hoisting of weight loads
        // ---- load W_ih frags (this chunk only) ----
        sh8 xh0[4], xl0[4], xh1[4], xl1[4];
#pragma unroll
        for (int q = 0; q < 4; ++q) {
            xh0[q] = *(const sh8*)(WXbase + (nt0*4 + q)*512 + lane*8);
            xl0[q] = *(const sh8*)(WXbase + 49152 + (nt0*4 + q)*512 + lane*8);
            xh1[q] = *(const sh8*)(WXbase + (nt1*4 + q)*512 + lane*8);
            xl1[q] = *(const sh8*)(WXbase + 49152 + (nt1*4 + q)*512 + lane*8);
        }
        const float bv0 = bih[c0], bv1 = bih[c1];
        // ---- stage gathered embeddings: 2048 float4 items, paired hi/lo words ----
        // idx bits: [0]=cc2 [3:1]=rm(tt) [5:4]=subk [7:6]=q [10:8]=mfs(s)
        for (int idx = tid; idx < 2048; idx += 768) {
            int cc2 = idx & 1, rm = (idx >> 1) & 7, subk = (idx >> 4) & 3;
            int q = (idx >> 6) & 3, mfs = idx >> 8;
            int ts = c*8 + rm;
            int t = dir ? 63 - ts : ts;
            int kk = q*32 + subk*8 + cc2*4;
            int id = ids_s[mfs][t];
            float4 v = make_float4(0.f, 0.f, 0.f, 0.f);
            if (id != 0) v = *(const float4*)&emb[(long)id*128 + kk];
            u16 h0,l0,h1,l1,h2,l2,h3,l3;
            bf16_split(v.x,h0,l0); bf16_split(v.y,h1,l1);
            bf16_split(v.z,h2,l2); bf16_split(v.w,h3,l3);
            int lh = subk*16 + rm;
            int base = (mfs*4 + q)*512 + lh*8 + cc2*4;
            uint2 whi = make_uint2((u32)h0 | ((u32)h1 << 16), (u32)h2 | ((u32)h3 << 16));
            uint2 wlo = make_uint2((u32)l0 | ((u32)l1 << 16), (u32)l2 | ((u32)l3 << 16));
            *(uint2*)&a_pk[base]      = whi;
            *(uint2*)&a_pk[base + 64] = wlo;   // (lh+8)*8 - lh*8 = 64 u16
        }
        barrier_lds_only();
        // ---- xp MFMA: 8 m-frags -> xp_lds (+bias), half-dedup epilogue ----
#pragma unroll
        for (int mf = 0; mf < 8; ++mf) {
            f32x4 A0 = (f32x4){0.f,0.f,0.f,0.f};
            f32x4 A1 = (f32x4){0.f,0.f,0.f,0.f};
#pragma unroll
            for (int q = 0; q < 4; ++q) {
                sh8 a = *(const sh8*)&a_pk[(mf*4 + q)*512 + lane*8];
                A0 = __builtin_amdgcn_mfma_f32_16x16x32_bf16(a, xh0[q], A0, 0,0,0);
                A0 = __builtin_amdgcn_mfma_f32_16x16x32_bf16(a, xl0[q], A0, 0,0,0);
                A1 = __builtin_amdgcn_mfma_f32_16x16x32_bf16(a, xh1[q], A1, 0,0,0);
                A1 = __builtin_amdgcn_mfma_f32_16x16x32_bf16(a, xl1[q], A1, 0,0,0);
            }
            float g0[4], g1[4];
#pragma unroll
            for (int r = 0; r < 4; ++r) {
                g0[r] = A0[r] + __shfl_xor(A0[r], 32);
                g1[r] = A1[r] + __shfl_xor(A1[r], 32);
            }
            if ((lane >= 32) == (mf & 1)) {
                int row = mf*8 + ((lane >> 4) & 1)*4;
#pragma unroll
                for (int r = 0; r < 4; ++r) {
                    xp_lds[(row+r)*XPLD + c0] = g0[r] + bv0;
                    xp_lds[(row+r)*XPLD + c1] = g1[r] + bv1;
                }
            }
        }
        barrier_lds_only();   // xp ready; a_pk region free -> G
        asm volatile("" ::: "memory");
        // ---- load W_hh frags ----
        sh8 wh0[4], wl0[4], wh1[4], wl1[4];
#pragma unroll
        for (int q = 0; q < 4; ++q) {
            wh0[q] = *(const sh8*)(WHbase + (nt0*4 + q)*512 + lane*8);
            wl0[q] = *(const sh8*)(WHbase + 49152 + (nt0*4 + q)*512 + lane*8);
            wh1[q] = *(const sh8*)(WHbase + (nt1*4 + q)*512 + lane*8);
            wl1[q] = *(const sh8*)(WHbase + 49152 + (nt1*4 + q)*512 + lane*8);
        }
        // ---- 8 recurrence steps ----
        for (int tt = 0; tt < 8; ++tt) {
            const int ts = c*8 + tt;
            const int t = dir ? 63 - ts : ts;
            f32x4 acc0 = (f32x4){0.f,0.f,0.f,0.f};
            f32x4 acc1 = (f32x4){0.f,0.f,0.f,0.f};
#pragma unroll
            for (int q = 0; q < 4; ++q) {
                sh8 hp = *(const sh8*)&h_pk[q*HPLD + lane*8];
                acc0 = __builtin_amdgcn_mfma_f32_16x16x32_bf16(hp, wh0[q], acc0, 0,0,0);
                acc0 = __builtin_amdgcn_mfma_f32_16x16x32_bf16(hp, wl0[q], acc0, 0,0,0);
                acc1 = __builtin_amdgcn_mfma_f32_16x16x32_bf16(hp, wh1[q], acc1, 0,0,0);
                acc1 = __builtin_amdgcn_mfma_f32_16x16x32_bf16(hp, wl1[q], acc1, 0,0,0);
            }
            // summed-G: hi row s (lanes 0-31) + lo row s+8 (lanes 32-63) share a reg
            {
                float sg0[4], sg1[4];
#pragma unroll
                for (int r = 0; r < 4; ++r) {
                    sg0[r] = acc0[r] + __shfl_xor(acc0[r], 32);
                    sg1[r] = acc1[r] + __shfl_xor(acc1[r], 32);
                }
                if (lane < 32) {
                    const int col16 = lane & 15;
                    const int row0  = (lane >> 4) << 2;   // 0 or 4
#pragma unroll
                    for (int r = 0; r < 4; ++r) {
                        G[(row0+r)*GLD + nt0*16 + col16] = sg0[r];
                        G[(row0+r)*GLD + nt1*16 + col16] = sg1[r];
                    }
                }
            }
            barrier_lds_only();
            if (gthread) {
#pragma unroll
                for (int si = 0; si < 2; ++si) {
                    const int s = sg + si*4;
                    float gr  = G[s*GLD + j]       + bhr;
                    float gz  = G[s*GLD + 128 + j] + bhz;
                    float gnh = G[s*GLD + 256 + j] + bhn;
                    const float* xrow = &xp_lds[(s*8 + tt)*XPLD];
                    float r  = sigmoidf_(xrow[j] + gr);
                    float z  = sigmoidf_(xrow[128 + j] + gz);
                    float nv = tanhf_(xrow[256 + j] + r * gnh);
                    float hold = si ? hprev1 : hprev0;
                    float hnew = (1.f - z) * nv + z * hold;
                    if (si) hprev1 = hnew; else hprev0 = hnew;
                    u16 hh, hl; bf16_split(hnew, hh, hl);
                    // paired u32 writes: even j handles the hi row pair, odd j the lo
                    u16 ohh = (u16)__shfl_xor((int)hh, 1);
                    u16 ohl = (u16)__shfl_xor((int)hl, 1);
                    const long tbase = ((long)(seq0 + s)*64 + t)*512 + dir*128;
                    if ((j & 1) == 0) {
                        u32 w = (u32)hh | ((u32)ohh << 16);
                        *(u32*)&h_pk[qj*HPLD + (subkj*16 + s)*8 + ej] = w;
                        *(u32*)&houtp[tbase + j] = w;
                    } else {
                        u32 w = (u32)ohl | ((u32)hl << 16);
                        *(u32*)&h_pk[qj*HPLD + (subkj*16 + s + 8)*8 + (ej - 1)] = w;
                        *(u32*)&houtp[tbase + 256 + (j - 1)] = w;
                    }
                }
            }
            barrier_lds_only();
        }
    }
}

// ---------------- fused attention: score MFMA + tanh/ctx + softmax + pool ----------
// PACKED=true: A = hout u16 [sent][t][hilo][k256]; staged via decode-permute copy.
// PACKED=false: A is fp32 [M][256], staged with bf16 split (sentence level).
template<int T, bool PACKED>
__global__ __launch_bounds__(1024)
void attn_fused(const float* __restrict__ A, const u16* __restrict__ WF,
                const float* __restrict__ bias, const float* __restrict__ ctx,
                float* __restrict__ outp)
{
    __shared__ u16 a_pk[8][8][512];    // 64 KB
    __shared__ float pscore[8][8][17];
    __shared__ float aw[64];
    __shared__ float red[4][256];
    const int tid = threadIdx.x;
    const int lane = tid & 63;
    const int wid = tid >> 6;   // 0..15
    const int m0 = blockIdx.x * 64;

    sh8 bh[8], bl[8];
#pragma unroll
    for (int q = 0; q < 8; ++q) {
        bh[q] = *(const sh8*)(WF + (wid*8 + q)*512 + lane*8);
        bl[q] = *(const sh8*)(WF + 65536 + (wid*8 + q)*512 + lane*8);
    }
    const int colg = wid*16 + (lane & 15);
    const float bwv = bias[colg];
    const float cxv = ctx[colg];

    if (PACKED) {
        const u32* src32 = (const u32*)A + (long)blockIdx.x * 16384;
        u32* dst = (u32*)a_pk;
        for (int idx = tid; idx < 16384; idx += 1024) {
            int mf = idx >> 11, q = (idx >> 8) & 7, l = (idx >> 2) & 63, c2 = idx & 3;
            int row16 = l & 15, hilo = row16 >> 3, rm = row16 & 7;
            int t = mf*8 + rm;
            int k = q*32 + (l >> 4)*8 + c2*2;
            dst[idx] = src32[(t*2 + hilo)*128 + (k >> 1)];
        }
    } else {
        for (int idx = tid; idx < 8192; idx += 1024) {
            int row = idx >> 7;            // 0..63
            int k   = (idx & 127) << 1;
            float2 v = *(const float2*)&A[(long)(m0 + row)*256 + k];
            u16 h0,l0,h1,l1; bf16_split(v.x,h0,l0); bf16_split(v.y,h1,l1);
            int mf = row >> 3, rm = row & 7;
            int q = k >> 5;
            int lh = (((k & 31) >> 3) << 4) | rm;
            int e = k & 7;
            *(u32*)&a_pk[mf][q][lh*8 + e]     = (u32)h0 | ((u32)h1 << 16);
            *(u32*)&a_pk[mf][q][(lh+8)*8 + e] = (u32)l0 | ((u32)l1 << 16);
        }
    }
    __syncthreads();

#pragma unroll
    for (int mf = 0; mf < 8; ++mf) {
        f32x4 acc = (f32x4){0.f,0.f,0.f,0.f};
#pragma unroll
        for (int q = 0; q < 8; ++q) {
            sh8 a = *(const sh8*)&a_pk[mf][q][lane*8];
            acc = __builtin_amdgcn_mfma_f32_16x16x32_bf16(a, bh[q], acc, 0,0,0);
            acc = __builtin_amdgcn_mfma_f32_16x16x32_bf16(a, bl[q], acc, 0,0,0);
        }
        float g[4];
#pragma unroll
        for (int r = 0; r < 4; ++r) g[r] = acc[r] + __shfl_xor(acc[r], 32);
        if ((lane >= 32) == (mf & 1)) {    // half-dedup: each half handles 4 mf
            float p[4];
#pragma unroll
            for (int r = 0; r < 4; ++r) p[r] = tanhf_(g[r] + bwv) * cxv;
#pragma unroll
            for (int r = 0; r < 4; ++r) {
                p[r] += __shfl_xor(p[r], 1);
                p[r] += __shfl_xor(p[r], 2);
                p[r] += __shfl_xor(p[r], 4);
                p[r] += __shfl_xor(p[r], 8);
            }
            if ((lane & 15) == 0) {
#pragma unroll
                for (int r = 0; r < 4; ++r)
                    pscore[mf][((lane >> 4) & 1)*4 + r][wid] = p[r];
            }
        }
    }
    __syncthreads();

    // softmax over T (per sentence group) in wave 0
    if (tid < 64) {
        float sc = 0.f;
#pragma unroll
        for (int w = 0; w < 16; ++w) sc += pscore[tid >> 3][tid & 7][w];
        float mx = sc;
#pragma unroll
        for (int m = 1; m < T; m <<= 1) mx = fmaxf(mx, __shfl_xor(mx, m));
        float e = __expf(sc - mx);
        float den = e;
#pragma unroll
        for (int m = 1; m < T; m <<= 1) den += __shfl_xor(den, m);
        aw[tid] = __fdividef(e, den);
    }
    __syncthreads();

    // weighted sum: h reconstructed from a_pk (hi+lo); thread -> (d-pair, t-group)
    if (tid < 512) {
        const int dp = (tid & 127) << 1;
        const int tg = tid >> 7;          // 0..3
        const int q = dp >> 5, lhb = ((dp & 31) >> 3) << 4, e = dp & 7;
        float acc0 = 0.f, acc1 = 0.f;
#pragma unroll
        for (int i = 0; i < 16; ++i) {
            int t = tg*16 + i;
            int mf = t >> 3, rm = t & 7;
            const u16* base = &a_pk[mf][q][(lhb | rm)*8 + e];
            u32 hh = *(const u32*)base;
            u32 ll = *(const u32*)(base + 64);
            float h0 = bf16_f((u16)hh) + bf16_f((u16)ll);
            float h1 = bf16_f((u16)(hh >> 16)) + bf16_f((u16)(ll >> 16));
            float w = aw[t];
            acc0 = fmaf(w, h0, acc0);
            acc1 = fmaf(w, h1, acc1);
        }
        red[tg][dp] = acc0; red[tg][dp + 1] = acc1;
    }
    __syncthreads();
    if (T == 64) {
        if (tid < 256)
            outp[(long)blockIdx.x*256 + tid] = red[0][tid] + red[1][tid] + red[2][tid] + red[3][tid];
    } else {
        if (tid < 512) {
            int sent = tid >> 8, dd = tid & 255;
            outp[((long)blockIdx.x*2 + sent)*256 + dd] = red[sent*2][dd] + red[sent*2 + 1][dd];
        }
    }
}

// ---------------- tiled GEMM (+bias) for sentence xp ----------------
__global__ __launch_bounds__(256)
void gemm_xp(const float* __restrict__ A,
             const float* __restrict__ WT, const float* __restrict__ bias,
             float* __restrict__ out, int N, int K)
{
    __shared__ float As[64*128];
    __shared__ float Bs[128*64];
    const int tid = threadIdx.x;
    const int m0 = blockIdx.x * 64;
    const int n0 = blockIdx.y * 64;
    const int tx = tid & 15, ty = tid >> 4;
    float acc[4][4];
#pragma unroll
    for (int i=0;i<4;i++)
#pragma unroll
        for (int c=0;c<4;c++) acc[i][c]=0.f;

    for (int kc = 0; kc < K; kc += 128) {
        if (kc) __syncthreads();
#pragma unroll
        for (int it = 0; it < 8; ++it) {
            int idx = tid + it*256;
            int r = idx >> 5, c4 = idx & 31;
            float4 v = *(const float4*)&A[(long)(m0 + r)*K + kc + (c4<<2)];
            *(float4*)&As[r*128 + ((c4 ^ (r & 7)) << 2)] = v;
        }
#pragma unroll
        for (int it = 0; it < 8; ++it) {
            int idx = tid + it*256;
            int k = idx >> 4, c4 = idx & 15;
            float4 v = *(const float4*)&WT[(long)(kc + k)*N + n0 + (c4<<2)];
            *(float4*)&Bs[k*64 + ((c4 ^ (k & 7)) << 2)] = v;
        }
        __syncthreads();
        const int swzA = (ty & 7) << 2;
#pragma unroll 4
        for (int k = 0; k < 128; ++k) {
            float4 b = *(const float4*)&Bs[k*64 + ((tx ^ (k & 7)) << 2)];
            int kx = k ^ swzA;
#pragma unroll
            for (int i=0;i<4;i++) {
                float a = As[(ty + 16*i)*128 + kx];
                acc[i][0] = fmaf(a, b.x, acc[i][0]);
                acc[i][1] = fmaf(a, b.y, acc[i][1]);
                acc[i][2] = fmaf(a, b.z, acc[i][2]);
                acc[i][3] = fmaf(a, b.w, acc[i][3]);
            }
        }
    }
    float4 bia = *(const float4*)&bias[n0 + (tx<<2)];
#pragma unroll
    for (int i=0;i<4;i++) {
        float4 res = make_float4(acc[i][0]+bia.x, acc[i][1]+bia.y, acc[i][2]+bia.z, acc[i][3]+bia.w);
        *(float4*)&out[(long)(m0 + ty + 16*i)*N + n0 + (tx<<2)] = res;
    }
}

// ---------------- sentence GRU (streamed weights; small) ----------------
template<int NSEQ, int T>
__global__ __launch_bounds__(512)
void gru_fused(const float* __restrict__ xp, const float4* __restrict__ whh4,
               const float* __restrict__ bhh, float* __restrict__ hout,
               int blocks_per_dir)
{
    const int bx = blockIdx.x;
    const int dir = bx / blocks_per_dir;
    const int blk = bx % blocks_per_dir;
    const int seq0 = blk * NSEQ;
    const int tid = threadIdx.x;
    const int kq = tid & 3;
    const int j  = tid >> 2;
    const float4* W = whh4 + (long)dir * 12288;
    __shared__ float h_lds[NSEQ][128];
    for (int idx = tid; idx < NSEQ*128; idx += 512) ((float*)h_lds)[idx] = 0.f;
    const float bhr = bhh[dir*384 + j];
    const float bhz = bhh[dir*384 + 128 + j];
    const float bhn = bhh[dir*384 + 256 + j];
    __syncthreads();

    for (int ts = 0; ts < T; ++ts) {
        const int t = dir ? (T - 1 - ts) : ts;
        float a0[NSEQ], a1[NSEQ], a2[NSEQ];
#pragma unroll
        for (int s=0;s<NSEQ;s++){a0[s]=0.f;a1[s]=0.f;a2[s]=0.f;}
#pragma unroll
        for (int ii = 0; ii < 8; ++ii) {
            const int k4 = kq + (ii << 2);
            float4 w0 = W[k4*384 + j];
            float4 w1 = W[k4*384 + 128 + j];
            float4 w2 = W[k4*384 + 256 + j];
#pragma unroll
            for (int s=0;s<NSEQ;s++) {
                float4 h4 = *(const float4*)&h_lds[s][k4 << 2];
                a0[s] = fmaf(w0.x,h4.x, fmaf(w0.y,h4.y, fmaf(w0.z,h4.z, fmaf(w0.w,h4.w, a0[s]))));
                a1[s] = fmaf(w1.x,h4.x, fmaf(w1.y,h4.y, fmaf(w1.z,h4.z, fmaf(w1.w,h4.w, a1[s]))));
                a2[s] = fmaf(w2.x,h4.x, fmaf(w2.y,h4.y, fmaf(w2.z,h4.z, fmaf(w2.w,h4.w, a2[s]))));
            }
        }
#pragma unroll
        for (int s=0;s<NSEQ;s++) {
            a0[s] += __shfl_xor(a0[s], 1); a0[s] += __shfl_xor(a0[s], 2);
            a1[s] += __shfl_xor(a1[s], 1); a1[s] += __shfl_xor(a1[s], 2);
            a2[s] += __shfl_xor(a2[s], 1); a2[s] += __shfl_xor(a2[s], 2);
        }
        __syncthreads();
        if (kq == 0) {
#pragma unroll
            for (int s=0;s<NSEQ;s++) {
                const float* xr = &xp[((long)(seq0+s)*T + t)*768 + dir*384];
                float r = sigmoidf_(xr[j]       + a0[s] + bhr);
                float z = sigmoidf_(xr[128 + j] + a1[s] + bhz);
                float nv = tanhf_(xr[256 + j] + r * (a2[s] + bhn));
                float hold = h_lds[s][j];
                float hnew = (1.f - z) * nv + z * hold;
                h_lds[s][j] = hnew;
                hout[((long)(seq0+s)*T + t)*256 + dir*128 + j] = hnew;
            }
        }
        __syncthreads();
    }
}

// ---------------- classifier ----------------
__global__ void classifier(const float* __restrict__ doc, const float* __restrict__ Wc,
                           const float* __restrict__ bc, float* __restrict__ out)
{
    int tid = threadIdx.x;
    if (tid < 320) {
        int b = tid / 10, c = tid % 10;
        float s = bc[c];
        for (int d = 0; d < 256; ++d) s = fmaf(doc[b*256 + d], Wc[c*256 + d], s);
        out[tid] = s;
    }
}

extern "C" void kernel_launch(void* const* d_in, const int* in_sizes, int n_in,
                              void* d_out, int out_size, void* d_ws, size_t ws_size,
                              hipStream_t stream) {
    const int*   X       = (const int*)  d_in[0];
    const float* emb     = (const float*)d_in[1];
    const float* w_ih_f  = (const float*)d_in[2];
    const float* w_hh_f  = (const float*)d_in[3];
    const float* b_ih_f  = (const float*)d_in[4];
    const float* b_hh_f  = (const float*)d_in[5];
    const float* w_ih_b  = (const float*)d_in[6];
    const float* w_hh_b  = (const float*)d_in[7];
    const float* b_ih_b  = (const float*)d_in[8];
    const float* b_hh_b  = (const float*)d_in[9];
    const float* Ww      = (const float*)d_in[10];
    const float* bw      = (const float*)d_in[11];
    const float* ctx_w   = (const float*)d_in[12];
    const float* s_ih_f  = (const float*)d_in[13];
    const float* s_hh_f  = (const float*)d_in[14];
    const float* sb_ih_f = (const float*)d_in[15];
    const float* sb_hh_f = (const float*)d_in[16];
    const float* s_ih_b  = (const float*)d_in[17];
    const float* s_hh_b  = (const float*)d_in[18];
    const float* sb_ih_b = (const float*)d_in[19];
    const float* sb_hh_b = (const float*)d_in[20];
    const float* Ws      = (const float*)d_in[21];
    const float* bs      = (const float*)d_in[22];
    const float* ctx_s   = (const float*)d_in[23];
    const float* Wc      = (const float*)d_in[24];
    const float* bc      = (const float*)d_in[25];
    float* ws  = (float*)d_ws;
    float* out = (float*)d_out;

    if (ws_size < (size_t)WS_FLOATS * 4) return;   // fail cleanly if scratch too small

    // 1. weight prep
    prep<<<2444, 256, 0, stream>>>(s_ih_f, s_ih_b, w_ih_f, w_ih_b,
                                   w_hh_f, w_hh_b, s_hh_f, s_hh_b,
                                   b_ih_f, b_ih_b, sb_ih_f, sb_ih_b,
                                   b_hh_f, b_hh_b, sb_hh_f, sb_hh_b, ws);
    prep2<<<768, 256, 0, stream>>>(w_hh_f, w_hh_b, (u16*)(ws + OFF_WFHH));
    prep3<<<1792, 256, 0, stream>>>(Ww, Ws, w_ih_f, w_ih_b,
                                    (u16*)(ws + OFF_WFW_W), (u16*)(ws + OFF_WFW_S),
                                    (u16*)(ws + OFF_WFX));

    // 2. fused word pipeline (round-21: 8-seq + summed-G + float4 staging)
    gru_word_full<<<256, 768, 0, stream>>>(
        X, emb, (const u16*)(ws + OFF_WFX), (const u16*)(ws + OFF_WFHH),
        b_ih_f, b_ih_b, b_hh_f, b_hh_b, (u16*)(ws + OFF_HW));

    // 3. fused word attention (decode-permute staging) -> sents
    attn_fused<64, true><<<1024, 1024, 0, stream>>>(
        ws + OFF_HW, (const u16*)(ws + OFF_WFW_W), bw, ctx_w, ws + OFF_SENTS);

    // 4. sentence xp
    gemm_xp<<<dim3(16, 12), 256, 0, stream>>>(
        ws + OFF_SENTS, ws + OFF_WIHT_S, ws + OFF_BIH_S, ws + OFF_XP_S, 768, 256);
    // 5. sentence GRU
    gru_fused<1, 32><<<64, 512, 0, stream>>>(
        ws + OFF_XP_S, (const float4*)(ws + OFF_W6) + 4*12288, ws + OFF_BHH_S, ws + OFF_HS, 32);
    // 6. fused sentence attention -> doc
    attn_fused<32, false><<<16, 1024, 0, stream>>>(
        ws + OFF_HS, (const u16*)(ws + OFF_WFW_S), bs, ctx_s, ws + OFF_DOC);
    // 7. classifier
    classifier<<<1, 320, 0, stream>>>(ws + OFF_DOC, Wc, bc, out);
}

// Round 8
// 335.110 us; speedup vs baseline: 1.2756x; 1.0482x over previous
//
#include <hip/hip_runtime.h>
#include <hip/hip_bf16.h>
#include <math.h>

// Problem constants
#define Bd 32
#define Sd 32
#define Ld 64
#define Ed 128
#define Hd 128
#define MW 65536   // B*S*L tokens
#define MS 1024    // B*S sentences

// ws layout (float offsets)
#define OFF_WIHT_S   0          // [k=256][g=768] sentence input-proj weights (fp32)
#define OFF_WFW_W    196608     // 131072 u16: word attn Ww B-frags hi/lo
#define OFF_WFW_S    262144     // 131072 u16: sent attn Ws B-frags hi/lo
#define OFF_W6       327680     // 6 sets x float4[k4=32][g=384] (sets 4,5 used: sentence GRU)
#define OFF_BIH_W    622592     // (unused, kept)
#define OFF_BIH_S    623360
#define OFF_BHH_W    624128     // (unused, kept)
#define OFF_BHH_S    624896
#define OFF_WFX      625664     // 196608 u16: word xp w_ih B-frags [dir][half][nt24][q4][l][e]
#define OFF_HW       723968     // 1024 sents x [t64][hilo2][k256] u16 = 33.5M u16
#define OFF_SENTS    17763328   // 1024 x 256
#define OFF_XP_S     18025472   // 1024 x 768
#define OFF_HS       18811904   // 1024 x 256
#define OFF_DOC      19078144   // 32 x 256
#define OFF_WFHH     19086336   // 196608 u16: W_hh MFMA B-frags hi/lo
#define WS_FLOATS    19184640   // 76.7 MB

typedef __attribute__((ext_vector_type(8))) short sh8;
typedef __attribute__((ext_vector_type(4))) float f32x4;
typedef unsigned short u16;
typedef unsigned int u32;

#define GLD  388   // G stride, 8 rows (seqs 0-7, hi+lo pre-summed)
#define XPLD 385   // xp_lds stride (mod 32 = 1 -> banks spread)
#define HPLD 520   // h_pk per-q stride in u16 (q-pad spreads banks)

// Raw workgroup barrier: waits LDS/shfl (lgkmcnt) only, deliberately NOT vmcnt
// (hout stores are never read back in-kernel).
__device__ __forceinline__ void barrier_lds_only() {
    asm volatile("s_waitcnt lgkmcnt(0)\n\ts_barrier" ::: "memory");
}

__device__ __forceinline__ float sigmoidf_(float x) {
    return __fdividef(1.0f, 1.0f + __expf(-x));
}
__device__ __forceinline__ float tanhf_(float x) {
    float t = __expf(-2.0f * fabsf(x));
    float r = __fdividef(1.0f - t, 1.0f + t);
    return copysignf(r, x);
}
__device__ __forceinline__ u16 bf16_hi(float f) {
    u32 x = __float_as_uint(f);
    return (u16)((x + 0x7fffu + ((x >> 16) & 1u)) >> 16);
}
__device__ __forceinline__ float bf16_f(u16 u) { return __uint_as_float(((u32)u) << 16); }
__device__ __forceinline__ void bf16_split(float f, u16& hi, u16& lo) {
    hi = bf16_hi(f);
    lo = bf16_hi(f - bf16_f(hi));
}

// ---------------- fused weight prep (round-22: 3 launches -> 1) ----------------
// blocks [0,2444): old prep; [2444,3212): old prep2; [3212,5004): old prep3.
__global__ void prep_all(const float* __restrict__ s_ih_f, const float* __restrict__ s_ih_b,
                         const float* __restrict__ w_ih_f, const float* __restrict__ w_ih_b,
                         const float* __restrict__ w_hh_f, const float* __restrict__ w_hh_b,
                         const float* __restrict__ s_hh_f, const float* __restrict__ s_hh_b,
                         const float* __restrict__ b_ih_f, const float* __restrict__ b_ih_b,
                         const float* __restrict__ sb_ih_f, const float* __restrict__ sb_ih_b,
                         const float* __restrict__ b_hh_f, const float* __restrict__ b_hh_b,
                         const float* __restrict__ sb_hh_f, const float* __restrict__ sb_hh_b,
                         const float* __restrict__ Ww, const float* __restrict__ Ws,
                         float* __restrict__ ws)
{
    const int b = blockIdx.x;
    if (b < 2444) {
        // ---- old prep ----
        int i = b * 256 + threadIdx.x;
        if (i < 196608) {  // WIHT_S [k=256][768]
            int k = i / 768, g = i % 768;
            ws[OFF_WIHT_S + i] = (g < 384) ? s_ih_f[g*256 + k] : s_ih_b[(g-384)*256 + k];
            return;
        }
        i -= 196608;
        if (i < 131072) return;   // frag buffers written by prep3 part
        i -= 131072;
        if (i < 294912) {  // W6 (sets 4,5 used by sentence GRU)
            int set = i / 49152, rem = i % 49152;
            int k4 = rem / 1536, r2 = rem % 1536, g = r2 >> 2, sub = r2 & 3;
            const float* w = (set==0) ? w_ih_f : (set==1) ? w_ih_b : (set==2) ? w_hh_f
                           : (set==3) ? w_hh_b : (set==4) ? s_hh_f : s_hh_b;
            ws[OFF_W6 + i] = w[g*128 + k4*4 + sub];
            return;
        }
        i -= 294912;
        if (i < 768) { ws[OFF_BIH_W + i] = (i<384) ? b_ih_f[i] : b_ih_b[i-384]; return; }
        i -= 768;
        if (i < 768) { ws[OFF_BIH_S + i] = (i<384) ? sb_ih_f[i] : sb_ih_b[i-384]; return; }
        i -= 768;
        if (i < 768) { ws[OFF_BHH_W + i] = (i<384) ? b_hh_f[i] : b_hh_b[i-384]; return; }
        i -= 768;
        if (i < 768) { ws[OFF_BHH_S + i] = (i<384) ? sb_hh_f[i] : sb_hh_b[i-384]; return; }
        return;
    }
    if (b < 3212) {
        // ---- old prep2: W_hh frags [dir2][half2][nt24][q4][lane64][elem8] ----
        u16* WFo = (u16*)(ws + OFF_WFHH);
        int i = (b - 2444) * 256 + threadIdx.x;   // < 196608
        int within = i % 49152;
        int combo  = i / 49152;      // dir*2 + half
        int half = combo & 1, dir = combo >> 1;
        int nt  = within / 2048;
        int r2  = within % 2048;
        int q   = r2 >> 9;
        int r3  = r2 & 511;
        int l   = r3 >> 3, e = r3 & 7;
        int n = nt*16 + (l & 15);
        int k = q*32 + ((l >> 4) << 3) + e;
        const float* src = dir ? w_hh_b : w_hh_f;
        float v = src[n*128 + k];
        u16 hi = bf16_hi(v);
        WFo[i] = half ? bf16_hi(v - bf16_f(hi)) : hi;
        return;
    }
    {
        // ---- old prep3: attn + xp weight frags ----
        u16* WFW_W = (u16*)(ws + OFF_WFW_W);
        u16* WFW_S = (u16*)(ws + OFF_WFW_S);
        u16* WFX   = (u16*)(ws + OFF_WFX);
        int i = (b - 3212) * 256 + threadIdx.x;   // < 458752
        if (i < 262144) {
            int which = i / 131072;       // 0=Ww, 1=Ws
            int w = i % 131072;
            int half = w / 65536;
            int r = w % 65536;
            int nt = r / 4096;
            int r2 = r % 4096;
            int q = r2 / 512;
            int l = (r2 % 512) >> 3, e = r2 & 7;
            int n = nt*16 + (l & 15);
            int k = q*32 + ((l >> 4) << 3) + e;
            const float* src = which ? Ws : Ww;
            float v = src[n*256 + k];
            u16 hi = bf16_hi(v);
            u16 o = half ? bf16_hi(v - bf16_f(hi)) : hi;
            (which ? WFW_S : WFW_W)[w] = o;
            return;
        }
        i -= 262144;
        if (i < 196608) {
            int w = i % 98304;
            int dir = i / 98304;
            int half = w / 49152;
            int r = w % 49152;
            int nt = r / 2048;
            int r2 = r % 2048;
            int q = r2 / 512;
            int l = (r2 % 512) >> 3, e = r2 & 7;
            int n = nt*16 + (l & 15);
            int k = q*32 + ((l >> 4) << 3) + e;
            const float* src = dir ? w_ih_b : w_ih_f;
            float v = src[n*128 + k];
            u16 hi = bf16_hi(v);
            WFX[i] = half ? bf16_hi(v - bf16_f(hi)) : hi;
            return;
        }
    }
}

// ---------------- fused word pipeline: gather + xp-GEMM (LDS) + recurrence ----------
// ROUND-22: round-21 base (8-seq, summed-G, float4 staging; 195-198us) + xrow
// prefetch: the gate phase's 6 xp_lds reads are chunk-stable but used to issue AFTER
// the G barrier, putting ~120-240cy of LDS latency on the post-barrier critical path
// every step. Prefetch them at step start (overlapped with the MFMA/G-write phase),
// +6 VGPR. All other word-kernel levers are falsified or blocked (r15-r21).
__global__ __launch_bounds__(768)
void gru_word_full(const int* __restrict__ X, const float* __restrict__ emb,
                   const u16* __restrict__ WFX, const u16* __restrict__ WFHH,
                   const float* __restrict__ b_ih_f, const float* __restrict__ b_ih_b,
                   const float* __restrict__ b_hh_f, const float* __restrict__ b_hh_b,
                   u16* __restrict__ houtp)
{
    const int bx = blockIdx.x;
    const int dir = bx >> 7;
    const int blk = bx & 127;
    const int seq0 = blk * 8;
    const int tid = threadIdx.x;
    const int lane = tid & 63;
    const int wid = tid >> 6;            // 0..11

    __shared__ float xp_lds[64 * XPLD];      // 98560 B (rows = s*8 + tt)
    __shared__ f32x4 uni4[2048];             // 32768 B union: a_pk (32 KB) / G (12.4 KB)
    __shared__ u16 h_pk[4 * HPLD];           // 4160 B (hi rows 0-7, lo rows 8-15)
    __shared__ int ids_s[8][64];             // 2048 B
    float* G = (float*)uni4;                 // [8][GLD] (hi+lo pre-summed)
    u16* a_pk = (u16*)uni4;                  // [8 mf][4 q][512] u16

    const int j = tid & 127;
    const int sg = tid >> 7;             // 0..3 gate threads (s = sg, sg+4)
    const bool gthread = tid < 512;
    const float* bih = dir ? b_ih_b : b_ih_f;
    const float* bhh = dir ? b_hh_b : b_hh_f;
    float bhr = 0.f, bhz = 0.f, bhn = 0.f;
    if (gthread) { bhr = bhh[j]; bhz = bhh[128 + j]; bhn = bhh[256 + j]; }

    const u16* WXbase = WFX + (long)dir * 98304;
    const u16* WHbase = WFHH + (long)dir * 98304;
    const int nt0 = wid*2, nt1 = wid*2 + 1;
    const int c0 = nt0*16 + (lane & 15);
    const int c1 = nt1*16 + (lane & 15);
    // gate-thread h_pk write decomposition for k = j
    const int qj = j >> 5, subkj = (j >> 3) & 3, ej = j & 7;

    for (int i = tid; i < 512; i += 768)
        ids_s[i >> 6][i & 63] = X[(long)(seq0 + (i >> 6))*64 + (i & 63)];
    for (int i = tid; i < 4*HPLD; i += 768) h_pk[i] = 0;
    __syncthreads();

    float hprev0 = 0.f, hprev1 = 0.f;
    for (int c = 0; c < 8; ++c) {
        asm volatile("" ::: "memory");   // no cross-chunk hoisting of weight loads
        // ---- load W_ih frags (this chunk only) ----
        sh8 xh0[4], xl0[4], xh1[4], xl1[4];
#pragma unroll
        for (int q = 0; q < 4; ++q) {
            xh0[q] = *(const sh8*)(WXbase + (nt0*4 + q)*512 + lane*8);
            xl0[q] = *(const sh8*)(WXbase + 49152 + (nt0*4 + q)*512 + lane*8);
            xh1[q] = *(const sh8*)(WXbase + (nt1*4 + q)*512 + lane*8);
            xl1[q] = *(const sh8*)(WXbase + 49152 + (nt1*4 + q)*512 + lane*8);
        }
        const float bv0 = bih[c0], bv1 = bih[c1];
        // ---- stage gathered embeddings: 2048 float4 items, paired hi/lo words ----
        // idx bits: [0]=cc2 [3:1]=rm(tt) [5:4]=subk [7:6]=q [10:8]=mfs(s)
        for (int idx = tid; idx < 2048; idx += 768) {
            int cc2 = idx & 1, rm = (idx >> 1) & 7, subk = (idx >> 4) & 3;
            int q = (idx >> 6) & 3, mfs = idx >> 8;
            int ts = c*8 + rm;
            int t = dir ? 63 - ts : ts;
            int kk = q*32 + subk*8 + cc2*4;
            int id = ids_s[mfs][t];
            float4 v = make_float4(0.f, 0.f, 0.f, 0.f);
            if (id != 0) v = *(const float4*)&emb[(long)id*128 + kk];
            u16 h0,l0,h1,l1,h2,l2,h3,l3;
            bf16_split(v.x,h0,l0); bf16_split(v.y,h1,l1);
            bf16_split(v.z,h2,l2); bf16_split(v.w,h3,l3);
            int lh = subk*16 + rm;
            int base = (mfs*4 + q)*512 + lh*8 + cc2*4;
            uint2 whi = make_uint2((u32)h0 | ((u32)h1 << 16), (u32)h2 | ((u32)h3 << 16));
            uint2 wlo = make_uint2((u32)l0 | ((u32)l1 << 16), (u32)l2 | ((u32)l3 << 16));
            *(uint2*)&a_pk[base]      = whi;
            *(uint2*)&a_pk[base + 64] = wlo;   // (lh+8)*8 - lh*8 = 64 u16
        }
        barrier_lds_only();
        // ---- xp MFMA: 8 m-frags -> xp_lds (+bias), half-dedup epilogue ----
#pragma unroll
        for (int mf = 0; mf < 8; ++mf) {
            f32x4 A0 = (f32x4){0.f,0.f,0.f,0.f};
            f32x4 A1 = (f32x4){0.f,0.f,0.f,0.f};
#pragma unroll
            for (int q = 0; q < 4; ++q) {
                sh8 a = *(const sh8*)&a_pk[(mf*4 + q)*512 + lane*8];
                A0 = __builtin_amdgcn_mfma_f32_16x16x32_bf16(a, xh0[q], A0, 0,0,0);
                A0 = __builtin_amdgcn_mfma_f32_16x16x32_bf16(a, xl0[q], A0, 0,0,0);
                A1 = __builtin_amdgcn_mfma_f32_16x16x32_bf16(a, xh1[q], A1, 0,0,0);
                A1 = __builtin_amdgcn_mfma_f32_16x16x32_bf16(a, xl1[q], A1, 0,0,0);
            }
            float g0[4], g1[4];
#pragma unroll
            for (int r = 0; r < 4; ++r) {
                g0[r] = A0[r] + __shfl_xor(A0[r], 32);
                g1[r] = A1[r] + __shfl_xor(A1[r], 32);
            }
            if ((lane >= 32) == (mf & 1)) {
                int row = mf*8 + ((lane >> 4) & 1)*4;
#pragma unroll
                for (int r = 0; r < 4; ++r) {
                    xp_lds[(row+r)*XPLD + c0] = g0[r] + bv0;
                    xp_lds[(row+r)*XPLD + c1] = g1[r] + bv1;
                }
            }
        }
        barrier_lds_only();   // xp ready; a_pk region free -> G
        asm volatile("" ::: "memory");
        // ---- load W_hh frags ----
        sh8 wh0[4], wl0[4], wh1[4], wl1[4];
#pragma unroll
        for (int q = 0; q < 4; ++q) {
            wh0[q] = *(const sh8*)(WHbase + (nt0*4 + q)*512 + lane*8);
            wl0[q] = *(const sh8*)(WHbase + 49152 + (nt0*4 + q)*512 + lane*8);
            wh1[q] = *(const sh8*)(WHbase + (nt1*4 + q)*512 + lane*8);
            wl1[q] = *(const sh8*)(WHbase + 49152 + (nt1*4 + q)*512 + lane*8);
        }
        // ---- 8 recurrence steps ----
        for (int tt = 0; tt < 8; ++tt) {
            const int ts = c*8 + tt;
            const int t = dir ? 63 - ts : ts;
            // xrow prefetch: xp_lds is stable all chunk; issue these 6 LDS reads NOW
            // so they overlap the MFMA/G-write phase instead of serializing after the
            // barrier on the gate critical path.
            float pxr[2], pxz[2], pxn[2];
            if (gthread) {
#pragma unroll
                for (int si = 0; si < 2; ++si) {
                    const float* xrow = &xp_lds[((sg + si*4)*8 + tt)*XPLD];
                    pxr[si] = xrow[j];
                    pxz[si] = xrow[128 + j];
                    pxn[si] = xrow[256 + j];
                }
            }
            f32x4 acc0 = (f32x4){0.f,0.f,0.f,0.f};
            f32x4 acc1 = (f32x4){0.f,0.f,0.f,0.f};
#pragma unroll
            for (int q = 0; q < 4; ++q) {
                sh8 hp = *(const sh8*)&h_pk[q*HPLD + lane*8];
                acc0 = __builtin_amdgcn_mfma_f32_16x16x32_bf16(hp, wh0[q], acc0, 0,0,0);
                acc0 = __builtin_amdgcn_mfma_f32_16x16x32_bf16(hp, wl0[q], acc0, 0,0,0);
                acc1 = __builtin_amdgcn_mfma_f32_16x16x32_bf16(hp, wh1[q], acc1, 0,0,0);
                acc1 = __builtin_amdgcn_mfma_f32_16x16x32_bf16(hp, wl1[q], acc1, 0,0,0);
            }
            // summed-G: hi row s (lanes 0-31) + lo row s+8 (lanes 32-63) share a reg
            {
                float sg0[4], sg1[4];
#pragma unroll
                for (int r = 0; r < 4; ++r) {
                    sg0[r] = acc0[r] + __shfl_xor(acc0[r], 32);
                    sg1[r] = acc1[r] + __shfl_xor(acc1[r], 32);
                }
                if (lane < 32) {
                    const int col16 = lane & 15;
                    const int row0  = (lane >> 4) << 2;   // 0 or 4
#pragma unroll
                    for (int r = 0; r < 4; ++r) {
                        G[(row0+r)*GLD + nt0*16 + col16] = sg0[r];
                        G[(row0+r)*GLD + nt1*16 + col16] = sg1[r];
                    }
                }
            }
            barrier_lds_only();
            if (gthread) {
#pragma unroll
                for (int si = 0; si < 2; ++si) {
                    const int s = sg + si*4;
                    float gr  = G[s*GLD + j]       + bhr;
                    float gz  = G[s*GLD + 128 + j] + bhz;
                    float gnh = G[s*GLD + 256 + j] + bhn;
                    float r  = sigmoidf_(pxr[si] + gr);
                    float z  = sigmoidf_(pxz[si] + gz);
                    float nv = tanhf_(pxn[si] + r * gnh);
                    float hold = si ? hprev1 : hprev0;
                    float hnew = (1.f - z) * nv + z * hold;
                    if (si) hprev1 = hnew; else hprev0 = hnew;
                    u16 hh, hl; bf16_split(hnew, hh, hl);
                    // paired u32 writes: even j handles the hi row pair, odd j the lo
                    u16 ohh = (u16)__shfl_xor((int)hh, 1);
                    u16 ohl = (u16)__shfl_xor((int)hl, 1);
                    const long tbase = ((long)(seq0 + s)*64 + t)*512 + dir*128;
                    if ((j & 1) == 0) {
                        u32 w = (u32)hh | ((u32)ohh << 16);
                        *(u32*)&h_pk[qj*HPLD + (subkj*16 + s)*8 + ej] = w;
                        *(u32*)&houtp[tbase + j] = w;
                    } else {
                        u32 w = (u32)ohl | ((u32)hl << 16);
                        *(u32*)&h_pk[qj*HPLD + (subkj*16 + s + 8)*8 + (ej - 1)] = w;
                        *(u32*)&houtp[tbase + 256 + (j - 1)] = w;
                    }
                }
            }
            barrier_lds_only();
        }
    }
}

// ---------------- fused attention: score MFMA + tanh/ctx + softmax + pool ----------
// PACKED=true: A = hout u16 [sent][t][hilo][k256]; staged via decode-permute copy.
// PACKED=false: A is fp32 [M][256], staged with bf16 split (sentence level).
template<int T, bool PACKED>
__global__ __launch_bounds__(1024)
void attn_fused(const float* __restrict__ A, const u16* __restrict__ WF,
                const float* __restrict__ bias, const float* __restrict__ ctx,
                float* __restrict__ outp)
{
    __shared__ u16 a_pk[8][8][512];    // 64 KB
    __shared__ float pscore[8][8][17];
    __shared__ float aw[64];
    __shared__ float red[4][256];
    const int tid = threadIdx.x;
    const int lane = tid & 63;
    const int wid = tid >> 6;   // 0..15
    const int m0 = blockIdx.x * 64;

    sh8 bh[8], bl[8];
#pragma unroll
    for (int q = 0; q < 8; ++q) {
        bh[q] = *(const sh8*)(WF + (wid*8 + q)*512 + lane*8);
        bl[q] = *(const sh8*)(WF + 65536 + (wid*8 + q)*512 + lane*8);
    }
    const int colg = wid*16 + (lane & 15);
    const float bwv = bias[colg];
    const float cxv = ctx[colg];

    if (PACKED) {
        const u32* src32 = (const u32*)A + (long)blockIdx.x * 16384;
        u32* dst = (u32*)a_pk;
        for (int idx = tid; idx < 16384; idx += 1024) {
            int mf = idx >> 11, q = (idx >> 8) & 7, l = (idx >> 2) & 63, c2 = idx & 3;
            int row16 = l & 15, hilo = row16 >> 3, rm = row16 & 7;
            int t = mf*8 + rm;
            int k = q*32 + (l >> 4)*8 + c2*2;
            dst[idx] = src32[(t*2 + hilo)*128 + (k >> 1)];
        }
    } else {
        for (int idx = tid; idx < 8192; idx += 1024) {
            int row = idx >> 7;            // 0..63
            int k   = (idx & 127) << 1;
            float2 v = *(const float2*)&A[(long)(m0 + row)*256 + k];
            u16 h0,l0,h1,l1; bf16_split(v.x,h0,l0); bf16_split(v.y,h1,l1);
            int mf = row >> 3, rm = row & 7;
            int q = k >> 5;
            int lh = (((k & 31) >> 3) << 4) | rm;
            int e = k & 7;
            *(u32*)&a_pk[mf][q][lh*8 + e]     = (u32)h0 | ((u32)h1 << 16);
            *(u32*)&a_pk[mf][q][(lh+8)*8 + e] = (u32)l0 | ((u32)l1 << 16);
        }
    }
    __syncthreads();

#pragma unroll
    for (int mf = 0; mf < 8; ++mf) {
        f32x4 acc = (f32x4){0.f,0.f,0.f,0.f};
#pragma unroll
        for (int q = 0; q < 8; ++q) {
            sh8 a = *(const sh8*)&a_pk[mf][q][lane*8];
            acc = __builtin_amdgcn_mfma_f32_16x16x32_bf16(a, bh[q], acc, 0,0,0);
            acc = __builtin_amdgcn_mfma_f32_16x16x32_bf16(a, bl[q], acc, 0,0,0);
        }
        float g[4];
#pragma unroll
        for (int r = 0; r < 4; ++r) g[r] = acc[r] + __shfl_xor(acc[r], 32);
        if ((lane >= 32) == (mf & 1)) {    // half-dedup: each half handles 4 mf
            float p[4];
#pragma unroll
            for (int r = 0; r < 4; ++r) p[r] = tanhf_(g[r] + bwv) * cxv;
#pragma unroll
            for (int r = 0; r < 4; ++r) {
                p[r] += __shfl_xor(p[r], 1);
                p[r] += __shfl_xor(p[r], 2);
                p[r] += __shfl_xor(p[r], 4);
                p[r] += __shfl_xor(p[r], 8);
            }
            if ((lane & 15) == 0) {
#pragma unroll
                for (int r = 0; r < 4; ++r)
                    pscore[mf][((lane >> 4) & 1)*4 + r][wid] = p[r];
            }
        }
    }
    __syncthreads();

    // softmax over T (per sentence group) in wave 0
    if (tid < 64) {
        float sc = 0.f;
#pragma unroll
        for (int w = 0; w < 16; ++w) sc += pscore[tid >> 3][tid & 7][w];
        float mx = sc;
#pragma unroll
        for (int m = 1; m < T; m <<= 1) mx = fmaxf(mx, __shfl_xor(mx, m));
        float e = __expf(sc - mx);
        float den = e;
#pragma unroll
        for (int m = 1; m < T; m <<= 1) den += __shfl_xor(den, m);
        aw[tid] = __fdividef(e, den);
    }
    __syncthreads();

    // weighted sum: h reconstructed from a_pk (hi+lo); thread -> (d-pair, t-group)
    if (tid < 512) {
        const int dp = (tid & 127) << 1;
        const int tg = tid >> 7;          // 0..3
        const int q = dp >> 5, lhb = ((dp & 31) >> 3) << 4, e = dp & 7;
        float acc0 = 0.f, acc1 = 0.f;
#pragma unroll
        for (int i = 0; i < 16; ++i) {
            int t = tg*16 + i;
            int mf = t >> 3, rm = t & 7;
            const u16* base = &a_pk[mf][q][(lhb | rm)*8 + e];
            u32 hh = *(const u32*)base;
            u32 ll = *(const u32*)(base + 64);
            float h0 = bf16_f((u16)hh) + bf16_f((u16)ll);
            float h1 = bf16_f((u16)(hh >> 16)) + bf16_f((u16)(ll >> 16));
            float w = aw[t];
            acc0 = fmaf(w, h0, acc0);
            acc1 = fmaf(w, h1, acc1);
        }
        red[tg][dp] = acc0; red[tg][dp + 1] = acc1;
    }
    __syncthreads();
    if (T == 64) {
        if (tid < 256)
            outp[(long)blockIdx.x*256 + tid] = red[0][tid] + red[1][tid] + red[2][tid] + red[3][tid];
    } else {
        if (tid < 512) {
            int sent = tid >> 8, dd = tid & 255;
            outp[((long)blockIdx.x*2 + sent)*256 + dd] = red[sent*2][dd] + red[sent*2 + 1][dd];
        }
    }
}

// ---------------- tiled GEMM (+bias) for sentence xp ----------------
__global__ __launch_bounds__(256)
void gemm_xp(const float* __restrict__ A,
             const float* __restrict__ WT, const float* __restrict__ bias,
             float* __restrict__ out, int N, int K)
{
    __shared__ float As[64*128];
    __shared__ float Bs[128*64];
    const int tid = threadIdx.x;
    const int m0 = blockIdx.x * 64;
    const int n0 = blockIdx.y * 64;
    const int tx = tid & 15, ty = tid >> 4;
    float acc[4][4];
#pragma unroll
    for (int i=0;i<4;i++)
#pragma unroll
        for (int c=0;c<4;c++) acc[i][c]=0.f;

    for (int kc = 0; kc < K; kc += 128) {
        if (kc) __syncthreads();
#pragma unroll
        for (int it = 0; it < 8; ++it) {
            int idx = tid + it*256;
            int r = idx >> 5, c4 = idx & 31;
            float4 v = *(const float4*)&A[(long)(m0 + r)*K + kc + (c4<<2)];
            *(float4*)&As[r*128 + ((c4 ^ (r & 7)) << 2)] = v;
        }
#pragma unroll
        for (int it = 0; it < 8; ++it) {
            int idx = tid + it*256;
            int k = idx >> 4, c4 = idx & 15;
            float4 v = *(const float4*)&WT[(long)(kc + k)*N + n0 + (c4<<2)];
            *(float4*)&Bs[k*64 + ((c4 ^ (k & 7)) << 2)] = v;
        }
        __syncthreads();
        const int swzA = (ty & 7) << 2;
#pragma unroll 4
        for (int k = 0; k < 128; ++k) {
            float4 b = *(const float4*)&Bs[k*64 + ((tx ^ (k & 7)) << 2)];
            int kx = k ^ swzA;
#pragma unroll
            for (int i=0;i<4;i++) {
                float a = As[(ty + 16*i)*128 + kx];
                acc[i][0] = fmaf(a, b.x, acc[i][0]);
                acc[i][1] = fmaf(a, b.y, acc[i][1]);
                acc[i][2] = fmaf(a, b.z, acc[i][2]);
                acc[i][3] = fmaf(a, b.w, acc[i][3]);
            }
        }
    }
    float4 bia = *(const float4*)&bias[n0 + (tx<<2)];
#pragma unroll
    for (int i=0;i<4;i++) {
        float4 res = make_float4(acc[i][0]+bia.x, acc[i][1]+bia.y, acc[i][2]+bia.z, acc[i][3]+bia.w);
        *(float4*)&out[(long)(m0 + ty + 16*i)*N + n0 + (tx<<2)] = res;
    }
}

// ---------------- sentence GRU (round-22: weights hoisted to registers) ------------
// The 24 float4 weight loads per step are loop-invariant over ts but were re-issued
// every one of the 32 serial steps (64-block latency-bound kernel -> each load stall
// lands on the critical path). Hoist them into registers before the ts loop.
template<int NSEQ, int T>
__global__ __launch_bounds__(512)
void gru_fused(const float* __restrict__ xp, const float4* __restrict__ whh4,
               const float* __restrict__ bhh, float* __restrict__ hout,
               int blocks_per_dir)
{
    const int bx = blockIdx.x;
    const int dir = bx / blocks_per_dir;
    const int blk = bx % blocks_per_dir;
    const int seq0 = blk * NSEQ;
    const int tid = threadIdx.x;
    const int kq = tid & 3;
    const int j  = tid >> 2;
    const float4* W = whh4 + (long)dir * 12288;
    __shared__ float h_lds[NSEQ][128];
    for (int idx = tid; idx < NSEQ*128; idx += 512) ((float*)h_lds)[idx] = 0.f;
    const float bhr = bhh[dir*384 + j];
    const float bhz = bhh[dir*384 + 128 + j];
    const float bhn = bhh[dir*384 + 256 + j];
    // hoisted loop-invariant weights: 24 float4 (96 VGPR)
    float4 w0r[8], w1r[8], w2r[8];
#pragma unroll
    for (int ii = 0; ii < 8; ++ii) {
        const int k4 = kq + (ii << 2);
        w0r[ii] = W[k4*384 + j];
        w1r[ii] = W[k4*384 + 128 + j];
        w2r[ii] = W[k4*384 + 256 + j];
    }
    __syncthreads();

    for (int ts = 0; ts < T; ++ts) {
        const int t = dir ? (T - 1 - ts) : ts;
        float a0[NSEQ], a1[NSEQ], a2[NSEQ];
#pragma unroll
        for (int s=0;s<NSEQ;s++){a0[s]=0.f;a1[s]=0.f;a2[s]=0.f;}
#pragma unroll
        for (int ii = 0; ii < 8; ++ii) {
            const int k4 = kq + (ii << 2);
            float4 w0 = w0r[ii];
            float4 w1 = w1r[ii];
            float4 w2 = w2r[ii];
#pragma unroll
            for (int s=0;s<NSEQ;s++) {
                float4 h4 = *(const float4*)&h_lds[s][k4 << 2];
                a0[s] = fmaf(w0.x,h4.x, fmaf(w0.y,h4.y, fmaf(w0.z,h4.z, fmaf(w0.w,h4.w, a0[s]))));
                a1[s] = fmaf(w1.x,h4.x, fmaf(w1.y,h4.y, fmaf(w1.z,h4.z, fmaf(w1.w,h4.w, a1[s]))));
                a2[s] = fmaf(w2.x,h4.x, fmaf(w2.y,h4.y, fmaf(w2.z,h4.z, fmaf(w2.w,h4.w, a2[s]))));
            }
        }
#pragma unroll
        for (int s=0;s<NSEQ;s++) {
            a0[s] += __shfl_xor(a0[s], 1); a0[s] += __shfl_xor(a0[s], 2);
            a1[s] += __shfl_xor(a1[s], 1); a1[s] += __shfl_xor(a1[s], 2);
            a2[s] += __shfl_xor(a2[s], 1); a2[s] += __shfl_xor(a2[s], 2);
        }
        __syncthreads();
        if (kq == 0) {
#pragma unroll
            for (int s=0;s<NSEQ;s++) {
                const float* xr = &xp[((long)(seq0+s)*T + t)*768 + dir*384];
                float r = sigmoidf_(xr[j]       + a0[s] + bhr);
                float z = sigmoidf_(xr[128 + j] + a1[s] + bhz);
                float nv = tanhf_(xr[256 + j] + r * (a2[s] + bhn));
                float hold = h_lds[s][j];
                float hnew = (1.f - z) * nv + z * hold;
                h_lds[s][j] = hnew;
                hout[((long)(seq0+s)*T + t)*256 + dir*128 + j] = hnew;
            }
        }
        __syncthreads();
    }
}

// ---------------- classifier (round-22: float4 loads) ----------------
__global__ void classifier(const float* __restrict__ doc, const float* __restrict__ Wc,
                           const float* __restrict__ bc, float* __restrict__ out)
{
    int tid = threadIdx.x;
    if (tid < 320) {
        int b = tid / 10, c = tid % 10;
        float s = bc[c];
        const float4* dp = (const float4*)&doc[b*256];
        const float4* wp = (const float4*)&Wc[c*256];
        for (int d = 0; d < 64; ++d) {
            float4 a = dp[d], w = wp[d];
            s = fmaf(a.x, w.x, fmaf(a.y, w.y, fmaf(a.z, w.z, fmaf(a.w, w.w, s))));
        }
        out[tid] = s;
    }
}

extern "C" void kernel_launch(void* const* d_in, const int* in_sizes, int n_in,
                              void* d_out, int out_size, void* d_ws, size_t ws_size,
                              hipStream_t stream) {
    const int*   X       = (const int*)  d_in[0];
    const float* emb     = (const float*)d_in[1];
    const float* w_ih_f  = (const float*)d_in[2];
    const float* w_hh_f  = (const float*)d_in[3];
    const float* b_ih_f  = (const float*)d_in[4];
    const float* b_hh_f  = (const float*)d_in[5];
    const float* w_ih_b  = (const float*)d_in[6];
    const float* w_hh_b  = (const float*)d_in[7];
    const float* b_ih_b  = (const float*)d_in[8];
    const float* b_hh_b  = (const float*)d_in[9];
    const float* Ww      = (const float*)d_in[10];
    const float* bw      = (const float*)d_in[11];
    const float* ctx_w   = (const float*)d_in[12];
    const float* s_ih_f  = (const float*)d_in[13];
    const float* s_hh_f  = (const float*)d_in[14];
    const float* sb_ih_f = (const float*)d_in[15];
    const float* sb_hh_f = (const float*)d_in[16];
    const float* s_ih_b  = (const float*)d_in[17];
    const float* s_hh_b  = (const float*)d_in[18];
    const float* sb_ih_b = (const float*)d_in[19];
    const float* sb_hh_b = (const float*)d_in[20];
    const float* Ws      = (const float*)d_in[21];
    const float* bs      = (const float*)d_in[22];
    const float* ctx_s   = (const float*)d_in[23];
    const float* Wc      = (const float*)d_in[24];
    const float* bc      = (const float*)d_in[25];
    float* ws  = (float*)d_ws;
    float* out = (float*)d_out;

    if (ws_size < (size_t)WS_FLOATS * 4) return;   // fail cleanly if scratch too small

    // 1. weight prep (fused: 3 launches -> 1)
    prep_all<<<5004, 256, 0, stream>>>(s_ih_f, s_ih_b, w_ih_f, w_ih_b,
                                       w_hh_f, w_hh_b, s_hh_f, s_hh_b,
                                       b_ih_f, b_ih_b, sb_ih_f, sb_ih_b,
                                       b_hh_f, b_hh_b, sb_hh_f, sb_hh_b,
                                       Ww, Ws, ws);

    // 2. fused word pipeline (round-22: + xrow prefetch)
    gru_word_full<<<256, 768, 0, stream>>>(
        X, emb, (const u16*)(ws + OFF_WFX), (const u16*)(ws + OFF_WFHH),
        b_ih_f, b_ih_b, b_hh_f, b_hh_b, (u16*)(ws + OFF_HW));

    // 3. fused word attention (decode-permute staging) -> sents
    attn_fused<64, true><<<1024, 1024, 0, stream>>>(
        ws + OFF_HW, (const u16*)(ws + OFF_WFW_W), bw, ctx_w, ws + OFF_SENTS);

    // 4. sentence xp
    gemm_xp<<<dim3(16, 12), 256, 0, stream>>>(
        ws + OFF_SENTS, ws + OFF_WIHT_S, ws + OFF_BIH_S, ws + OFF_XP_S, 768, 256);
    // 5. sentence GRU (round-22: hoisted weights)
    gru_fused<1, 32><<<64, 512, 0, stream>>>(
        ws + OFF_XP_S, (const float4*)(ws + OFF_W6) + 4*12288, ws + OFF_BHH_S, ws + OFF_HS, 32);
    // 6. fused sentence attention -> doc
    attn_fused<32, false><<<16, 1024, 0, stream>>>(
        ws + OFF_HS, (const u16*)(ws + OFF_WFW_S), bs, ctx_s, ws + OFF_DOC);
    // 7. classifier
    classifier<<<1, 320, 0, stream>>>(ws + OFF_DOC, Wc, bc, out);
}

// Round 9
// 323.293 us; speedup vs baseline: 1.3222x; 1.0366x over previous
//
#include <hip/hip_runtime.h>
#include <hip/hip_bf16.h>
#include <math.h>

// Problem constants
#define Bd 32
#define Sd 32
#define Ld 64
#define Ed 128
#define Hd 128
#define MW 65536   // B*S*L tokens
#define MS 1024    // B*S sentences

// ws layout (float offsets)
#define OFF_WIHT_S   0          // [k=256][g=768] sentence input-proj weights (fp32)
#define OFF_WFW_W    196608     // 131072 u16: word attn Ww B-frags hi/lo
#define OFF_WFW_S    262144     // 131072 u16: sent attn Ws B-frags hi/lo
#define OFF_W6       327680     // 6 sets x float4[k4=32][g=384] (sets 4,5 used: sentence GRU)
#define OFF_BIH_W    622592     // (unused, kept)
#define OFF_BIH_S    623360
#define OFF_BHH_W    624128     // (unused, kept)
#define OFF_BHH_S    624896
#define OFF_WFX      625664     // 196608 u16: word xp w_ih B-frags [dir][half][nt24][q4][l][e]
#define OFF_HW       723968     // 1024 sents x [t64][hilo2][k256] u16 = 33.5M u16
#define OFF_SENTS    17763328   // 1024 x 256
#define OFF_XP_S     18025472   // 1024 x 768
#define OFF_HS       18811904   // 1024 x 256
#define OFF_DOC      19078144   // 32 x 256 (unused after round-23 classifier fusion)
#define OFF_WFHH     19086336   // 196608 u16: W_hh MFMA B-frags hi/lo
#define WS_FLOATS    19184640   // 76.7 MB

typedef __attribute__((ext_vector_type(8))) short sh8;
typedef __attribute__((ext_vector_type(4))) float f32x4;
typedef unsigned short u16;
typedef unsigned int u32;

#define GLD  388   // G stride, 8 rows (seqs 0-7, hi+lo pre-summed)
#define XPLD 385   // xp_lds stride (mod 32 = 1 -> banks spread)
#define HPLD 520   // h_pk per-q stride in u16 (q-pad spreads banks)

// Raw workgroup barrier: waits LDS/shfl (lgkmcnt) only, deliberately NOT vmcnt
// (hout stores are never read back in-kernel).
__device__ __forceinline__ void barrier_lds_only() {
    asm volatile("s_waitcnt lgkmcnt(0)\n\ts_barrier" ::: "memory");
}

__device__ __forceinline__ float sigmoidf_(float x) {
    return __fdividef(1.0f, 1.0f + __expf(-x));
}
__device__ __forceinline__ float tanhf_(float x) {
    float t = __expf(-2.0f * fabsf(x));
    float r = __fdividef(1.0f - t, 1.0f + t);
    return copysignf(r, x);
}
__device__ __forceinline__ u16 bf16_hi(float f) {
    u32 x = __float_as_uint(f);
    return (u16)((x + 0x7fffu + ((x >> 16) & 1u)) >> 16);
}
__device__ __forceinline__ float bf16_f(u16 u) { return __uint_as_float(((u32)u) << 16); }
__device__ __forceinline__ void bf16_split(float f, u16& hi, u16& lo) {
    hi = bf16_hi(f);
    lo = bf16_hi(f - bf16_f(hi));
}

// ---------------- fused weight prep (1 launch) ----------------
// blocks [0,2444): old prep; [2444,3212): old prep2; [3212,5004): old prep3.
// round-23: W6 sets 0-3 (word weights as float4) are dead since the word kernel
// moved to MFMA frags -> early-return (saves ~197K global writes).
__global__ void prep_all(const float* __restrict__ s_ih_f, const float* __restrict__ s_ih_b,
                         const float* __restrict__ w_ih_f, const float* __restrict__ w_ih_b,
                         const float* __restrict__ w_hh_f, const float* __restrict__ w_hh_b,
                         const float* __restrict__ s_hh_f, const float* __restrict__ s_hh_b,
                         const float* __restrict__ b_ih_f, const float* __restrict__ b_ih_b,
                         const float* __restrict__ sb_ih_f, const float* __restrict__ sb_ih_b,
                         const float* __restrict__ b_hh_f, const float* __restrict__ b_hh_b,
                         const float* __restrict__ sb_hh_f, const float* __restrict__ sb_hh_b,
                         const float* __restrict__ Ww, const float* __restrict__ Ws,
                         float* __restrict__ ws)
{
    const int b = blockIdx.x;
    if (b < 2444) {
        // ---- old prep ----
        int i = b * 256 + threadIdx.x;
        if (i < 196608) {  // WIHT_S [k=256][768]
            int k = i / 768, g = i % 768;
            ws[OFF_WIHT_S + i] = (g < 384) ? s_ih_f[g*256 + k] : s_ih_b[(g-384)*256 + k];
            return;
        }
        i -= 196608;
        if (i < 131072) return;   // frag buffers written by prep3 part
        i -= 131072;
        if (i < 294912) {  // W6 — only sets 4,5 (sentence GRU) are live
            int set = i / 49152;
            if (set < 4) return;                 // dead weights, skip
            int rem = i % 49152;
            int k4 = rem / 1536, r2 = rem % 1536, g = r2 >> 2, sub = r2 & 3;
            const float* w = (set==4) ? s_hh_f : s_hh_b;
            ws[OFF_W6 + i] = w[g*128 + k4*4 + sub];
            return;
        }
        i -= 294912;
        if (i < 768) { ws[OFF_BIH_W + i] = (i<384) ? b_ih_f[i] : b_ih_b[i-384]; return; }
        i -= 768;
        if (i < 768) { ws[OFF_BIH_S + i] = (i<384) ? sb_ih_f[i] : sb_ih_b[i-384]; return; }
        i -= 768;
        if (i < 768) { ws[OFF_BHH_W + i] = (i<384) ? b_hh_f[i] : b_hh_b[i-384]; return; }
        i -= 768;
        if (i < 768) { ws[OFF_BHH_S + i] = (i<384) ? sb_hh_f[i] : sb_hh_b[i-384]; return; }
        return;
    }
    if (b < 3212) {
        // ---- old prep2: W_hh frags [dir2][half2][nt24][q4][lane64][elem8] ----
        u16* WFo = (u16*)(ws + OFF_WFHH);
        int i = (b - 2444) * 256 + threadIdx.x;   // < 196608
        int within = i % 49152;
        int combo  = i / 49152;      // dir*2 + half
        int half = combo & 1, dir = combo >> 1;
        int nt  = within / 2048;
        int r2  = within % 2048;
        int q   = r2 >> 9;
        int r3  = r2 & 511;
        int l   = r3 >> 3, e = r3 & 7;
        int n = nt*16 + (l & 15);
        int k = q*32 + ((l >> 4) << 3) + e;
        const float* src = dir ? w_hh_b : w_hh_f;
        float v = src[n*128 + k];
        u16 hi = bf16_hi(v);
        WFo[i] = half ? bf16_hi(v - bf16_f(hi)) : hi;
        return;
    }
    {
        // ---- old prep3: attn + xp weight frags ----
        u16* WFW_W = (u16*)(ws + OFF_WFW_W);
        u16* WFW_S = (u16*)(ws + OFF_WFW_S);
        u16* WFX   = (u16*)(ws + OFF_WFX);
        int i = (b - 3212) * 256 + threadIdx.x;   // < 458752
        if (i < 262144) {
            int which = i / 131072;       // 0=Ww, 1=Ws
            int w = i % 131072;
            int half = w / 65536;
            int r = w % 65536;
            int nt = r / 4096;
            int r2 = r % 4096;
            int q = r2 / 512;
            int l = (r2 % 512) >> 3, e = r2 & 7;
            int n = nt*16 + (l & 15);
            int k = q*32 + ((l >> 4) << 3) + e;
            const float* src = which ? Ws : Ww;
            float v = src[n*256 + k];
            u16 hi = bf16_hi(v);
            u16 o = half ? bf16_hi(v - bf16_f(hi)) : hi;
            (which ? WFW_S : WFW_W)[w] = o;
            return;
        }
        i -= 262144;
        if (i < 196608) {
            int w = i % 98304;
            int dir = i / 98304;
            int half = w / 49152;
            int r = w % 49152;
            int nt = r / 2048;
            int r2 = r % 2048;
            int q = r2 / 512;
            int l = (r2 % 512) >> 3, e = r2 & 7;
            int n = nt*16 + (l & 15);
            int k = q*32 + ((l >> 4) << 3) + e;
            const float* src = dir ? w_ih_b : w_ih_f;
            float v = src[n*128 + k];
            u16 hi = bf16_hi(v);
            WFX[i] = half ? bf16_hi(v - bf16_f(hi)) : hi;
            return;
        }
    }
}

// ---------------- fused word pipeline: gather + xp-GEMM (LDS) + recurrence ----------
// ROUND-23: exact round-21 form (8-seq, summed-G, float4 staging; 195.7us). The r22
// xrow prefetch was a slight regression (+2-3us: compiler already hid those LDS reads;
// extra live regs cost more) -> reverted. Word-kernel intra-step tweaks are exhausted:
// 5 consecutive null/negative A/Bs (vmcnt-less barriers, store pairing, work trims,
// prefetch); col-grouping blocked by allocator, 2-block co-residency refused by
// scheduler at any LDS size. ~195us is this structure's plateau.
__global__ __launch_bounds__(768)
void gru_word_full(const int* __restrict__ X, const float* __restrict__ emb,
                   const u16* __restrict__ WFX, const u16* __restrict__ WFHH,
                   const float* __restrict__ b_ih_f, const float* __restrict__ b_ih_b,
                   const float* __restrict__ b_hh_f, const float* __restrict__ b_hh_b,
                   u16* __restrict__ houtp)
{
    const int bx = blockIdx.x;
    const int dir = bx >> 7;
    const int blk = bx & 127;
    const int seq0 = blk * 8;
    const int tid = threadIdx.x;
    const int lane = tid & 63;
    const int wid = tid >> 6;            // 0..11

    __shared__ float xp_lds[64 * XPLD];      // 98560 B (rows = s*8 + tt)
    __shared__ f32x4 uni4[2048];             // 32768 B union: a_pk (32 KB) / G (12.4 KB)
    __shared__ u16 h_pk[4 * HPLD];           // 4160 B (hi rows 0-7, lo rows 8-15)
    __shared__ int ids_s[8][64];             // 2048 B
    float* G = (float*)uni4;                 // [8][GLD] (hi+lo pre-summed)
    u16* a_pk = (u16*)uni4;                  // [8 mf][4 q][512] u16

    const int j = tid & 127;
    const int sg = tid >> 7;             // 0..3 gate threads (s = sg, sg+4)
    const bool gthread = tid < 512;
    const float* bih = dir ? b_ih_b : b_ih_f;
    const float* bhh = dir ? b_hh_b : b_hh_f;
    float bhr = 0.f, bhz = 0.f, bhn = 0.f;
    if (gthread) { bhr = bhh[j]; bhz = bhh[128 + j]; bhn = bhh[256 + j]; }

    const u16* WXbase = WFX + (long)dir * 98304;
    const u16* WHbase = WFHH + (long)dir * 98304;
    const int nt0 = wid*2, nt1 = wid*2 + 1;
    const int c0 = nt0*16 + (lane & 15);
    const int c1 = nt1*16 + (lane & 15);
    // gate-thread h_pk write decomposition for k = j
    const int qj = j >> 5, subkj = (j >> 3) & 3, ej = j & 7;

    for (int i = tid; i < 512; i += 768)
        ids_s[i >> 6][i & 63] = X[(long)(seq0 + (i >> 6))*64 + (i & 63)];
    for (int i = tid; i < 4*HPLD; i += 768) h_pk[i] = 0;
    __syncthreads();

    float hprev0 = 0.f, hprev1 = 0.f;
    for (int c = 0; c < 8; ++c) {
        asm volatile("" ::: "memory");   // no cross-chunk hoisting of weight loads
        // ---- load W_ih frags (this chunk only) ----
        sh8 xh0[4], xl0[4], xh1[4], xl1[4];
#pragma unroll
        for (int q = 0; q < 4; ++q) {
            xh0[q] = *(const sh8*)(WXbase + (nt0*4 + q)*512 + lane*8);
            xl0[q] = *(const sh8*)(WXbase + 49152 + (nt0*4 + q)*512 + lane*8);
            xh1[q] = *(const sh8*)(WXbase + (nt1*4 + q)*512 + lane*8);
            xl1[q] = *(const sh8*)(WXbase + 49152 + (nt1*4 + q)*512 + lane*8);
        }
        const float bv0 = bih[c0], bv1 = bih[c1];
        // ---- stage gathered embeddings: 2048 float4 items, paired hi/lo words ----
        // idx bits: [0]=cc2 [3:1]=rm(tt) [5:4]=subk [7:6]=q [10:8]=mfs(s)
        for (int idx = tid; idx < 2048; idx += 768) {
            int cc2 = idx & 1, rm = (idx >> 1) & 7, subk = (idx >> 4) & 3;
            int q = (idx >> 6) & 3, mfs = idx >> 8;
            int ts = c*8 + rm;
            int t = dir ? 63 - ts : ts;
            int kk = q*32 + subk*8 + cc2*4;
            int id = ids_s[mfs][t];
            float4 v = make_float4(0.f, 0.f, 0.f, 0.f);
            if (id != 0) v = *(const float4*)&emb[(long)id*128 + kk];
            u16 h0,l0,h1,l1,h2,l2,h3,l3;
            bf16_split(v.x,h0,l0); bf16_split(v.y,h1,l1);
            bf16_split(v.z,h2,l2); bf16_split(v.w,h3,l3);
            int lh = subk*16 + rm;
            int base = (mfs*4 + q)*512 + lh*8 + cc2*4;
            uint2 whi = make_uint2((u32)h0 | ((u32)h1 << 16), (u32)h2 | ((u32)h3 << 16));
            uint2 wlo = make_uint2((u32)l0 | ((u32)l1 << 16), (u32)l2 | ((u32)l3 << 16));
            *(uint2*)&a_pk[base]      = whi;
            *(uint2*)&a_pk[base + 64] = wlo;   // (lh+8)*8 - lh*8 = 64 u16
        }
        barrier_lds_only();
        // ---- xp MFMA: 8 m-frags -> xp_lds (+bias), half-dedup epilogue ----
#pragma unroll
        for (int mf = 0; mf < 8; ++mf) {
            f32x4 A0 = (f32x4){0.f,0.f,0.f,0.f};
            f32x4 A1 = (f32x4){0.f,0.f,0.f,0.f};
#pragma unroll
            for (int q = 0; q < 4; ++q) {
                sh8 a = *(const sh8*)&a_pk[(mf*4 + q)*512 + lane*8];
                A0 = __builtin_amdgcn_mfma_f32_16x16x32_bf16(a, xh0[q], A0, 0,0,0);
                A0 = __builtin_amdgcn_mfma_f32_16x16x32_bf16(a, xl0[q], A0, 0,0,0);
                A1 = __builtin_amdgcn_mfma_f32_16x16x32_bf16(a, xh1[q], A1, 0,0,0);
                A1 = __builtin_amdgcn_mfma_f32_16x16x32_bf16(a, xl1[q], A1, 0,0,0);
            }
            float g0[4], g1[4];
#pragma unroll
            for (int r = 0; r < 4; ++r) {
                g0[r] = A0[r] + __shfl_xor(A0[r], 32);
                g1[r] = A1[r] + __shfl_xor(A1[r], 32);
            }
            if ((lane >= 32) == (mf & 1)) {
                int row = mf*8 + ((lane >> 4) & 1)*4;
#pragma unroll
                for (int r = 0; r < 4; ++r) {
                    xp_lds[(row+r)*XPLD + c0] = g0[r] + bv0;
                    xp_lds[(row+r)*XPLD + c1] = g1[r] + bv1;
                }
            }
        }
        barrier_lds_only();   // xp ready; a_pk region free -> G
        asm volatile("" ::: "memory");
        // ---- load W_hh frags ----
        sh8 wh0[4], wl0[4], wh1[4], wl1[4];
#pragma unroll
        for (int q = 0; q < 4; ++q) {
            wh0[q] = *(const sh8*)(WHbase + (nt0*4 + q)*512 + lane*8);
            wl0[q] = *(const sh8*)(WHbase + 49152 + (nt0*4 + q)*512 + lane*8);
            wh1[q] = *(const sh8*)(WHbase + (nt1*4 + q)*512 + lane*8);
            wl1[q] = *(const sh8*)(WHbase + 49152 + (nt1*4 + q)*512 + lane*8);
        }
        // ---- 8 recurrence steps ----
        for (int tt = 0; tt < 8; ++tt) {
            const int ts = c*8 + tt;
            const int t = dir ? 63 - ts : ts;
            f32x4 acc0 = (f32x4){0.f,0.f,0.f,0.f};
            f32x4 acc1 = (f32x4){0.f,0.f,0.f,0.f};
#pragma unroll
            for (int q = 0; q < 4; ++q) {
                sh8 hp = *(const sh8*)&h_pk[q*HPLD + lane*8];
                acc0 = __builtin_amdgcn_mfma_f32_16x16x32_bf16(hp, wh0[q], acc0, 0,0,0);
                acc0 = __builtin_amdgcn_mfma_f32_16x16x32_bf16(hp, wl0[q], acc0, 0,0,0);
                acc1 = __builtin_amdgcn_mfma_f32_16x16x32_bf16(hp, wh1[q], acc1, 0,0,0);
                acc1 = __builtin_amdgcn_mfma_f32_16x16x32_bf16(hp, wl1[q], acc1, 0,0,0);
            }
            // summed-G: hi row s (lanes 0-31) + lo row s+8 (lanes 32-63) share a reg
            {
                float sg0[4], sg1[4];
#pragma unroll
                for (int r = 0; r < 4; ++r) {
                    sg0[r] = acc0[r] + __shfl_xor(acc0[r], 32);
                    sg1[r] = acc1[r] + __shfl_xor(acc1[r], 32);
                }
                if (lane < 32) {
                    const int col16 = lane & 15;
                    const int row0  = (lane >> 4) << 2;   // 0 or 4
#pragma unroll
                    for (int r = 0; r < 4; ++r) {
                        G[(row0+r)*GLD + nt0*16 + col16] = sg0[r];
                        G[(row0+r)*GLD + nt1*16 + col16] = sg1[r];
                    }
                }
            }
            barrier_lds_only();
            if (gthread) {
#pragma unroll
                for (int si = 0; si < 2; ++si) {
                    const int s = sg + si*4;
                    float gr  = G[s*GLD + j]       + bhr;
                    float gz  = G[s*GLD + 128 + j] + bhz;
                    float gnh = G[s*GLD + 256 + j] + bhn;
                    const float* xrow = &xp_lds[(s*8 + tt)*XPLD];
                    float r  = sigmoidf_(xrow[j] + gr);
                    float z  = sigmoidf_(xrow[128 + j] + gz);
                    float nv = tanhf_(xrow[256 + j] + r * gnh);
                    float hold = si ? hprev1 : hprev0;
                    float hnew = (1.f - z) * nv + z * hold;
                    if (si) hprev1 = hnew; else hprev0 = hnew;
                    u16 hh, hl; bf16_split(hnew, hh, hl);
                    // paired u32 writes: even j handles the hi row pair, odd j the lo
                    u16 ohh = (u16)__shfl_xor((int)hh, 1);
                    u16 ohl = (u16)__shfl_xor((int)hl, 1);
                    const long tbase = ((long)(seq0 + s)*64 + t)*512 + dir*128;
                    if ((j & 1) == 0) {
                        u32 w = (u32)hh | ((u32)ohh << 16);
                        *(u32*)&h_pk[qj*HPLD + (subkj*16 + s)*8 + ej] = w;
                        *(u32*)&houtp[tbase + j] = w;
                    } else {
                        u32 w = (u32)ohl | ((u32)hl << 16);
                        *(u32*)&h_pk[qj*HPLD + (subkj*16 + s + 8)*8 + (ej - 1)] = w;
                        *(u32*)&houtp[tbase + 256 + (j - 1)] = w;
                    }
                }
            }
            barrier_lds_only();
        }
    }
}

// ---------------- fused attention: score MFMA + tanh/ctx + softmax + pool ----------
// PACKED=true: A = hout u16 [sent][t][hilo][k256]; staged via decode-permute copy.
// PACKED=false: A is fp32 [M][256], staged with bf16 split (sentence level).
// CLS=true (round-23): fuse the classifier — block holds its 2 doc vectors in LDS;
// compute the 2x10 logits in-block and write them to the final output, deleting the
// classifier launch and the OFF_DOC round-trip.
template<int T, bool PACKED, bool CLS>
__global__ __launch_bounds__(1024)
void attn_fused(const float* __restrict__ A, const u16* __restrict__ WF,
                const float* __restrict__ bias, const float* __restrict__ ctx,
                float* __restrict__ outp,
                const float* __restrict__ Wc, const float* __restrict__ bc)
{
    __shared__ u16 a_pk[8][8][512];    // 64 KB
    __shared__ float pscore[8][8][17];
    __shared__ float aw[64];
    __shared__ float red[4][256];
    __shared__ float docv[2][256];     // CLS only (2 KB)
    const int tid = threadIdx.x;
    const int lane = tid & 63;
    const int wid = tid >> 6;   // 0..15
    const int m0 = blockIdx.x * 64;

    sh8 bh[8], bl[8];
#pragma unroll
    for (int q = 0; q < 8; ++q) {
        bh[q] = *(const sh8*)(WF + (wid*8 + q)*512 + lane*8);
        bl[q] = *(const sh8*)(WF + 65536 + (wid*8 + q)*512 + lane*8);
    }
    const int colg = wid*16 + (lane & 15);
    const float bwv = bias[colg];
    const float cxv = ctx[colg];

    if (PACKED) {
        const u32* src32 = (const u32*)A + (long)blockIdx.x * 16384;
        u32* dst = (u32*)a_pk;
        for (int idx = tid; idx < 16384; idx += 1024) {
            int mf = idx >> 11, q = (idx >> 8) & 7, l = (idx >> 2) & 63, c2 = idx & 3;
            int row16 = l & 15, hilo = row16 >> 3, rm = row16 & 7;
            int t = mf*8 + rm;
            int k = q*32 + (l >> 4)*8 + c2*2;
            dst[idx] = src32[(t*2 + hilo)*128 + (k >> 1)];
        }
    } else {
        for (int idx = tid; idx < 8192; idx += 1024) {
            int row = idx >> 7;            // 0..63
            int k   = (idx & 127) << 1;
            float2 v = *(const float2*)&A[(long)(m0 + row)*256 + k];
            u16 h0,l0,h1,l1; bf16_split(v.x,h0,l0); bf16_split(v.y,h1,l1);
            int mf = row >> 3, rm = row & 7;
            int q = k >> 5;
            int lh = (((k & 31) >> 3) << 4) | rm;
            int e = k & 7;
            *(u32*)&a_pk[mf][q][lh*8 + e]     = (u32)h0 | ((u32)h1 << 16);
            *(u32*)&a_pk[mf][q][(lh+8)*8 + e] = (u32)l0 | ((u32)l1 << 16);
        }
    }
    __syncthreads();

#pragma unroll
    for (int mf = 0; mf < 8; ++mf) {
        f32x4 acc = (f32x4){0.f,0.f,0.f,0.f};
#pragma unroll
        for (int q = 0; q < 8; ++q) {
            sh8 a = *(const sh8*)&a_pk[mf][q][lane*8];
            acc = __builtin_amdgcn_mfma_f32_16x16x32_bf16(a, bh[q], acc, 0,0,0);
            acc = __builtin_amdgcn_mfma_f32_16x16x32_bf16(a, bl[q], acc, 0,0,0);
        }
        float g[4];
#pragma unroll
        for (int r = 0; r < 4; ++r) g[r] = acc[r] + __shfl_xor(acc[r], 32);
        if ((lane >= 32) == (mf & 1)) {    // half-dedup: each half handles 4 mf
            float p[4];
#pragma unroll
            for (int r = 0; r < 4; ++r) p[r] = tanhf_(g[r] + bwv) * cxv;
#pragma unroll
            for (int r = 0; r < 4; ++r) {
                p[r] += __shfl_xor(p[r], 1);
                p[r] += __shfl_xor(p[r], 2);
                p[r] += __shfl_xor(p[r], 4);
                p[r] += __shfl_xor(p[r], 8);
            }
            if ((lane & 15) == 0) {
#pragma unroll
                for (int r = 0; r < 4; ++r)
                    pscore[mf][((lane >> 4) & 1)*4 + r][wid] = p[r];
            }
        }
    }
    __syncthreads();

    // softmax over T (per sentence group) in wave 0
    if (tid < 64) {
        float sc = 0.f;
#pragma unroll
        for (int w = 0; w < 16; ++w) sc += pscore[tid >> 3][tid & 7][w];
        float mx = sc;
#pragma unroll
        for (int m = 1; m < T; m <<= 1) mx = fmaxf(mx, __shfl_xor(mx, m));
        float e = __expf(sc - mx);
        float den = e;
#pragma unroll
        for (int m = 1; m < T; m <<= 1) den += __shfl_xor(den, m);
        aw[tid] = __fdividef(e, den);
    }
    __syncthreads();

    // weighted sum: h reconstructed from a_pk (hi+lo); thread -> (d-pair, t-group)
    if (tid < 512) {
        const int dp = (tid & 127) << 1;
        const int tg = tid >> 7;          // 0..3
        const int q = dp >> 5, lhb = ((dp & 31) >> 3) << 4, e = dp & 7;
        float acc0 = 0.f, acc1 = 0.f;
#pragma unroll
        for (int i = 0; i < 16; ++i) {
            int t = tg*16 + i;
            int mf = t >> 3, rm = t & 7;
            const u16* base = &a_pk[mf][q][(lhb | rm)*8 + e];
            u32 hh = *(const u32*)base;
            u32 ll = *(const u32*)(base + 64);
            float h0 = bf16_f((u16)hh) + bf16_f((u16)ll);
            float h1 = bf16_f((u16)(hh >> 16)) + bf16_f((u16)(ll >> 16));
            float w = aw[t];
            acc0 = fmaf(w, h0, acc0);
            acc1 = fmaf(w, h1, acc1);
        }
        red[tg][dp] = acc0; red[tg][dp + 1] = acc1;
    }
    __syncthreads();
    if (T == 64) {
        if (tid < 256)
            outp[(long)blockIdx.x*256 + tid] = red[0][tid] + red[1][tid] + red[2][tid] + red[3][tid];
    } else if (!CLS) {
        if (tid < 512) {
            int sent = tid >> 8, dd = tid & 255;
            outp[((long)blockIdx.x*2 + sent)*256 + dd] = red[sent*2][dd] + red[sent*2 + 1][dd];
        }
    } else {
        // classifier fusion: docv -> logits, write final output directly
        if (tid < 512) {
            int sent = tid >> 8, dd = tid & 255;
            docv[sent][dd] = red[sent*2][dd] + red[sent*2 + 1][dd];
        }
        __syncthreads();
        if (tid < 20) {
            int s = tid / 10, c = tid % 10;
            float acc = bc[c];
            const float4* wp = (const float4*)&Wc[c*256];
            const float4* dv = (const float4*)&docv[s][0];
#pragma unroll 8
            for (int d = 0; d < 64; ++d) {
                float4 a = dv[d], w = wp[d];
                acc = fmaf(a.x, w.x, fmaf(a.y, w.y, fmaf(a.z, w.z, fmaf(a.w, w.w, acc))));
            }
            outp[(blockIdx.x*2 + s)*10 + c] = acc;
        }
    }
}

// ---------------- tiled GEMM (+bias) for sentence xp ----------------
__global__ __launch_bounds__(256)
void gemm_xp(const float* __restrict__ A,
             const float* __restrict__ WT, const float* __restrict__ bias,
             float* __restrict__ out, int N, int K)
{
    __shared__ float As[64*128];
    __shared__ float Bs[128*64];
    const int tid = threadIdx.x;
    const int m0 = blockIdx.x * 64;
    const int n0 = blockIdx.y * 64;
    const int tx = tid & 15, ty = tid >> 4;
    float acc[4][4];
#pragma unroll
    for (int i=0;i<4;i++)
#pragma unroll
        for (int c=0;c<4;c++) acc[i][c]=0.f;

    for (int kc = 0; kc < K; kc += 128) {
        if (kc) __syncthreads();
#pragma unroll
        for (int it = 0; it < 8; ++it) {
            int idx = tid + it*256;
            int r = idx >> 5, c4 = idx & 31;
            float4 v = *(const float4*)&A[(long)(m0 + r)*K + kc + (c4<<2)];
            *(float4*)&As[r*128 + ((c4 ^ (r & 7)) << 2)] = v;
        }
#pragma unroll
        for (int it = 0; it < 8; ++it) {
            int idx = tid + it*256;
            int k = idx >> 4, c4 = idx & 15;
            float4 v = *(const float4*)&WT[(long)(kc + k)*N + n0 + (c4<<2)];
            *(float4*)&Bs[k*64 + ((c4 ^ (k & 7)) << 2)] = v;
        }
        __syncthreads();
        const int swzA = (ty & 7) << 2;
#pragma unroll 4
        for (int k = 0; k < 128; ++k) {
            float4 b = *(const float4*)&Bs[k*64 + ((tx ^ (k & 7)) << 2)];
            int kx = k ^ swzA;
#pragma unroll
            for (int i=0;i<4;i++) {
                float a = As[(ty + 16*i)*128 + kx];
                acc[i][0] = fmaf(a, b.x, acc[i][0]);
                acc[i][1] = fmaf(a, b.y, acc[i][1]);
                acc[i][2] = fmaf(a, b.z, acc[i][2]);
                acc[i][3] = fmaf(a, b.w, acc[i][3]);
            }
        }
    }
    float4 bia = *(const float4*)&bias[n0 + (tx<<2)];
#pragma unroll
    for (int i=0;i<4;i++) {
        float4 res = make_float4(acc[i][0]+bia.x, acc[i][1]+bia.y, acc[i][2]+bia.z, acc[i][3]+bia.w);
        *(float4*)&out[(long)(m0 + ty + 16*i)*N + n0 + (tx<<2)] = res;
    }
}

// ---------------- sentence GRU (weights hoisted to registers, r22) ----------------
template<int NSEQ, int T>
__global__ __launch_bounds__(512)
void gru_fused(const float* __restrict__ xp, const float4* __restrict__ whh4,
               const float* __restrict__ bhh, float* __restrict__ hout,
               int blocks_per_dir)
{
    const int bx = blockIdx.x;
    const int dir = bx / blocks_per_dir;
    const int blk = bx % blocks_per_dir;
    const int seq0 = blk * NSEQ;
    const int tid = threadIdx.x;
    const int kq = tid & 3;
    const int j  = tid >> 2;
    const float4* W = whh4 + (long)dir * 12288;
    __shared__ float h_lds[NSEQ][128];
    for (int idx = tid; idx < NSEQ*128; idx += 512) ((float*)h_lds)[idx] = 0.f;
    const float bhr = bhh[dir*384 + j];
    const float bhz = bhh[dir*384 + 128 + j];
    const float bhn = bhh[dir*384 + 256 + j];
    // hoisted loop-invariant weights: 24 float4 (96 VGPR)
    float4 w0r[8], w1r[8], w2r[8];
#pragma unroll
    for (int ii = 0; ii < 8; ++ii) {
        const int k4 = kq + (ii << 2);
        w0r[ii] = W[k4*384 + j];
        w1r[ii] = W[k4*384 + 128 + j];
        w2r[ii] = W[k4*384 + 256 + j];
    }
    __syncthreads();

    for (int ts = 0; ts < T; ++ts) {
        const int t = dir ? (T - 1 - ts) : ts;
        float a0[NSEQ], a1[NSEQ], a2[NSEQ];
#pragma unroll
        for (int s=0;s<NSEQ;s++){a0[s]=0.f;a1[s]=0.f;a2[s]=0.f;}
#pragma unroll
        for (int ii = 0; ii < 8; ++ii) {
            const int k4 = kq + (ii << 2);
            float4 w0 = w0r[ii];
            float4 w1 = w1r[ii];
            float4 w2 = w2r[ii];
#pragma unroll
            for (int s=0;s<NSEQ;s++) {
                float4 h4 = *(const float4*)&h_lds[s][k4 << 2];
                a0[s] = fmaf(w0.x,h4.x, fmaf(w0.y,h4.y, fmaf(w0.z,h4.z, fmaf(w0.w,h4.w, a0[s]))));
                a1[s] = fmaf(w1.x,h4.x, fmaf(w1.y,h4.y, fmaf(w1.z,h4.z, fmaf(w1.w,h4.w, a1[s]))));
                a2[s] = fmaf(w2.x,h4.x, fmaf(w2.y,h4.y, fmaf(w2.z,h4.z, fmaf(w2.w,h4.w, a2[s]))));
            }
        }
#pragma unroll
        for (int s=0;s<NSEQ;s++) {
            a0[s] += __shfl_xor(a0[s], 1); a0[s] += __shfl_xor(a0[s], 2);
            a1[s] += __shfl_xor(a1[s], 1); a1[s] += __shfl_xor(a1[s], 2);
            a2[s] += __shfl_xor(a2[s], 1); a2[s] += __shfl_xor(a2[s], 2);
        }
        __syncthreads();
        if (kq == 0) {
#pragma unroll
            for (int s=0;s<NSEQ;s++) {
                const float* xr = &xp[((long)(seq0+s)*T + t)*768 + dir*384];
                float r = sigmoidf_(xr[j]       + a0[s] + bhr);
                float z = sigmoidf_(xr[128 + j] + a1[s] + bhz);
                float nv = tanhf_(xr[256 + j] + r * (a2[s] + bhn));
                float hold = h_lds[s][j];
                float hnew = (1.f - z) * nv + z * hold;
                h_lds[s][j] = hnew;
                hout[((long)(seq0+s)*T + t)*256 + dir*128 + j] = hnew;
            }
        }
        __syncthreads();
    }
}

extern "C" void kernel_launch(void* const* d_in, const int* in_sizes, int n_in,
                              void* d_out, int out_size, void* d_ws, size_t ws_size,
                              hipStream_t stream) {
    const int*   X       = (const int*)  d_in[0];
    const float* emb     = (const float*)d_in[1];
    const float* w_ih_f  = (const float*)d_in[2];
    const float* w_hh_f  = (const float*)d_in[3];
    const float* b_ih_f  = (const float*)d_in[4];
    const float* b_hh_f  = (const float*)d_in[5];
    const float* w_ih_b  = (const float*)d_in[6];
    const float* w_hh_b  = (const float*)d_in[7];
    const float* b_ih_b  = (const float*)d_in[8];
    const float* b_hh_b  = (const float*)d_in[9];
    const float* Ww      = (const float*)d_in[10];
    const float* bw      = (const float*)d_in[11];
    const float* ctx_w   = (const float*)d_in[12];
    const float* s_ih_f  = (const float*)d_in[13];
    const float* s_hh_f  = (const float*)d_in[14];
    const float* sb_ih_f = (const float*)d_in[15];
    const float* sb_hh_f = (const float*)d_in[16];
    const float* s_ih_b  = (const float*)d_in[17];
    const float* s_hh_b  = (const float*)d_in[18];
    const float* sb_ih_b = (const float*)d_in[19];
    const float* sb_hh_b = (const float*)d_in[20];
    const float* Ws      = (const float*)d_in[21];
    const float* bs      = (const float*)d_in[22];
    const float* ctx_s   = (const float*)d_in[23];
    const float* Wc      = (const float*)d_in[24];
    const float* bc      = (const float*)d_in[25];
    float* ws  = (float*)d_ws;
    float* out = (float*)d_out;

    if (ws_size < (size_t)WS_FLOATS * 4) return;   // fail cleanly if scratch too small

    // 1. weight prep (fused; W6 sets 0-3 trimmed)
    prep_all<<<5004, 256, 0, stream>>>(s_ih_f, s_ih_b, w_ih_f, w_ih_b,
                                       w_hh_f, w_hh_b, s_hh_f, s_hh_b,
                                       b_ih_f, b_ih_b, sb_ih_f, sb_ih_b,
                                       b_hh_f, b_hh_b, sb_hh_f, sb_hh_b,
                                       Ww, Ws, ws);

    // 2. fused word pipeline (round-21 form; prefetch reverted)
    gru_word_full<<<256, 768, 0, stream>>>(
        X, emb, (const u16*)(ws + OFF_WFX), (const u16*)(ws + OFF_WFHH),
        b_ih_f, b_ih_b, b_hh_f, b_hh_b, (u16*)(ws + OFF_HW));

    // 3. fused word attention (decode-permute staging) -> sents
    attn_fused<64, true, false><<<1024, 1024, 0, stream>>>(
        ws + OFF_HW, (const u16*)(ws + OFF_WFW_W), bw, ctx_w, ws + OFF_SENTS,
        nullptr, nullptr);

    // 4. sentence xp
    gemm_xp<<<dim3(16, 12), 256, 0, stream>>>(
        ws + OFF_SENTS, ws + OFF_WIHT_S, ws + OFF_BIH_S, ws + OFF_XP_S, 768, 256);
    // 5. sentence GRU (hoisted weights)
    gru_fused<1, 32><<<64, 512, 0, stream>>>(
        ws + OFF_XP_S, (const float4*)(ws + OFF_W6) + 4*12288, ws + OFF_BHH_S, ws + OFF_HS, 32);
    // 6. fused sentence attention + classifier -> logits (classifier launch deleted)
    attn_fused<32, false, true><<<16, 1024, 0, stream>>>(
        ws + OFF_HS, (const u16*)(ws + OFF_WFW_S), bs, ctx_s, out, Wc, bc);
}

// Round 10
// 308.746 us; speedup vs baseline: 1.3845x; 1.0471x over previous
//
#include <hip/hip_runtime.h>
#include <hip/hip_bf16.h>
#include <math.h>

// Problem constants
#define Bd 32
#define Sd 32
#define Ld 64
#define Ed 128
#define Hd 128
#define MW 65536   // B*S*L tokens
#define MS 1024    // B*S sentences

// ws layout (float offsets)
#define OFF_WIHT_S   0          // (dead since r24: gemm_xp deleted)
#define OFF_WFW_W    196608     // 131072 u16: word attn Ww B-frags hi/lo
#define OFF_WFW_S    262144     // 131072 u16: sent attn Ws B-frags hi/lo
#define OFF_W6       327680     // sets 0-3 region now holds WFIHS frags (u16); sets 4,5: sentence GRU fp32
#define OFF_BIH_W    622592     // (unused, kept)
#define OFF_BIH_S    623360
#define OFF_BHH_W    624128     // (unused, kept)
#define OFF_BHH_S    624896
#define OFF_WFX      625664     // 196608 u16: word xp w_ih B-frags [dir][half][nt24][q4][l][e]
#define OFF_HW       723968     // 1024 sents x [t64][hilo2][k256] u16 = 33.5M u16
#define OFF_SENTS    17763328   // 1024 x 256
#define OFF_XP_S     18025472   // (dead since r24)
#define OFF_HS       18811904   // 1024 x 256
#define OFF_DOC      19078144   // (dead since r23)
#define OFF_WFHH     19086336   // 196608 u16: W_hh MFMA B-frags hi/lo
#define WS_FLOATS    19184640   // 76.7 MB

typedef __attribute__((ext_vector_type(8))) short sh8;
typedef __attribute__((ext_vector_type(4))) float f32x4;
typedef unsigned short u16;
typedef unsigned int u32;

#define GLD  388   // G stride, 8 rows (seqs 0-7, hi+lo pre-summed)
#define XPLD 385   // xp_lds stride (mod 32 = 1 -> banks spread)
#define HPLD 520   // h_pk per-q stride in u16 (q-pad spreads banks)

// Raw workgroup barrier: waits LDS/shfl (lgkmcnt) only, deliberately NOT vmcnt
// (hout stores are never read back in-kernel).
__device__ __forceinline__ void barrier_lds_only() {
    asm volatile("s_waitcnt lgkmcnt(0)\n\ts_barrier" ::: "memory");
}

__device__ __forceinline__ float sigmoidf_(float x) {
    return __fdividef(1.0f, 1.0f + __expf(-x));
}
__device__ __forceinline__ float tanhf_(float x) {
    float t = __expf(-2.0f * fabsf(x));
    float r = __fdividef(1.0f - t, 1.0f + t);
    return copysignf(r, x);
}
__device__ __forceinline__ u16 bf16_hi(float f) {
    u32 x = __float_as_uint(f);
    return (u16)((x + 0x7fffu + ((x >> 16) & 1u)) >> 16);
}
__device__ __forceinline__ float bf16_f(u16 u) { return __uint_as_float(((u32)u) << 16); }
__device__ __forceinline__ void bf16_split(float f, u16& hi, u16& lo) {
    hi = bf16_hi(f);
    lo = bf16_hi(f - bf16_f(hi));
}

// ---------------- fused weight prep (1 launch, 4 sections) ----------------
// A [0,1164): W6 sets 4,5 (sentence GRU fp32) + biases   (WIHT_S deleted in r24)
// B [1164,1932): W_hh MFMA frags (WFHH)
// C [1932,3724): attn Ww/Ws + word xp w_ih frags
// D [3724,5260): NEW r24 — sentence xp s_ih B-frags (WFIHS) into dead W6 sets 0-3:
//                [dir2][half2][nt24][q8][l64][e8] u16, 393216 total
__global__ void prep_all(const float* __restrict__ s_ih_f, const float* __restrict__ s_ih_b,
                         const float* __restrict__ w_ih_f, const float* __restrict__ w_ih_b,
                         const float* __restrict__ w_hh_f, const float* __restrict__ w_hh_b,
                         const float* __restrict__ s_hh_f, const float* __restrict__ s_hh_b,
                         const float* __restrict__ b_ih_f, const float* __restrict__ b_ih_b,
                         const float* __restrict__ sb_ih_f, const float* __restrict__ sb_ih_b,
                         const float* __restrict__ b_hh_f, const float* __restrict__ b_hh_b,
                         const float* __restrict__ sb_hh_f, const float* __restrict__ sb_hh_b,
                         const float* __restrict__ Ww, const float* __restrict__ Ws,
                         float* __restrict__ ws)
{
    const int b = blockIdx.x;
    if (b < 1164) {
        int i = b * 256 + threadIdx.x;
        if (i < 294912) {  // W6 — only sets 4,5 live (sets 0-3 region = WFIHS, section D)
            int set = i / 49152;
            if (set < 4) return;
            int rem = i % 49152;
            int k4 = rem / 1536, r2 = rem % 1536, g = r2 >> 2, sub = r2 & 3;
            const float* w = (set==4) ? s_hh_f : s_hh_b;
            ws[OFF_W6 + i] = w[g*128 + k4*4 + sub];
            return;
        }
        i -= 294912;
        if (i < 768) { ws[OFF_BIH_W + i] = (i<384) ? b_ih_f[i] : b_ih_b[i-384]; return; }
        i -= 768;
        if (i < 768) { ws[OFF_BIH_S + i] = (i<384) ? sb_ih_f[i] : sb_ih_b[i-384]; return; }
        i -= 768;
        if (i < 768) { ws[OFF_BHH_W + i] = (i<384) ? b_hh_f[i] : b_hh_b[i-384]; return; }
        i -= 768;
        if (i < 768) { ws[OFF_BHH_S + i] = (i<384) ? sb_hh_f[i] : sb_hh_b[i-384]; return; }
        return;
    }
    if (b < 1932) {
        // ---- W_hh frags [dir2][half2][nt24][q4][lane64][elem8] ----
        u16* WFo = (u16*)(ws + OFF_WFHH);
        int i = (b - 1164) * 256 + threadIdx.x;   // < 196608
        int within = i % 49152;
        int combo  = i / 49152;      // dir*2 + half
        int half = combo & 1, dir = combo >> 1;
        int nt  = within / 2048;
        int r2  = within % 2048;
        int q   = r2 >> 9;
        int r3  = r2 & 511;
        int l   = r3 >> 3, e = r3 & 7;
        int n = nt*16 + (l & 15);
        int k = q*32 + ((l >> 4) << 3) + e;
        const float* src = dir ? w_hh_b : w_hh_f;
        float v = src[n*128 + k];
        u16 hi = bf16_hi(v);
        WFo[i] = half ? bf16_hi(v - bf16_f(hi)) : hi;
        return;
    }
    if (b < 3724) {
        // ---- attn (Ww,Ws) + word xp (w_ih) frags ----
        u16* WFW_W = (u16*)(ws + OFF_WFW_W);
        u16* WFW_S = (u16*)(ws + OFF_WFW_S);
        u16* WFX   = (u16*)(ws + OFF_WFX);
        int i = (b - 1932) * 256 + threadIdx.x;   // < 458752
        if (i < 262144) {
            int which = i / 131072;       // 0=Ww, 1=Ws
            int w = i % 131072;
            int half = w / 65536;
            int r = w % 65536;
            int nt = r / 4096;
            int r2 = r % 4096;
            int q = r2 / 512;
            int l = (r2 % 512) >> 3, e = r2 & 7;
            int n = nt*16 + (l & 15);
            int k = q*32 + ((l >> 4) << 3) + e;
            const float* src = which ? Ws : Ww;
            float v = src[n*256 + k];
            u16 hi = bf16_hi(v);
            u16 o = half ? bf16_hi(v - bf16_f(hi)) : hi;
            (which ? WFW_S : WFW_W)[w] = o;
            return;
        }
        i -= 262144;
        if (i < 196608) {
            int w = i % 98304;
            int dir = i / 98304;
            int half = w / 49152;
            int r = w % 49152;
            int nt = r / 2048;
            int r2 = r % 2048;
            int q = r2 / 512;
            int l = (r2 % 512) >> 3, e = r2 & 7;
            int n = nt*16 + (l & 15);
            int k = q*32 + ((l >> 4) << 3) + e;
            const float* src = dir ? w_ih_b : w_ih_f;
            float v = src[n*128 + k];
            u16 hi = bf16_hi(v);
            WFX[i] = half ? bf16_hi(v - bf16_f(hi)) : hi;
            return;
        }
        return;
    }
    {
        // ---- section D: WFIHS = s_ih B-frags [dir2][half2][nt24][q8][l64][e8] ----
        u16* WFIHS = (u16*)(ws + OFF_W6);
        int i = (b - 3724) * 256 + threadIdx.x;   // < 393216
        int dir  = i / 196608;
        int w    = i % 196608;
        int half = w / 98304;
        int r    = w % 98304;
        int nt = r / 4096;
        int r2 = r % 4096;
        int q  = r2 / 512;
        int l  = (r2 % 512) >> 3, e = r2 & 7;
        int n = nt*16 + (l & 15);                 // row in [0,384): gate*128 + j
        int k = q*32 + ((l >> 4) << 3) + e;       // k in [0,256)
        const float* src = dir ? s_ih_b : s_ih_f;
        float v = src[n*256 + k];
        u16 hi = bf16_hi(v);
        WFIHS[i] = half ? bf16_hi(v - bf16_f(hi)) : hi;
    }
}

// ---------------- fused word pipeline (round-21 form; stable at ~197us) ----------
__global__ __launch_bounds__(768)
void gru_word_full(const int* __restrict__ X, const float* __restrict__ emb,
                   const u16* __restrict__ WFX, const u16* __restrict__ WFHH,
                   const float* __restrict__ b_ih_f, const float* __restrict__ b_ih_b,
                   const float* __restrict__ b_hh_f, const float* __restrict__ b_hh_b,
                   u16* __restrict__ houtp)
{
    const int bx = blockIdx.x;
    const int dir = bx >> 7;
    const int blk = bx & 127;
    const int seq0 = blk * 8;
    const int tid = threadIdx.x;
    const int lane = tid & 63;
    const int wid = tid >> 6;            // 0..11

    __shared__ float xp_lds[64 * XPLD];      // 98560 B (rows = s*8 + tt)
    __shared__ f32x4 uni4[2048];             // 32768 B union: a_pk (32 KB) / G (12.4 KB)
    __shared__ u16 h_pk[4 * HPLD];           // 4160 B (hi rows 0-7, lo rows 8-15)
    __shared__ int ids_s[8][64];             // 2048 B
    float* G = (float*)uni4;                 // [8][GLD] (hi+lo pre-summed)
    u16* a_pk = (u16*)uni4;                  // [8 mf][4 q][512] u16

    const int j = tid & 127;
    const int sg = tid >> 7;             // 0..3 gate threads (s = sg, sg+4)
    const bool gthread = tid < 512;
    const float* bih = dir ? b_ih_b : b_ih_f;
    const float* bhh = dir ? b_hh_b : b_hh_f;
    float bhr = 0.f, bhz = 0.f, bhn = 0.f;
    if (gthread) { bhr = bhh[j]; bhz = bhh[128 + j]; bhn = bhh[256 + j]; }

    const u16* WXbase = WFX + (long)dir * 98304;
    const u16* WHbase = WFHH + (long)dir * 98304;
    const int nt0 = wid*2, nt1 = wid*2 + 1;
    const int c0 = nt0*16 + (lane & 15);
    const int c1 = nt1*16 + (lane & 15);
    // gate-thread h_pk write decomposition for k = j
    const int qj = j >> 5, subkj = (j >> 3) & 3, ej = j & 7;

    for (int i = tid; i < 512; i += 768)
        ids_s[i >> 6][i & 63] = X[(long)(seq0 + (i >> 6))*64 + (i & 63)];
    for (int i = tid; i < 4*HPLD; i += 768) h_pk[i] = 0;
    __syncthreads();

    float hprev0 = 0.f, hprev1 = 0.f;
    for (int c = 0; c < 8; ++c) {
        asm volatile("" ::: "memory");   // no cross-chunk hoisting of weight loads
        // ---- load W_ih frags (this chunk only) ----
        sh8 xh0[4], xl0[4], xh1[4], xl1[4];
#pragma unroll
        for (int q = 0; q < 4; ++q) {
            xh0[q] = *(const sh8*)(WXbase + (nt0*4 + q)*512 + lane*8);
            xl0[q] = *(const sh8*)(WXbase + 49152 + (nt0*4 + q)*512 + lane*8);
            xh1[q] = *(const sh8*)(WXbase + (nt1*4 + q)*512 + lane*8);
            xl1[q] = *(const sh8*)(WXbase + 49152 + (nt1*4 + q)*512 + lane*8);
        }
        const float bv0 = bih[c0], bv1 = bih[c1];
        // ---- stage gathered embeddings: 2048 float4 items, paired hi/lo words ----
        // idx bits: [0]=cc2 [3:1]=rm(tt) [5:4]=subk [7:6]=q [10:8]=mfs(s)
        for (int idx = tid; idx < 2048; idx += 768) {
            int cc2 = idx & 1, rm = (idx >> 1) & 7, subk = (idx >> 4) & 3;
            int q = (idx >> 6) & 3, mfs = idx >> 8;
            int ts = c*8 + rm;
            int t = dir ? 63 - ts : ts;
            int kk = q*32 + subk*8 + cc2*4;
            int id = ids_s[mfs][t];
            float4 v = make_float4(0.f, 0.f, 0.f, 0.f);
            if (id != 0) v = *(const float4*)&emb[(long)id*128 + kk];
            u16 h0,l0,h1,l1,h2,l2,h3,l3;
            bf16_split(v.x,h0,l0); bf16_split(v.y,h1,l1);
            bf16_split(v.z,h2,l2); bf16_split(v.w,h3,l3);
            int lh = subk*16 + rm;
            int base = (mfs*4 + q)*512 + lh*8 + cc2*4;
            uint2 whi = make_uint2((u32)h0 | ((u32)h1 << 16), (u32)h2 | ((u32)h3 << 16));
            uint2 wlo = make_uint2((u32)l0 | ((u32)l1 << 16), (u32)l2 | ((u32)l3 << 16));
            *(uint2*)&a_pk[base]      = whi;
            *(uint2*)&a_pk[base + 64] = wlo;   // (lh+8)*8 - lh*8 = 64 u16
        }
        barrier_lds_only();
        // ---- xp MFMA: 8 m-frags -> xp_lds (+bias), half-dedup epilogue ----
#pragma unroll
        for (int mf = 0; mf < 8; ++mf) {
            f32x4 A0 = (f32x4){0.f,0.f,0.f,0.f};
            f32x4 A1 = (f32x4){0.f,0.f,0.f,0.f};
#pragma unroll
            for (int q = 0; q < 4; ++q) {
                sh8 a = *(const sh8*)&a_pk[(mf*4 + q)*512 + lane*8];
                A0 = __builtin_amdgcn_mfma_f32_16x16x32_bf16(a, xh0[q], A0, 0,0,0);
                A0 = __builtin_amdgcn_mfma_f32_16x16x32_bf16(a, xl0[q], A0, 0,0,0);
                A1 = __builtin_amdgcn_mfma_f32_16x16x32_bf16(a, xh1[q], A1, 0,0,0);
                A1 = __builtin_amdgcn_mfma_f32_16x16x32_bf16(a, xl1[q], A1, 0,0,0);
            }
            float g0[4], g1[4];
#pragma unroll
            for (int r = 0; r < 4; ++r) {
                g0[r] = A0[r] + __shfl_xor(A0[r], 32);
                g1[r] = A1[r] + __shfl_xor(A1[r], 32);
            }
            if ((lane >= 32) == (mf & 1)) {
                int row = mf*8 + ((lane >> 4) & 1)*4;
#pragma unroll
                for (int r = 0; r < 4; ++r) {
                    xp_lds[(row+r)*XPLD + c0] = g0[r] + bv0;
                    xp_lds[(row+r)*XPLD + c1] = g1[r] + bv1;
                }
            }
        }
        barrier_lds_only();   // xp ready; a_pk region free -> G
        asm volatile("" ::: "memory");
        // ---- load W_hh frags ----
        sh8 wh0[4], wl0[4], wh1[4], wl1[4];
#pragma unroll
        for (int q = 0; q < 4; ++q) {
            wh0[q] = *(const sh8*)(WHbase + (nt0*4 + q)*512 + lane*8);
            wl0[q] = *(const sh8*)(WHbase + 49152 + (nt0*4 + q)*512 + lane*8);
            wh1[q] = *(const sh8*)(WHbase + (nt1*4 + q)*512 + lane*8);
            wl1[q] = *(const sh8*)(WHbase + 49152 + (nt1*4 + q)*512 + lane*8);
        }
        // ---- 8 recurrence steps ----
        for (int tt = 0; tt < 8; ++tt) {
            const int ts = c*8 + tt;
            const int t = dir ? 63 - ts : ts;
            f32x4 acc0 = (f32x4){0.f,0.f,0.f,0.f};
            f32x4 acc1 = (f32x4){0.f,0.f,0.f,0.f};
#pragma unroll
            for (int q = 0; q < 4; ++q) {
                sh8 hp = *(const sh8*)&h_pk[q*HPLD + lane*8];
                acc0 = __builtin_amdgcn_mfma_f32_16x16x32_bf16(hp, wh0[q], acc0, 0,0,0);
                acc0 = __builtin_amdgcn_mfma_f32_16x16x32_bf16(hp, wl0[q], acc0, 0,0,0);
                acc1 = __builtin_amdgcn_mfma_f32_16x16x32_bf16(hp, wh1[q], acc1, 0,0,0);
                acc1 = __builtin_amdgcn_mfma_f32_16x16x32_bf16(hp, wl1[q], acc1, 0,0,0);
            }
            // summed-G: hi row s (lanes 0-31) + lo row s+8 (lanes 32-63) share a reg
            {
                float sg0[4], sg1[4];
#pragma unroll
                for (int r = 0; r < 4; ++r) {
                    sg0[r] = acc0[r] + __shfl_xor(acc0[r], 32);
                    sg1[r] = acc1[r] + __shfl_xor(acc1[r], 32);
                }
                if (lane < 32) {
                    const int col16 = lane & 15;
                    const int row0  = (lane >> 4) << 2;   // 0 or 4
#pragma unroll
                    for (int r = 0; r < 4; ++r) {
                        G[(row0+r)*GLD + nt0*16 + col16] = sg0[r];
                        G[(row0+r)*GLD + nt1*16 + col16] = sg1[r];
                    }
                }
            }
            barrier_lds_only();
            if (gthread) {
#pragma unroll
                for (int si = 0; si < 2; ++si) {
                    const int s = sg + si*4;
                    float gr  = G[s*GLD + j]       + bhr;
                    float gz  = G[s*GLD + 128 + j] + bhz;
                    float gnh = G[s*GLD + 256 + j] + bhn;
                    const float* xrow = &xp_lds[(s*8 + tt)*XPLD];
                    float r  = sigmoidf_(xrow[j] + gr);
                    float z  = sigmoidf_(xrow[128 + j] + gz);
                    float nv = tanhf_(xrow[256 + j] + r * gnh);
                    float hold = si ? hprev1 : hprev0;
                    float hnew = (1.f - z) * nv + z * hold;
                    if (si) hprev1 = hnew; else hprev0 = hnew;
                    u16 hh, hl; bf16_split(hnew, hh, hl);
                    // paired u32 writes: even j handles the hi row pair, odd j the lo
                    u16 ohh = (u16)__shfl_xor((int)hh, 1);
                    u16 ohl = (u16)__shfl_xor((int)hl, 1);
                    const long tbase = ((long)(seq0 + s)*64 + t)*512 + dir*128;
                    if ((j & 1) == 0) {
                        u32 w = (u32)hh | ((u32)ohh << 16);
                        *(u32*)&h_pk[qj*HPLD + (subkj*16 + s)*8 + ej] = w;
                        *(u32*)&houtp[tbase + j] = w;
                    } else {
                        u32 w = (u32)ohl | ((u32)hl << 16);
                        *(u32*)&h_pk[qj*HPLD + (subkj*16 + s + 8)*8 + (ej - 1)] = w;
                        *(u32*)&houtp[tbase + 256 + (j - 1)] = w;
                    }
                }
            }
            barrier_lds_only();
        }
    }
}

// ---------------- fused attention: score MFMA + tanh/ctx + softmax + pool ----------
// PACKED=true: A = hout u16 [sent][t][hilo][k256]; staged via uint4 decode-permute.
// PACKED=false: A is fp32 [M][256], staged with bf16 split (sentence level).
// CLS=true: fused classifier (r23).
template<int T, bool PACKED, bool CLS>
__global__ __launch_bounds__(1024)
void attn_fused(const float* __restrict__ A, const u16* __restrict__ WF,
                const float* __restrict__ bias, const float* __restrict__ ctx,
                float* __restrict__ outp,
                const float* __restrict__ Wc, const float* __restrict__ bc)
{
    __shared__ u16 a_pk[8][8][512];    // 64 KB
    __shared__ float pscore[8][8][17];
    __shared__ float aw[64];
    __shared__ float red[4][256];
    __shared__ float docv[2][256];     // CLS only (2 KB)
    const int tid = threadIdx.x;
    const int lane = tid & 63;
    const int wid = tid >> 6;   // 0..15
    const int m0 = blockIdx.x * 64;

    sh8 bh[8], bl[8];
#pragma unroll
    for (int q = 0; q < 8; ++q) {
        bh[q] = *(const sh8*)(WF + (wid*8 + q)*512 + lane*8);
        bl[q] = *(const sh8*)(WF + 65536 + (wid*8 + q)*512 + lane*8);
    }
    const int colg = wid*16 + (lane & 15);
    const float bwv = bias[colg];
    const float cxv = ctx[colg];

    if (PACKED) {
        // r24: uint4 staging — src (k>>1 over c2) and dst (idx) both contiguous
        const u32* src32 = (const u32*)A + (long)blockIdx.x * 16384;
        u32* dst = (u32*)a_pk;
        for (int idx4 = tid; idx4 < 4096; idx4 += 1024) {
            int idx = idx4 << 2;
            int mf = idx >> 11, q = (idx >> 8) & 7, l = (idx >> 2) & 63;
            int row16 = l & 15, hilo = row16 >> 3, rm = row16 & 7;
            int t = mf*8 + rm;
            int kb2 = q*16 + (l >> 4)*4;       // (kbase>>1), multiple of 4
            *(uint4*)&dst[idx] = *(const uint4*)&src32[(t*2 + hilo)*128 + kb2];
        }
    } else {
        for (int idx = tid; idx < 8192; idx += 1024) {
            int row = idx >> 7;            // 0..63
            int k   = (idx & 127) << 1;
            float2 v = *(const float2*)&A[(long)(m0 + row)*256 + k];
            u16 h0,l0,h1,l1; bf16_split(v.x,h0,l0); bf16_split(v.y,h1,l1);
            int mf = row >> 3, rm = row & 7;
            int q = k >> 5;
            int lh = (((k & 31) >> 3) << 4) | rm;
            int e = k & 7;
            *(u32*)&a_pk[mf][q][lh*8 + e]     = (u32)h0 | ((u32)h1 << 16);
            *(u32*)&a_pk[mf][q][(lh+8)*8 + e] = (u32)l0 | ((u32)l1 << 16);
        }
    }
    __syncthreads();

#pragma unroll
    for (int mf = 0; mf < 8; ++mf) {
        f32x4 acc = (f32x4){0.f,0.f,0.f,0.f};
#pragma unroll
        for (int q = 0; q < 8; ++q) {
            sh8 a = *(const sh8*)&a_pk[mf][q][lane*8];
            acc = __builtin_amdgcn_mfma_f32_16x16x32_bf16(a, bh[q], acc, 0,0,0);
            acc = __builtin_amdgcn_mfma_f32_16x16x32_bf16(a, bl[q], acc, 0,0,0);
        }
        float g[4];
#pragma unroll
        for (int r = 0; r < 4; ++r) g[r] = acc[r] + __shfl_xor(acc[r], 32);
        if ((lane >= 32) == (mf & 1)) {    // half-dedup: each half handles 4 mf
            float p[4];
#pragma unroll
            for (int r = 0; r < 4; ++r) p[r] = tanhf_(g[r] + bwv) * cxv;
#pragma unroll
            for (int r = 0; r < 4; ++r) {
                p[r] += __shfl_xor(p[r], 1);
                p[r] += __shfl_xor(p[r], 2);
                p[r] += __shfl_xor(p[r], 4);
                p[r] += __shfl_xor(p[r], 8);
            }
            if ((lane & 15) == 0) {
#pragma unroll
                for (int r = 0; r < 4; ++r)
                    pscore[mf][((lane >> 4) & 1)*4 + r][wid] = p[r];
            }
        }
    }
    __syncthreads();

    // softmax over T (per sentence group) in wave 0
    if (tid < 64) {
        float sc = 0.f;
#pragma unroll
        for (int w = 0; w < 16; ++w) sc += pscore[tid >> 3][tid & 7][w];
        float mx = sc;
#pragma unroll
        for (int m = 1; m < T; m <<= 1) mx = fmaxf(mx, __shfl_xor(mx, m));
        float e = __expf(sc - mx);
        float den = e;
#pragma unroll
        for (int m = 1; m < T; m <<= 1) den += __shfl_xor(den, m);
        aw[tid] = __fdividef(e, den);
    }
    __syncthreads();

    // weighted sum: h reconstructed from a_pk (hi+lo); thread -> (d-pair, t-group)
    if (tid < 512) {
        const int dp = (tid & 127) << 1;
        const int tg = tid >> 7;          // 0..3
        const int q = dp >> 5, lhb = ((dp & 31) >> 3) << 4, e = dp & 7;
        float acc0 = 0.f, acc1 = 0.f;
#pragma unroll
        for (int i = 0; i < 16; ++i) {
            int t = tg*16 + i;
            int mf = t >> 3, rm = t & 7;
            const u16* base = &a_pk[mf][q][(lhb | rm)*8 + e];
            u32 hh = *(const u32*)base;
            u32 ll = *(const u32*)(base + 64);
            float h0 = bf16_f((u16)hh) + bf16_f((u16)ll);
            float h1 = bf16_f((u16)(hh >> 16)) + bf16_f((u16)(ll >> 16));
            float w = aw[t];
            acc0 = fmaf(w, h0, acc0);
            acc1 = fmaf(w, h1, acc1);
        }
        red[tg][dp] = acc0; red[tg][dp + 1] = acc1;
    }
    __syncthreads();
    if (T == 64) {
        if (tid < 256)
            outp[(long)blockIdx.x*256 + tid] = red[0][tid] + red[1][tid] + red[2][tid] + red[3][tid];
    } else if (!CLS) {
        if (tid < 512) {
            int sent = tid >> 8, dd = tid & 255;
            outp[((long)blockIdx.x*2 + sent)*256 + dd] = red[sent*2][dd] + red[sent*2 + 1][dd];
        }
    } else {
        // classifier fusion: docv -> logits, write final output directly
        if (tid < 512) {
            int sent = tid >> 8, dd = tid & 255;
            docv[sent][dd] = red[sent*2][dd] + red[sent*2 + 1][dd];
        }
        __syncthreads();
        if (tid < 20) {
            int s = tid / 10, c = tid % 10;
            float acc = bc[c];
            const float4* wp = (const float4*)&Wc[c*256];
            const float4* dv = (const float4*)&docv[s][0];
#pragma unroll 8
            for (int d = 0; d < 64; ++d) {
                float4 a = dv[d], w = wp[d];
                acc = fmaf(a.x, w.x, fmaf(a.y, w.y, fmaf(a.z, w.z, fmaf(a.w, w.w, acc))));
            }
            outp[(blockIdx.x*2 + s)*10 + c] = acc;
        }
    }
}

// ---------------- sentence pipeline: xp MFMA + GRU recurrence (round-24) ----------
// Replaces gemm_xp + gru_fused. Block = (dir, doc): 64 blocks, 512 threads (8 waves).
// Phase 1: stage this doc's 32 sent vectors (fp32 [32][256]) into MFMA A-frags
//   (hi/lo split), word-staging pattern with 4 m-frags (8 t hi rows + 8 lo), q=8.
// Phase 2: xp = sents x s_ih^T (+bias) via MFMA; wave w owns nt {w, w+8, w+16} of 24;
//   per nt: 1536/64 MFMA; epilogue identical to word xp (shfl_xor(32) hi+lo merge,
//   half-dedup write). Output xp_lds[32][385] fp32 — no global round-trip.
// Phase 3: r22 recurrence (hoisted fp32 weights) reading xp from LDS.
__global__ __launch_bounds__(512)
void gru_sent(const float* __restrict__ sents, const u16* __restrict__ WFIHS,
              const float* __restrict__ bih_s, const float4* __restrict__ whh4,
              const float* __restrict__ bhh, float* __restrict__ hout)
{
    const int bx = blockIdx.x;
    const int dir = bx >> 5;
    const int doc = bx & 31;
    const int tid = threadIdx.x;
    const int lane = tid & 63;
    const int wid = tid >> 6;            // 0..7

    __shared__ float xp_lds[32 * XPLD];  // 49280 B
    __shared__ u16 a_pk[4 * 8 * 512];    // 32768 B: [mf4][q8][l64][e8]
    __shared__ float h_lds[128];

    for (int i = tid; i < 128; i += 512) h_lds[i] = 0.f;

    // ---- phase 1: stage sents rows -> A-frags (2048 float4 items, 4 iters) ----
    // idx bits: [0]=cc2 [3:1]=rm [5:4]=subk [8:6]=q [10:9]=mf ; t = mf*8+rm
    for (int idx = tid; idx < 2048; idx += 512) {
        int cc2 = idx & 1, rm = (idx >> 1) & 7, subk = (idx >> 4) & 3;
        int q = (idx >> 6) & 7, mf = (idx >> 9) & 3;
        int t = mf*8 + rm;
        int kk = q*32 + subk*8 + cc2*4;
        float4 v = *(const float4*)&sents[(long)(doc*32 + t)*256 + kk];
        u16 h0,l0,h1,l1,h2,l2,h3,l3;
        bf16_split(v.x,h0,l0); bf16_split(v.y,h1,l1);
        bf16_split(v.z,h2,l2); bf16_split(v.w,h3,l3);
        int lh = subk*16 + rm;
        int base = (mf*8 + q)*512 + lh*8 + cc2*4;
        uint2 whi = make_uint2((u32)h0 | ((u32)h1 << 16), (u32)h2 | ((u32)h3 << 16));
        uint2 wlo = make_uint2((u32)l0 | ((u32)l1 << 16), (u32)l2 | ((u32)l3 << 16));
        *(uint2*)&a_pk[base]      = whi;
        *(uint2*)&a_pk[base + 64] = wlo;
    }
    barrier_lds_only();

    // ---- phase 2: xp MFMA, wave w -> nt {w, w+8, w+16} ----
    const u16* WFbase = WFIHS + (long)dir * 196608;
#pragma unroll 1
    for (int ni = 0; ni < 3; ++ni) {
        const int nt = wid + ni*8;
        sh8 wh[8], wl[8];
#pragma unroll
        for (int q = 0; q < 8; ++q) {
            wh[q] = *(const sh8*)(WFbase + (nt*8 + q)*512 + lane*8);
            wl[q] = *(const sh8*)(WFbase + 98304 + (nt*8 + q)*512 + lane*8);
        }
        const int col16 = lane & 15;
        const float bv = bih_s[dir*384 + nt*16 + col16];
        f32x4 A0 = (f32x4){0.f,0.f,0.f,0.f};
        f32x4 A1 = (f32x4){0.f,0.f,0.f,0.f};
        f32x4 A2 = (f32x4){0.f,0.f,0.f,0.f};
        f32x4 A3 = (f32x4){0.f,0.f,0.f,0.f};
#pragma unroll
        for (int q = 0; q < 8; ++q) {
            sh8 a0 = *(const sh8*)&a_pk[(0*8 + q)*512 + lane*8];
            sh8 a1 = *(const sh8*)&a_pk[(1*8 + q)*512 + lane*8];
            sh8 a2 = *(const sh8*)&a_pk[(2*8 + q)*512 + lane*8];
            sh8 a3 = *(const sh8*)&a_pk[(3*8 + q)*512 + lane*8];
            A0 = __builtin_amdgcn_mfma_f32_16x16x32_bf16(a0, wh[q], A0, 0,0,0);
            A0 = __builtin_amdgcn_mfma_f32_16x16x32_bf16(a0, wl[q], A0, 0,0,0);
            A1 = __builtin_amdgcn_mfma_f32_16x16x32_bf16(a1, wh[q], A1, 0,0,0);
            A1 = __builtin_amdgcn_mfma_f32_16x16x32_bf16(a1, wl[q], A1, 0,0,0);
            A2 = __builtin_amdgcn_mfma_f32_16x16x32_bf16(a2, wh[q], A2, 0,0,0);
            A2 = __builtin_amdgcn_mfma_f32_16x16x32_bf16(a2, wl[q], A2, 0,0,0);
            A3 = __builtin_amdgcn_mfma_f32_16x16x32_bf16(a3, wh[q], A3, 0,0,0);
            A3 = __builtin_amdgcn_mfma_f32_16x16x32_bf16(a3, wl[q], A3, 0,0,0);
        }
#pragma unroll
        for (int mf = 0; mf < 4; ++mf) {
            f32x4 A = (mf==0) ? A0 : (mf==1) ? A1 : (mf==2) ? A2 : A3;
            float g[4];
#pragma unroll
            for (int r = 0; r < 4; ++r) g[r] = A[r] + __shfl_xor(A[r], 32);
            if ((lane >= 32) == (mf & 1)) {
                int row = mf*8 + ((lane >> 4) & 1)*4;
#pragma unroll
                for (int r = 0; r < 4; ++r)
                    xp_lds[(row+r)*XPLD + nt*16 + col16] = g[r] + bv;
            }
        }
    }
    barrier_lds_only();
    asm volatile("" ::: "memory");   // keep recurrence weight loads below xp phase

    // ---- phase 3: recurrence (r22 form, xp from LDS) ----
    const int kq = tid & 3;
    const int j  = tid >> 2;
    const float4* W = whh4 + (long)dir * 12288;
    const float bhr = bhh[dir*384 + j];
    const float bhz = bhh[dir*384 + 128 + j];
    const float bhn = bhh[dir*384 + 256 + j];
    float4 w0r[8], w1r[8], w2r[8];
#pragma unroll
    for (int ii = 0; ii < 8; ++ii) {
        const int k4 = kq + (ii << 2);
        w0r[ii] = W[k4*384 + j];
        w1r[ii] = W[k4*384 + 128 + j];
        w2r[ii] = W[k4*384 + 256 + j];
    }

    for (int ts = 0; ts < 32; ++ts) {
        const int t = dir ? (31 - ts) : ts;
        float a0 = 0.f, a1 = 0.f, a2 = 0.f;
#pragma unroll
        for (int ii = 0; ii < 8; ++ii) {
            const int k4 = kq + (ii << 2);
            float4 w0 = w0r[ii];
            float4 w1 = w1r[ii];
            float4 w2 = w2r[ii];
            float4 h4 = *(const float4*)&h_lds[k4 << 2];
            a0 = fmaf(w0.x,h4.x, fmaf(w0.y,h4.y, fmaf(w0.z,h4.z, fmaf(w0.w,h4.w, a0))));
            a1 = fmaf(w1.x,h4.x, fmaf(w1.y,h4.y, fmaf(w1.z,h4.z, fmaf(w1.w,h4.w, a1))));
            a2 = fmaf(w2.x,h4.x, fmaf(w2.y,h4.y, fmaf(w2.z,h4.z, fmaf(w2.w,h4.w, a2))));
        }
        a0 += __shfl_xor(a0, 1); a0 += __shfl_xor(a0, 2);
        a1 += __shfl_xor(a1, 1); a1 += __shfl_xor(a1, 2);
        a2 += __shfl_xor(a2, 1); a2 += __shfl_xor(a2, 2);
        __syncthreads();
        if (kq == 0) {
            const float* xr = &xp_lds[t*XPLD];
            float r = sigmoidf_(xr[j]       + a0 + bhr);
            float z = sigmoidf_(xr[128 + j] + a1 + bhz);
            float nv = tanhf_(xr[256 + j] + r * (a2 + bhn));
            float hold = h_lds[j];
            float hnew = (1.f - z) * nv + z * hold;
            h_lds[j] = hnew;
            hout[((long)(doc*32) + t)*256*1 + (long)t*0 + ((long)(doc*32 + t))*0] = 0.f; // (dead; see below)
        }
        __syncthreads();
        if (kq == 0) {
            // separate store after barrier is unnecessary; fold into above — kept simple:
        }
    }
    // NOTE: the hout store is inside the kq==0 block below (rewritten cleanly):
}

// Clean version of gru_sent without the botched store above is used instead.
__global__ __launch_bounds__(512)
void gru_sent2(const float* __restrict__ sents, const u16* __restrict__ WFIHS,
               const float* __restrict__ bih_s, const float4* __restrict__ whh4,
               const float* __restrict__ bhh, float* __restrict__ hout)
{
    const int bx = blockIdx.x;
    const int dir = bx >> 5;
    const int doc = bx & 31;
    const int tid = threadIdx.x;
    const int lane = tid & 63;
    const int wid = tid >> 6;            // 0..7

    __shared__ float xp_lds[32 * XPLD];  // 49280 B
    __shared__ u16 a_pk[4 * 8 * 512];    // 32768 B: [mf4][q8][l64][e8]
    __shared__ float h_lds[128];

    for (int i = tid; i < 128; i += 512) h_lds[i] = 0.f;

    // ---- phase 1: stage sents rows -> A-frags ----
    for (int idx = tid; idx < 2048; idx += 512) {
        int cc2 = idx & 1, rm = (idx >> 1) & 7, subk = (idx >> 4) & 3;
        int q = (idx >> 6) & 7, mf = (idx >> 9) & 3;
        int t = mf*8 + rm;
        int kk = q*32 + subk*8 + cc2*4;
        float4 v = *(const float4*)&sents[(long)(doc*32 + t)*256 + kk];
        u16 h0,l0,h1,l1,h2,l2,h3,l3;
        bf16_split(v.x,h0,l0); bf16_split(v.y,h1,l1);
        bf16_split(v.z,h2,l2); bf16_split(v.w,h3,l3);
        int lh = subk*16 + rm;
        int base = (mf*8 + q)*512 + lh*8 + cc2*4;
        uint2 whi = make_uint2((u32)h0 | ((u32)h1 << 16), (u32)h2 | ((u32)h3 << 16));
        uint2 wlo = make_uint2((u32)l0 | ((u32)l1 << 16), (u32)l2 | ((u32)l3 << 16));
        *(uint2*)&a_pk[base]      = whi;
        *(uint2*)&a_pk[base + 64] = wlo;
    }
    barrier_lds_only();

    // ---- phase 2: xp MFMA ----
    const u16* WFbase = WFIHS + (long)dir * 196608;
#pragma unroll 1
    for (int ni = 0; ni < 3; ++ni) {
        const int nt = wid + ni*8;
        sh8 wh[8], wl[8];
#pragma unroll
        for (int q = 0; q < 8; ++q) {
            wh[q] = *(const sh8*)(WFbase + (nt*8 + q)*512 + lane*8);
            wl[q] = *(const sh8*)(WFbase + 98304 + (nt*8 + q)*512 + lane*8);
        }
        const int col16 = lane & 15;
        const float bv = bih_s[dir*384 + nt*16 + col16];
        f32x4 A0 = (f32x4){0.f,0.f,0.f,0.f};
        f32x4 A1 = (f32x4){0.f,0.f,0.f,0.f};
        f32x4 A2 = (f32x4){0.f,0.f,0.f,0.f};
        f32x4 A3 = (f32x4){0.f,0.f,0.f,0.f};
#pragma unroll
        for (int q = 0; q < 8; ++q) {
            sh8 a0 = *(const sh8*)&a_pk[(0*8 + q)*512 + lane*8];
            sh8 a1 = *(const sh8*)&a_pk[(1*8 + q)*512 + lane*8];
            sh8 a2 = *(const sh8*)&a_pk[(2*8 + q)*512 + lane*8];
            sh8 a3 = *(const sh8*)&a_pk[(3*8 + q)*512 + lane*8];
            A0 = __builtin_amdgcn_mfma_f32_16x16x32_bf16(a0, wh[q], A0, 0,0,0);
            A0 = __builtin_amdgcn_mfma_f32_16x16x32_bf16(a0, wl[q], A0, 0,0,0);
            A1 = __builtin_amdgcn_mfma_f32_16x16x32_bf16(a1, wh[q], A1, 0,0,0);
            A1 = __builtin_amdgcn_mfma_f32_16x16x32_bf16(a1, wl[q], A1, 0,0,0);
            A2 = __builtin_amdgcn_mfma_f32_16x16x32_bf16(a2, wh[q], A2, 0,0,0);
            A2 = __builtin_amdgcn_mfma_f32_16x16x32_bf16(a2, wl[q], A2, 0,0,0);
            A3 = __builtin_amdgcn_mfma_f32_16x16x32_bf16(a3, wh[q], A3, 0,0,0);
            A3 = __builtin_amdgcn_mfma_f32_16x16x32_bf16(a3, wl[q], A3, 0,0,0);
        }
#pragma unroll
        for (int mf = 0; mf < 4; ++mf) {
            f32x4 A = (mf==0) ? A0 : (mf==1) ? A1 : (mf==2) ? A2 : A3;
            float g[4];
#pragma unroll
            for (int r = 0; r < 4; ++r) g[r] = A[r] + __shfl_xor(A[r], 32);
            if ((lane >= 32) == (mf & 1)) {
                int row = mf*8 + ((lane >> 4) & 1)*4;
#pragma unroll
                for (int r = 0; r < 4; ++r)
                    xp_lds[(row+r)*XPLD + nt*16 + col16] = g[r] + bv;
            }
        }
    }
    barrier_lds_only();
    asm volatile("" ::: "memory");   // keep recurrence weight loads below xp phase

    // ---- phase 3: recurrence (hoisted weights; xp from LDS) ----
    const int kq = tid & 3;
    const int j  = tid >> 2;
    const float4* W = whh4 + (long)dir * 12288;
    const float bhr = bhh[dir*384 + j];
    const float bhz = bhh[dir*384 + 128 + j];
    const float bhn = bhh[dir*384 + 256 + j];
    float4 w0r[8], w1r[8], w2r[8];
#pragma unroll
    for (int ii = 0; ii < 8; ++ii) {
        const int k4 = kq + (ii << 2);
        w0r[ii] = W[k4*384 + j];
        w1r[ii] = W[k4*384 + 128 + j];
        w2r[ii] = W[k4*384 + 256 + j];
    }

    for (int ts = 0; ts < 32; ++ts) {
        const int t = dir ? (31 - ts) : ts;
        float a0 = 0.f, a1 = 0.f, a2 = 0.f;
#pragma unroll
        for (int ii = 0; ii < 8; ++ii) {
            const int k4 = kq + (ii << 2);
            float4 w0 = w0r[ii];
            float4 w1 = w1r[ii];
            float4 w2 = w2r[ii];
            float4 h4 = *(const float4*)&h_lds[k4 << 2];
            a0 = fmaf(w0.x,h4.x, fmaf(w0.y,h4.y, fmaf(w0.z,h4.z, fmaf(w0.w,h4.w, a0))));
            a1 = fmaf(w1.x,h4.x, fmaf(w1.y,h4.y, fmaf(w1.z,h4.z, fmaf(w1.w,h4.w, a1))));
            a2 = fmaf(w2.x,h4.x, fmaf(w2.y,h4.y, fmaf(w2.z,h4.z, fmaf(w2.w,h4.w, a2))));
        }
        a0 += __shfl_xor(a0, 1); a0 += __shfl_xor(a0, 2);
        a1 += __shfl_xor(a1, 1); a1 += __shfl_xor(a1, 2);
        a2 += __shfl_xor(a2, 1); a2 += __shfl_xor(a2, 2);
        __syncthreads();
        if (kq == 0) {
            const float* xr = &xp_lds[t*XPLD];
            float r = sigmoidf_(xr[j]       + a0 + bhr);
            float z = sigmoidf_(xr[128 + j] + a1 + bhz);
            float nv = tanhf_(xr[256 + j] + r * (a2 + bhn));
            float hold = h_lds[j];
            float hnew = (1.f - z) * nv + z * hold;
            h_lds[j] = hnew;
            hout[((long)(doc*32 + t))*256 + dir*128 + j] = hnew;
        }
        __syncthreads();
    }
}

extern "C" void kernel_launch(void* const* d_in, const int* in_sizes, int n_in,
                              void* d_out, int out_size, void* d_ws, size_t ws_size,
                              hipStream_t stream) {
    const int*   X       = (const int*)  d_in[0];
    const float* emb     = (const float*)d_in[1];
    const float* w_ih_f  = (const float*)d_in[2];
    const float* w_hh_f  = (const float*)d_in[3];
    const float* b_ih_f  = (const float*)d_in[4];
    const float* b_hh_f  = (const float*)d_in[5];
    const float* w_ih_b  = (const float*)d_in[6];
    const float* w_hh_b  = (const float*)d_in[7];
    const float* b_ih_b  = (const float*)d_in[8];
    const float* b_hh_b  = (const float*)d_in[9];
    const float* Ww      = (const float*)d_in[10];
    const float* bw      = (const float*)d_in[11];
    const float* ctx_w   = (const float*)d_in[12];
    const float* s_ih_f  = (const float*)d_in[13];
    const float* s_hh_f  = (const float*)d_in[14];
    const float* sb_ih_f = (const float*)d_in[15];
    const float* sb_hh_f = (const float*)d_in[16];
    const float* s_ih_b  = (const float*)d_in[17];
    const float* s_hh_b  = (const float*)d_in[18];
    const float* sb_ih_b = (const float*)d_in[19];
    const float* sb_hh_b = (const float*)d_in[20];
    const float* Ws      = (const float*)d_in[21];
    const float* bs      = (const float*)d_in[22];
    const float* ctx_s   = (const float*)d_in[23];
    const float* Wc      = (const float*)d_in[24];
    const float* bc      = (const float*)d_in[25];
    float* ws  = (float*)d_ws;
    float* out = (float*)d_out;

    if (ws_size < (size_t)WS_FLOATS * 4) return;   // fail cleanly if scratch too small

    // 1. weight prep (4 sections incl. new WFIHS; WIHT_S deleted)
    prep_all<<<5260, 256, 0, stream>>>(s_ih_f, s_ih_b, w_ih_f, w_ih_b,
                                       w_hh_f, w_hh_b, s_hh_f, s_hh_b,
                                       b_ih_f, b_ih_b, sb_ih_f, sb_ih_b,
                                       b_hh_f, b_hh_b, sb_hh_f, sb_hh_b,
                                       Ww, Ws, ws);

    // 2. fused word pipeline
    gru_word_full<<<256, 768, 0, stream>>>(
        X, emb, (const u16*)(ws + OFF_WFX), (const u16*)(ws + OFF_WFHH),
        b_ih_f, b_ih_b, b_hh_f, b_hh_b, (u16*)(ws + OFF_HW));

    // 3. fused word attention -> sents
    attn_fused<64, true, false><<<1024, 1024, 0, stream>>>(
        ws + OFF_HW, (const u16*)(ws + OFF_WFW_W), bw, ctx_w, ws + OFF_SENTS,
        nullptr, nullptr);

    // 4. sentence pipeline: xp MFMA + GRU fused (gemm_xp launch deleted)
    gru_sent2<<<64, 512, 0, stream>>>(
        ws + OFF_SENTS, (const u16*)(ws + OFF_W6), ws + OFF_BIH_S,
        (const float4*)(ws + OFF_W6) + 4*12288, ws + OFF_BHH_S, ws + OFF_HS);

    // 5. fused sentence attention + classifier -> logits
    attn_fused<32, false, true><<<16, 1024, 0, stream>>>(
        ws + OFF_HS, (const u16*)(ws + OFF_WFW_S), bs, ctx_s, out, Wc, bc);
}

// Round 11
// 307.342 us; speedup vs baseline: 1.3908x; 1.0046x over previous
//
#include <hip/hip_runtime.h>
#include <hip/hip_bf16.h>
#include <math.h>

// Problem constants
#define Bd 32
#define Sd 32
#define Ld 64
#define Ed 128
#define Hd 128
#define MW 65536   // B*S*L tokens
#define MS 1024    // B*S sentences

// ws layout (float offsets)
#define OFF_WIHT_S   0          // (dead since r24)
#define OFF_WFW_W    196608     // 131072 u16: word attn Ww B-frags hi/lo
#define OFF_WFW_S    262144     // 131072 u16: sent attn Ws B-frags hi/lo
#define OFF_W6       327680     // sets 0-3 region holds WFIHS frags (u16); sets 4,5: sentence GRU fp32
#define OFF_BIH_W    622592     // (unused, kept)
#define OFF_BIH_S    623360
#define OFF_BHH_W    624128     // (unused, kept)
#define OFF_BHH_S    624896
#define OFF_WFX      625664     // 196608 u16: word xp w_ih B-frags [dir][half][nt24][q4][l][e]
#define OFF_HW       723968     // 1024 sents x [t64][hilo2][k256] u16 = 33.5M u16
#define OFF_SENTS    17763328   // 1024 x 256
#define OFF_XP_S     18025472   // (dead since r24)
#define OFF_HS       18811904   // 1024 x 256
#define OFF_DOC      19078144   // (dead since r23)
#define OFF_WFHH     19086336   // 196608 u16: W_hh MFMA B-frags hi/lo
#define WS_FLOATS    19184640   // 76.7 MB

typedef __attribute__((ext_vector_type(8))) short sh8;
typedef __attribute__((ext_vector_type(4))) float f32x4;
typedef unsigned short u16;
typedef unsigned int u32;

#define GLD  388   // G stride, 8 rows (seqs 0-7, hi+lo pre-summed)
#define XPLD 385   // xp_lds stride (mod 32 = 1 -> banks spread)
#define HPLD 520   // h_pk per-q stride in u16 (q-pad spreads banks)

// Raw workgroup barrier: waits LDS/shfl (lgkmcnt) only, deliberately NOT vmcnt
// (hout stores / in-flight staging gathers are not drained — the gather issued
// before the barrier is consumed after it, AITER-style).
__device__ __forceinline__ void barrier_lds_only() {
    asm volatile("s_waitcnt lgkmcnt(0)\n\ts_barrier" ::: "memory");
}

__device__ __forceinline__ float sigmoidf_(float x) {
    return __fdividef(1.0f, 1.0f + __expf(-x));
}
__device__ __forceinline__ float tanhf_(float x) {
    float t = __expf(-2.0f * fabsf(x));
    float r = __fdividef(1.0f - t, 1.0f + t);
    return copysignf(r, x);
}
__device__ __forceinline__ u16 bf16_hi(float f) {
    u32 x = __float_as_uint(f);
    return (u16)((x + 0x7fffu + ((x >> 16) & 1u)) >> 16);
}
__device__ __forceinline__ float bf16_f(u16 u) { return __uint_as_float(((u32)u) << 16); }
__device__ __forceinline__ void bf16_split(float f, u16& hi, u16& lo) {
    hi = bf16_hi(f);
    lo = bf16_hi(f - bf16_f(hi));
}

// ---------------- fused weight prep (1 launch, 4 sections) ----------------
__global__ void prep_all(const float* __restrict__ s_ih_f, const float* __restrict__ s_ih_b,
                         const float* __restrict__ w_ih_f, const float* __restrict__ w_ih_b,
                         const float* __restrict__ w_hh_f, const float* __restrict__ w_hh_b,
                         const float* __restrict__ s_hh_f, const float* __restrict__ s_hh_b,
                         const float* __restrict__ b_ih_f, const float* __restrict__ b_ih_b,
                         const float* __restrict__ sb_ih_f, const float* __restrict__ sb_ih_b,
                         const float* __restrict__ b_hh_f, const float* __restrict__ b_hh_b,
                         const float* __restrict__ sb_hh_f, const float* __restrict__ sb_hh_b,
                         const float* __restrict__ Ww, const float* __restrict__ Ws,
                         float* __restrict__ ws)
{
    const int b = blockIdx.x;
    if (b < 1164) {
        int i = b * 256 + threadIdx.x;
        if (i < 294912) {  // W6 — only sets 4,5 live (sets 0-3 region = WFIHS, section D)
            int set = i / 49152;
            if (set < 4) return;
            int rem = i % 49152;
            int k4 = rem / 1536, r2 = rem % 1536, g = r2 >> 2, sub = r2 & 3;
            const float* w = (set==4) ? s_hh_f : s_hh_b;
            ws[OFF_W6 + i] = w[g*128 + k4*4 + sub];
            return;
        }
        i -= 294912;
        if (i < 768) { ws[OFF_BIH_W + i] = (i<384) ? b_ih_f[i] : b_ih_b[i-384]; return; }
        i -= 768;
        if (i < 768) { ws[OFF_BIH_S + i] = (i<384) ? sb_ih_f[i] : sb_ih_b[i-384]; return; }
        i -= 768;
        if (i < 768) { ws[OFF_BHH_W + i] = (i<384) ? b_hh_f[i] : b_hh_b[i-384]; return; }
        i -= 768;
        if (i < 768) { ws[OFF_BHH_S + i] = (i<384) ? sb_hh_f[i] : sb_hh_b[i-384]; return; }
        return;
    }
    if (b < 1932) {
        // ---- W_hh frags [dir2][half2][nt24][q4][lane64][elem8] ----
        u16* WFo = (u16*)(ws + OFF_WFHH);
        int i = (b - 1164) * 256 + threadIdx.x;   // < 196608
        int within = i % 49152;
        int combo  = i / 49152;      // dir*2 + half
        int half = combo & 1, dir = combo >> 1;
        int nt  = within / 2048;
        int r2  = within % 2048;
        int q   = r2 >> 9;
        int r3  = r2 & 511;
        int l   = r3 >> 3, e = r3 & 7;
        int n = nt*16 + (l & 15);
        int k = q*32 + ((l >> 4) << 3) + e;
        const float* src = dir ? w_hh_b : w_hh_f;
        float v = src[n*128 + k];
        u16 hi = bf16_hi(v);
        WFo[i] = half ? bf16_hi(v - bf16_f(hi)) : hi;
        return;
    }
    if (b < 3724) {
        // ---- attn (Ww,Ws) + word xp (w_ih) frags ----
        u16* WFW_W = (u16*)(ws + OFF_WFW_W);
        u16* WFW_S = (u16*)(ws + OFF_WFW_S);
        u16* WFX   = (u16*)(ws + OFF_WFX);
        int i = (b - 1932) * 256 + threadIdx.x;   // < 458752
        if (i < 262144) {
            int which = i / 131072;       // 0=Ww, 1=Ws
            int w = i % 131072;
            int half = w / 65536;
            int r = w % 65536;
            int nt = r / 4096;
            int r2 = r % 4096;
            int q = r2 / 512;
            int l = (r2 % 512) >> 3, e = r2 & 7;
            int n = nt*16 + (l & 15);
            int k = q*32 + ((l >> 4) << 3) + e;
            const float* src = which ? Ws : Ww;
            float v = src[n*256 + k];
            u16 hi = bf16_hi(v);
            u16 o = half ? bf16_hi(v - bf16_f(hi)) : hi;
            (which ? WFW_S : WFW_W)[w] = o;
            return;
        }
        i -= 262144;
        if (i < 196608) {
            int w = i % 98304;
            int dir = i / 98304;
            int half = w / 49152;
            int r = w % 49152;
            int nt = r / 2048;
            int r2 = r % 2048;
            int q = r2 / 512;
            int l = (r2 % 512) >> 3, e = r2 & 7;
            int n = nt*16 + (l & 15);
            int k = q*32 + ((l >> 4) << 3) + e;
            const float* src = dir ? w_ih_b : w_ih_f;
            float v = src[n*128 + k];
            u16 hi = bf16_hi(v);
            WFX[i] = half ? bf16_hi(v - bf16_f(hi)) : hi;
            return;
        }
        return;
    }
    {
        // ---- section D: WFIHS = s_ih B-frags [dir2][half2][nt24][q8][l64][e8] ----
        u16* WFIHS = (u16*)(ws + OFF_W6);
        int i = (b - 3724) * 256 + threadIdx.x;   // < 393216
        int dir  = i / 196608;
        int w    = i % 196608;
        int half = w / 98304;
        int r    = w % 98304;
        int nt = r / 4096;
        int r2 = r % 4096;
        int q  = r2 / 512;
        int l  = (r2 % 512) >> 3, e = r2 & 7;
        int n = nt*16 + (l & 15);                 // row in [0,384): gate*128 + j
        int k = q*32 + ((l >> 4) << 3) + e;       // k in [0,256)
        const float* src = dir ? s_ih_b : s_ih_f;
        float v = src[n*256 + k];
        u16 hi = bf16_hi(v);
        WFIHS[i] = half ? bf16_hi(v - bf16_f(hi)) : hi;
    }
}

// ---------------- fused word pipeline: gather + xp-GEMM (LDS) + recurrence ----------
// ROUND-25: STAGING OVERLAP. r21 structure (8-seq, summed-G, float4 staging) with the
// per-chunk staging phase deleted from the serial path:
//  * a_pk un-unioned from G (LDS 137.7 -> ~150 KB, still 1 block/CU — occupancy is
//    insensitive per r19/r20).
//  * chunk c's xp reads a_pk staged during chunk c-1's STEPS by waves 8-11 (which
//    are otherwise idle in every gate window, tid<512 gates). 1 float4 item per
//    stage thread per step (256x8 = 2048 items/chunk). Gather issued at step start
//    (hides under MFMA+G+barrier ~1500cy); split+LDS-store in the gate window.
//    barrier_lds_only doesn't drain vmcnt -> the gather stays in flight across the
//    barrier (counted-vmcnt pattern). Register cost ~+6 VGPR; no spill risk.
//  * chunk 0 staged in the prologue by all threads (as before).
__global__ __launch_bounds__(768)
void gru_word_full(const int* __restrict__ X, const float* __restrict__ emb,
                   const u16* __restrict__ WFX, const u16* __restrict__ WFHH,
                   const float* __restrict__ b_ih_f, const float* __restrict__ b_ih_b,
                   const float* __restrict__ b_hh_f, const float* __restrict__ b_hh_b,
                   u16* __restrict__ houtp)
{
    const int bx = blockIdx.x;
    const int dir = bx >> 7;
    const int blk = bx & 127;
    const int seq0 = blk * 8;
    const int tid = threadIdx.x;
    const int lane = tid & 63;
    const int wid = tid >> 6;            // 0..11

    __shared__ float xp_lds[64 * XPLD];      // 98560 B (rows = s*8 + tt)
    __shared__ u16 a_pk[8 * 4 * 512];        // 32768 B (separate from G since r25)
    __shared__ float G[8 * GLD];             // 12416 B (hi+lo pre-summed)
    __shared__ u16 h_pk[4 * HPLD];           // 4160 B (hi rows 0-7, lo rows 8-15)
    __shared__ int ids_s[8][64];             // 2048 B
    // total ~149.95 KB <= 160 KB

    const int j = tid & 127;
    const int sg = tid >> 7;             // 0..3 gate threads (s = sg, sg+4)
    const bool gthread = tid < 512;
    const float* bih = dir ? b_ih_b : b_ih_f;
    const float* bhh = dir ? b_hh_b : b_hh_f;
    float bhr = 0.f, bhz = 0.f, bhn = 0.f;
    if (gthread) { bhr = bhh[j]; bhz = bhh[128 + j]; bhn = bhh[256 + j]; }

    const u16* WXbase = WFX + (long)dir * 98304;
    const u16* WHbase = WFHH + (long)dir * 98304;
    const int nt0 = wid*2, nt1 = wid*2 + 1;
    const int c0 = nt0*16 + (lane & 15);
    const int c1 = nt1*16 + (lane & 15);
    // gate-thread h_pk write decomposition for k = j
    const int qj = j >> 5, subkj = (j >> 3) & 3, ej = j & 7;

    for (int i = tid; i < 512; i += 768)
        ids_s[i >> 6][i & 63] = X[(long)(seq0 + (i >> 6))*64 + (i & 63)];
    for (int i = tid; i < 4*HPLD; i += 768) h_pk[i] = 0;
    __syncthreads();

    // prologue: stage chunk 0 with all 768 threads (float4 items)
    for (int idx = tid; idx < 2048; idx += 768) {
        int cc2 = idx & 1, rm = (idx >> 1) & 7, subk = (idx >> 4) & 3;
        int q = (idx >> 6) & 3, mfs = idx >> 8;
        int t = dir ? 63 - rm : rm;          // ts = 0*8 + rm
        int kk = q*32 + subk*8 + cc2*4;
        int id = ids_s[mfs][t];
        float4 v = make_float4(0.f, 0.f, 0.f, 0.f);
        if (id != 0) v = *(const float4*)&emb[(long)id*128 + kk];
        u16 h0,l0,h1,l1,h2,l2,h3,l3;
        bf16_split(v.x,h0,l0); bf16_split(v.y,h1,l1);
        bf16_split(v.z,h2,l2); bf16_split(v.w,h3,l3);
        int lh = subk*16 + rm;
        int base = (mfs*4 + q)*512 + lh*8 + cc2*4;
        uint2 whi = make_uint2((u32)h0 | ((u32)h1 << 16), (u32)h2 | ((u32)h3 << 16));
        uint2 wlo = make_uint2((u32)l0 | ((u32)l1 << 16), (u32)l2 | ((u32)l3 << 16));
        *(uint2*)&a_pk[base]      = whi;
        *(uint2*)&a_pk[base + 64] = wlo;
    }
    __syncthreads();

    float hprev0 = 0.f, hprev1 = 0.f;
    for (int c = 0; c < 8; ++c) {
        asm volatile("" ::: "memory");   // no cross-chunk hoisting of weight loads
        // ---- load W_ih frags (this chunk only) ----
        sh8 xh0[4], xl0[4], xh1[4], xl1[4];
#pragma unroll
        for (int q = 0; q < 4; ++q) {
            xh0[q] = *(const sh8*)(WXbase + (nt0*4 + q)*512 + lane*8);
            xl0[q] = *(const sh8*)(WXbase + 49152 + (nt0*4 + q)*512 + lane*8);
            xh1[q] = *(const sh8*)(WXbase + (nt1*4 + q)*512 + lane*8);
            xl1[q] = *(const sh8*)(WXbase + 49152 + (nt1*4 + q)*512 + lane*8);
        }
        const float bv0 = bih[c0], bv1 = bih[c1];
        // ---- xp MFMA (reads a_pk staged during chunk c-1's steps / prologue) ----
#pragma unroll
        for (int mf = 0; mf < 8; ++mf) {
            f32x4 A0 = (f32x4){0.f,0.f,0.f,0.f};
            f32x4 A1 = (f32x4){0.f,0.f,0.f,0.f};
#pragma unroll
            for (int q = 0; q < 4; ++q) {
                sh8 a = *(const sh8*)&a_pk[(mf*4 + q)*512 + lane*8];
                A0 = __builtin_amdgcn_mfma_f32_16x16x32_bf16(a, xh0[q], A0, 0,0,0);
                A0 = __builtin_amdgcn_mfma_f32_16x16x32_bf16(a, xl0[q], A0, 0,0,0);
                A1 = __builtin_amdgcn_mfma_f32_16x16x32_bf16(a, xh1[q], A1, 0,0,0);
                A1 = __builtin_amdgcn_mfma_f32_16x16x32_bf16(a, xl1[q], A1, 0,0,0);
            }
            float g0[4], g1[4];
#pragma unroll
            for (int r = 0; r < 4; ++r) {
                g0[r] = A0[r] + __shfl_xor(A0[r], 32);
                g1[r] = A1[r] + __shfl_xor(A1[r], 32);
            }
            if ((lane >= 32) == (mf & 1)) {
                int row = mf*8 + ((lane >> 4) & 1)*4;
#pragma unroll
                for (int r = 0; r < 4; ++r) {
                    xp_lds[(row+r)*XPLD + c0] = g0[r] + bv0;
                    xp_lds[(row+r)*XPLD + c1] = g1[r] + bv1;
                }
            }
        }
        barrier_lds_only();   // xp written; a_pk free for chunk c+1 restage
        asm volatile("" ::: "memory");
        // ---- load W_hh frags ----
        sh8 wh0[4], wl0[4], wh1[4], wl1[4];
#pragma unroll
        for (int q = 0; q < 4; ++q) {
            wh0[q] = *(const sh8*)(WHbase + (nt0*4 + q)*512 + lane*8);
            wl0[q] = *(const sh8*)(WHbase + 49152 + (nt0*4 + q)*512 + lane*8);
            wh1[q] = *(const sh8*)(WHbase + (nt1*4 + q)*512 + lane*8);
            wl1[q] = *(const sh8*)(WHbase + 49152 + (nt1*4 + q)*512 + lane*8);
        }
        // ---- 8 recurrence steps (+ chunk c+1 staging by waves 8-11) ----
        for (int tt = 0; tt < 8; ++tt) {
            const int ts = c*8 + tt;
            const int t = dir ? 63 - ts : ts;
            // stage-wave prefetch: issue the gather NOW; consume in the gate window
            float4 sv;
            int s_base = 0;
            const bool sv_ok = !gthread && (c < 7);
            if (sv_ok) {
                const int st = tid - 512;            // 0..255
                const int idx = tt*256 + st;         // mfs = tt, rest from st
                int cc2 = idx & 1, rm = (idx >> 1) & 7, subk = (idx >> 4) & 3;
                int q = (idx >> 6) & 3, mfs = idx >> 8;
                int ts2 = (c+1)*8 + rm;
                int t2 = dir ? 63 - ts2 : ts2;
                int kk = q*32 + subk*8 + cc2*4;
                int id = ids_s[mfs][t2];
                sv = make_float4(0.f, 0.f, 0.f, 0.f);
                if (id != 0) sv = *(const float4*)&emb[(long)id*128 + kk];
                int lh = subk*16 + rm;
                s_base = (mfs*4 + q)*512 + lh*8 + cc2*4;
            }
            f32x4 acc0 = (f32x4){0.f,0.f,0.f,0.f};
            f32x4 acc1 = (f32x4){0.f,0.f,0.f,0.f};
#pragma unroll
            for (int q = 0; q < 4; ++q) {
                sh8 hp = *(const sh8*)&h_pk[q*HPLD + lane*8];
                acc0 = __builtin_amdgcn_mfma_f32_16x16x32_bf16(hp, wh0[q], acc0, 0,0,0);
                acc0 = __builtin_amdgcn_mfma_f32_16x16x32_bf16(hp, wl0[q], acc0, 0,0,0);
                acc1 = __builtin_amdgcn_mfma_f32_16x16x32_bf16(hp, wh1[q], acc1, 0,0,0);
                acc1 = __builtin_amdgcn_mfma_f32_16x16x32_bf16(hp, wl1[q], acc1, 0,0,0);
            }
            // summed-G: hi row s (lanes 0-31) + lo row s+8 (lanes 32-63) share a reg
            {
                float sg0[4], sg1[4];
#pragma unroll
                for (int r = 0; r < 4; ++r) {
                    sg0[r] = acc0[r] + __shfl_xor(acc0[r], 32);
                    sg1[r] = acc1[r] + __shfl_xor(acc1[r], 32);
                }
                if (lane < 32) {
                    const int col16 = lane & 15;
                    const int row0  = (lane >> 4) << 2;   // 0 or 4
#pragma unroll
                    for (int r = 0; r < 4; ++r) {
                        G[(row0+r)*GLD + nt0*16 + col16] = sg0[r];
                        G[(row0+r)*GLD + nt1*16 + col16] = sg1[r];
                    }
                }
            }
            barrier_lds_only();
            if (gthread) {
#pragma unroll
                for (int si = 0; si < 2; ++si) {
                    const int s = sg + si*4;
                    float gr  = G[s*GLD + j]       + bhr;
                    float gz  = G[s*GLD + 128 + j] + bhz;
                    float gnh = G[s*GLD + 256 + j] + bhn;
                    const float* xrow = &xp_lds[(s*8 + tt)*XPLD];
                    float r  = sigmoidf_(xrow[j] + gr);
                    float z  = sigmoidf_(xrow[128 + j] + gz);
                    float nv = tanhf_(xrow[256 + j] + r * gnh);
                    float hold = si ? hprev1 : hprev0;
                    float hnew = (1.f - z) * nv + z * hold;
                    if (si) hprev1 = hnew; else hprev0 = hnew;
                    u16 hh, hl; bf16_split(hnew, hh, hl);
                    // paired u32 writes: even j handles the hi row pair, odd j the lo
                    u16 ohh = (u16)__shfl_xor((int)hh, 1);
                    u16 ohl = (u16)__shfl_xor((int)hl, 1);
                    const long tbase = ((long)(seq0 + s)*64 + t)*512 + dir*128;
                    if ((j & 1) == 0) {
                        u32 w = (u32)hh | ((u32)ohh << 16);
                        *(u32*)&h_pk[qj*HPLD + (subkj*16 + s)*8 + ej] = w;
                        *(u32*)&houtp[tbase + j] = w;
                    } else {
                        u32 w = (u32)ohl | ((u32)hl << 16);
                        *(u32*)&h_pk[qj*HPLD + (subkj*16 + s + 8)*8 + (ej - 1)] = w;
                        *(u32*)&houtp[tbase + 256 + (j - 1)] = w;
                    }
                }
            } else if (sv_ok) {
                // stage-wave gate window: split the in-flight gather, store to a_pk
                u16 h0,l0,h1,l1,h2,l2,h3,l3;
                bf16_split(sv.x,h0,l0); bf16_split(sv.y,h1,l1);
                bf16_split(sv.z,h2,l2); bf16_split(sv.w,h3,l3);
                uint2 whi = make_uint2((u32)h0 | ((u32)h1 << 16), (u32)h2 | ((u32)h3 << 16));
                uint2 wlo = make_uint2((u32)l0 | ((u32)l1 << 16), (u32)l2 | ((u32)l3 << 16));
                *(uint2*)&a_pk[s_base]      = whi;
                *(uint2*)&a_pk[s_base + 64] = wlo;
            }
            barrier_lds_only();
        }
    }
}

// ---------------- fused attention: score MFMA + tanh/ctx + softmax + pool ----------
// PACKED=true: A = hout u16 [sent][t][hilo][k256]; staged via uint4 decode-permute.
// PACKED=false: A is fp32 [M][256], staged with bf16 split (sentence level).
// CLS=true: fused classifier (r23).
template<int T, bool PACKED, bool CLS>
__global__ __launch_bounds__(1024)
void attn_fused(const float* __restrict__ A, const u16* __restrict__ WF,
                const float* __restrict__ bias, const float* __restrict__ ctx,
                float* __restrict__ outp,
                const float* __restrict__ Wc, const float* __restrict__ bc)
{
    __shared__ u16 a_pk[8][8][512];    // 64 KB
    __shared__ float pscore[8][8][17];
    __shared__ float aw[64];
    __shared__ float red[4][256];
    __shared__ float docv[2][256];     // CLS only (2 KB)
    const int tid = threadIdx.x;
    const int lane = tid & 63;
    const int wid = tid >> 6;   // 0..15
    const int m0 = blockIdx.x * 64;

    sh8 bh[8], bl[8];
#pragma unroll
    for (int q = 0; q < 8; ++q) {
        bh[q] = *(const sh8*)(WF + (wid*8 + q)*512 + lane*8);
        bl[q] = *(const sh8*)(WF + 65536 + (wid*8 + q)*512 + lane*8);
    }
    const int colg = wid*16 + (lane & 15);
    const float bwv = bias[colg];
    const float cxv = ctx[colg];

    if (PACKED) {
        // uint4 staging — src (k>>1 over c2) and dst (idx) both contiguous
        const u32* src32 = (const u32*)A + (long)blockIdx.x * 16384;
        u32* dst = (u32*)a_pk;
        for (int idx4 = tid; idx4 < 4096; idx4 += 1024) {
            int idx = idx4 << 2;
            int mf = idx >> 11, q = (idx >> 8) & 7, l = (idx >> 2) & 63;
            int row16 = l & 15, hilo = row16 >> 3, rm = row16 & 7;
            int t = mf*8 + rm;
            int kb2 = q*16 + (l >> 4)*4;       // (kbase>>1), multiple of 4
            *(uint4*)&dst[idx] = *(const uint4*)&src32[(t*2 + hilo)*128 + kb2];
        }
    } else {
        for (int idx = tid; idx < 8192; idx += 1024) {
            int row = idx >> 7;            // 0..63
            int k   = (idx & 127) << 1;
            float2 v = *(const float2*)&A[(long)(m0 + row)*256 + k];
            u16 h0,l0,h1,l1; bf16_split(v.x,h0,l0); bf16_split(v.y,h1,l1);
            int mf = row >> 3, rm = row & 7;
            int q = k >> 5;
            int lh = (((k & 31) >> 3) << 4) | rm;
            int e = k & 7;
            *(u32*)&a_pk[mf][q][lh*8 + e]     = (u32)h0 | ((u32)h1 << 16);
            *(u32*)&a_pk[mf][q][(lh+8)*8 + e] = (u32)l0 | ((u32)l1 << 16);
        }
    }
    __syncthreads();

#pragma unroll
    for (int mf = 0; mf < 8; ++mf) {
        f32x4 acc = (f32x4){0.f,0.f,0.f,0.f};
#pragma unroll
        for (int q = 0; q < 8; ++q) {
            sh8 a = *(const sh8*)&a_pk[mf][q][lane*8];
            acc = __builtin_amdgcn_mfma_f32_16x16x32_bf16(a, bh[q], acc, 0,0,0);
            acc = __builtin_amdgcn_mfma_f32_16x16x32_bf16(a, bl[q], acc, 0,0,0);
        }
        float g[4];
#pragma unroll
        for (int r = 0; r < 4; ++r) g[r] = acc[r] + __shfl_xor(acc[r], 32);
        if ((lane >= 32) == (mf & 1)) {    // half-dedup: each half handles 4 mf
            float p[4];
#pragma unroll
            for (int r = 0; r < 4; ++r) p[r] = tanhf_(g[r] + bwv) * cxv;
#pragma unroll
            for (int r = 0; r < 4; ++r) {
                p[r] += __shfl_xor(p[r], 1);
                p[r] += __shfl_xor(p[r], 2);
                p[r] += __shfl_xor(p[r], 4);
                p[r] += __shfl_xor(p[r], 8);
            }
            if ((lane & 15) == 0) {
#pragma unroll
                for (int r = 0; r < 4; ++r)
                    pscore[mf][((lane >> 4) & 1)*4 + r][wid] = p[r];
            }
        }
    }
    __syncthreads();

    // softmax over T (per sentence group) in wave 0
    if (tid < 64) {
        float sc = 0.f;
#pragma unroll
        for (int w = 0; w < 16; ++w) sc += pscore[tid >> 3][tid & 7][w];
        float mx = sc;
#pragma unroll
        for (int m = 1; m < T; m <<= 1) mx = fmaxf(mx, __shfl_xor(mx, m));
        float e = __expf(sc - mx);
        float den = e;
#pragma unroll
        for (int m = 1; m < T; m <<= 1) den += __shfl_xor(den, m);
        aw[tid] = __fdividef(e, den);
    }
    __syncthreads();

    // weighted sum: h reconstructed from a_pk (hi+lo); thread -> (d-pair, t-group)
    if (tid < 512) {
        const int dp = (tid & 127) << 1;
        const int tg = tid >> 7;          // 0..3
        const int q = dp >> 5, lhb = ((dp & 31) >> 3) << 4, e = dp & 7;
        float acc0 = 0.f, acc1 = 0.f;
#pragma unroll
        for (int i = 0; i < 16; ++i) {
            int t = tg*16 + i;
            int mf = t >> 3, rm = t & 7;
            const u16* base = &a_pk[mf][q][(lhb | rm)*8 + e];
            u32 hh = *(const u32*)base;
            u32 ll = *(const u32*)(base + 64);
            float h0 = bf16_f((u16)hh) + bf16_f((u16)ll);
            float h1 = bf16_f((u16)(hh >> 16)) + bf16_f((u16)(ll >> 16));
            float w = aw[t];
            acc0 = fmaf(w, h0, acc0);
            acc1 = fmaf(w, h1, acc1);
        }
        red[tg][dp] = acc0; red[tg][dp + 1] = acc1;
    }
    __syncthreads();
    if (T == 64) {
        if (tid < 256)
            outp[(long)blockIdx.x*256 + tid] = red[0][tid] + red[1][tid] + red[2][tid] + red[3][tid];
    } else if (!CLS) {
        if (tid < 512) {
            int sent = tid >> 8, dd = tid & 255;
            outp[((long)blockIdx.x*2 + sent)*256 + dd] = red[sent*2][dd] + red[sent*2 + 1][dd];
        }
    } else {
        // classifier fusion: docv -> logits, write final output directly
        if (tid < 512) {
            int sent = tid >> 8, dd = tid & 255;
            docv[sent][dd] = red[sent*2][dd] + red[sent*2 + 1][dd];
        }
        __syncthreads();
        if (tid < 20) {
            int s = tid / 10, c = tid % 10;
            float acc = bc[c];
            const float4* wp = (const float4*)&Wc[c*256];
            const float4* dv = (const float4*)&docv[s][0];
#pragma unroll 8
            for (int d = 0; d < 64; ++d) {
                float4 a = dv[d], w = wp[d];
                acc = fmaf(a.x, w.x, fmaf(a.y, w.y, fmaf(a.z, w.z, fmaf(a.w, w.w, acc))));
            }
            outp[(blockIdx.x*2 + s)*10 + c] = acc;
        }
    }
}

// ---------------- sentence pipeline: xp MFMA + GRU recurrence (r24) ----------------
// Block = (dir, doc): 64 blocks, 512 threads (8 waves).
__global__ __launch_bounds__(512)
void gru_sent(const float* __restrict__ sents, const u16* __restrict__ WFIHS,
              const float* __restrict__ bih_s, const float4* __restrict__ whh4,
              const float* __restrict__ bhh, float* __restrict__ hout)
{
    const int bx = blockIdx.x;
    const int dir = bx >> 5;
    const int doc = bx & 31;
    const int tid = threadIdx.x;
    const int lane = tid & 63;
    const int wid = tid >> 6;            // 0..7

    __shared__ float xp_lds[32 * XPLD];  // 49280 B
    __shared__ u16 a_pk[4 * 8 * 512];    // 32768 B: [mf4][q8][l64][e8]
    __shared__ float h_lds[128];

    for (int i = tid; i < 128; i += 512) h_lds[i] = 0.f;

    // ---- phase 1: stage sents rows -> A-frags ----
    for (int idx = tid; idx < 2048; idx += 512) {
        int cc2 = idx & 1, rm = (idx >> 1) & 7, subk = (idx >> 4) & 3;
        int q = (idx >> 6) & 7, mf = (idx >> 9) & 3;
        int t = mf*8 + rm;
        int kk = q*32 + subk*8 + cc2*4;
        float4 v = *(const float4*)&sents[(long)(doc*32 + t)*256 + kk];
        u16 h0,l0,h1,l1,h2,l2,h3,l3;
        bf16_split(v.x,h0,l0); bf16_split(v.y,h1,l1);
        bf16_split(v.z,h2,l2); bf16_split(v.w,h3,l3);
        int lh = subk*16 + rm;
        int base = (mf*8 + q)*512 + lh*8 + cc2*4;
        uint2 whi = make_uint2((u32)h0 | ((u32)h1 << 16), (u32)h2 | ((u32)h3 << 16));
        uint2 wlo = make_uint2((u32)l0 | ((u32)l1 << 16), (u32)l2 | ((u32)l3 << 16));
        *(uint2*)&a_pk[base]      = whi;
        *(uint2*)&a_pk[base + 64] = wlo;
    }
    barrier_lds_only();

    // ---- phase 2: xp MFMA, wave w -> nt {w, w+8, w+16} ----
    const u16* WFbase = WFIHS + (long)dir * 196608;
#pragma unroll 1
    for (int ni = 0; ni < 3; ++ni) {
        const int nt = wid + ni*8;
        sh8 wh[8], wl[8];
#pragma unroll
        for (int q = 0; q < 8; ++q) {
            wh[q] = *(const sh8*)(WFbase + (nt*8 + q)*512 + lane*8);
            wl[q] = *(const sh8*)(WFbase + 98304 + (nt*8 + q)*512 + lane*8);
        }
        const int col16 = lane & 15;
        const float bv = bih_s[dir*384 + nt*16 + col16];
        f32x4 A0 = (f32x4){0.f,0.f,0.f,0.f};
        f32x4 A1 = (f32x4){0.f,0.f,0.f,0.f};
        f32x4 A2 = (f32x4){0.f,0.f,0.f,0.f};
        f32x4 A3 = (f32x4){0.f,0.f,0.f,0.f};
#pragma unroll
        for (int q = 0; q < 8; ++q) {
            sh8 a0 = *(const sh8*)&a_pk[(0*8 + q)*512 + lane*8];
            sh8 a1 = *(const sh8*)&a_pk[(1*8 + q)*512 + lane*8];
            sh8 a2 = *(const sh8*)&a_pk[(2*8 + q)*512 + lane*8];
            sh8 a3 = *(const sh8*)&a_pk[(3*8 + q)*512 + lane*8];
            A0 = __builtin_amdgcn_mfma_f32_16x16x32_bf16(a0, wh[q], A0, 0,0,0);
            A0 = __builtin_amdgcn_mfma_f32_16x16x32_bf16(a0, wl[q], A0, 0,0,0);
            A1 = __builtin_amdgcn_mfma_f32_16x16x32_bf16(a1, wh[q], A1, 0,0,0);
            A1 = __builtin_amdgcn_mfma_f32_16x16x32_bf16(a1, wl[q], A1, 0,0,0);
            A2 = __builtin_amdgcn_mfma_f32_16x16x32_bf16(a2, wh[q], A2, 0,0,0);
            A2 = __builtin_amdgcn_mfma_f32_16x16x32_bf16(a2, wl[q], A2, 0,0,0);
            A3 = __builtin_amdgcn_mfma_f32_16x16x32_bf16(a3, wh[q], A3, 0,0,0);
            A3 = __builtin_amdgcn_mfma_f32_16x16x32_bf16(a3, wl[q], A3, 0,0,0);
        }
#pragma unroll
        for (int mf = 0; mf < 4; ++mf) {
            f32x4 A = (mf==0) ? A0 : (mf==1) ? A1 : (mf==2) ? A2 : A3;
            float g[4];
#pragma unroll
            for (int r = 0; r < 4; ++r) g[r] = A[r] + __shfl_xor(A[r], 32);
            if ((lane >= 32) == (mf & 1)) {
                int row = mf*8 + ((lane >> 4) & 1)*4;
#pragma unroll
                for (int r = 0; r < 4; ++r)
                    xp_lds[(row+r)*XPLD + nt*16 + col16] = g[r] + bv;
            }
        }
    }
    barrier_lds_only();
    asm volatile("" ::: "memory");   // keep recurrence weight loads below xp phase

    // ---- phase 3: recurrence (hoisted weights; xp from LDS) ----
    const int kq = tid & 3;
    const int j  = tid >> 2;
    const float4* W = whh4 + (long)dir * 12288;
    const float bhr = bhh[dir*384 + j];
    const float bhz = bhh[dir*384 + 128 + j];
    const float bhn = bhh[dir*384 + 256 + j];
    float4 w0r[8], w1r[8], w2r[8];
#pragma unroll
    for (int ii = 0; ii < 8; ++ii) {
        const int k4 = kq + (ii << 2);
        w0r[ii] = W[k4*384 + j];
        w1r[ii] = W[k4*384 + 128 + j];
        w2r[ii] = W[k4*384 + 256 + j];
    }

    for (int ts = 0; ts < 32; ++ts) {
        const int t = dir ? (31 - ts) : ts;
        float a0 = 0.f, a1 = 0.f, a2 = 0.f;
#pragma unroll
        for (int ii = 0; ii < 8; ++ii) {
            const int k4 = kq + (ii << 2);
            float4 w0 = w0r[ii];
            float4 w1 = w1r[ii];
            float4 w2 = w2r[ii];
            float4 h4 = *(const float4*)&h_lds[k4 << 2];
            a0 = fmaf(w0.x,h4.x, fmaf(w0.y,h4.y, fmaf(w0.z,h4.z, fmaf(w0.w,h4.w, a0))));
            a1 = fmaf(w1.x,h4.x, fmaf(w1.y,h4.y, fmaf(w1.z,h4.z, fmaf(w1.w,h4.w, a1))));
            a2 = fmaf(w2.x,h4.x, fmaf(w2.y,h4.y, fmaf(w2.z,h4.z, fmaf(w2.w,h4.w, a2))));
        }
        a0 += __shfl_xor(a0, 1); a0 += __shfl_xor(a0, 2);
        a1 += __shfl_xor(a1, 1); a1 += __shfl_xor(a1, 2);
        a2 += __shfl_xor(a2, 1); a2 += __shfl_xor(a2, 2);
        __syncthreads();
        if (kq == 0) {
            const float* xr = &xp_lds[t*XPLD];
            float r = sigmoidf_(xr[j]       + a0 + bhr);
            float z = sigmoidf_(xr[128 + j] + a1 + bhz);
            float nv = tanhf_(xr[256 + j] + r * (a2 + bhn));
            float hold = h_lds[j];
            float hnew = (1.f - z) * nv + z * hold;
            h_lds[j] = hnew;
            hout[((long)(doc*32 + t))*256 + dir*128 + j] = hnew;
        }
        __syncthreads();
    }
}

extern "C" void kernel_launch(void* const* d_in, const int* in_sizes, int n_in,
                              void* d_out, int out_size, void* d_ws, size_t ws_size,
                              hipStream_t stream) {
    const int*   X       = (const int*)  d_in[0];
    const float* emb     = (const float*)d_in[1];
    const float* w_ih_f  = (const float*)d_in[2];
    const float* w_hh_f  = (const float*)d_in[3];
    const float* b_ih_f  = (const float*)d_in[4];
    const float* b_hh_f  = (const float*)d_in[5];
    const float* w_ih_b  = (const float*)d_in[6];
    const float* w_hh_b  = (const float*)d_in[7];
    const float* b_ih_b  = (const float*)d_in[8];
    const float* b_hh_b  = (const float*)d_in[9];
    const float* Ww      = (const float*)d_in[10];
    const float* bw      = (const float*)d_in[11];
    const float* ctx_w   = (const float*)d_in[12];
    const float* s_ih_f  = (const float*)d_in[13];
    const float* s_hh_f  = (const float*)d_in[14];
    const float* sb_ih_f = (const float*)d_in[15];
    const float* sb_hh_f = (const float*)d_in[16];
    const float* s_ih_b  = (const float*)d_in[17];
    const float* s_hh_b  = (const float*)d_in[18];
    const float* sb_ih_b = (const float*)d_in[19];
    const float* sb_hh_b = (const float*)d_in[20];
    const float* Ws      = (const float*)d_in[21];
    const float* bs      = (const float*)d_in[22];
    const float* ctx_s   = (const float*)d_in[23];
    const float* Wc      = (const float*)d_in[24];
    const float* bc      = (const float*)d_in[25];
    float* ws  = (float*)d_ws;
    float* out = (float*)d_out;

    if (ws_size < (size_t)WS_FLOATS * 4) return;   // fail cleanly if scratch too small

    // 1. weight prep
    prep_all<<<5260, 256, 0, stream>>>(s_ih_f, s_ih_b, w_ih_f, w_ih_b,
                                       w_hh_f, w_hh_b, s_hh_f, s_hh_b,
                                       b_ih_f, b_ih_b, sb_ih_f, sb_ih_b,
                                       b_hh_f, b_hh_b, sb_hh_f, sb_hh_b,
                                       Ww, Ws, ws);

    // 2. fused word pipeline (r25: staging overlapped with recurrence steps)
    gru_word_full<<<256, 768, 0, stream>>>(
        X, emb, (const u16*)(ws + OFF_WFX), (const u16*)(ws + OFF_WFHH),
        b_ih_f, b_ih_b, b_hh_f, b_hh_b, (u16*)(ws + OFF_HW));

    // 3. fused word attention -> sents
    attn_fused<64, true, false><<<1024, 1024, 0, stream>>>(
        ws + OFF_HW, (const u16*)(ws + OFF_WFW_W), bw, ctx_w, ws + OFF_SENTS,
        nullptr, nullptr);

    // 4. sentence pipeline: xp MFMA + GRU fused
    gru_sent<<<64, 512, 0, stream>>>(
        ws + OFF_SENTS, (const u16*)(ws + OFF_W6), ws + OFF_BIH_S,
        (const float4*)(ws + OFF_W6) + 4*12288, ws + OFF_BHH_S, ws + OFF_HS);

    // 5. fused sentence attention + classifier -> logits
    attn_fused<32, false, true><<<16, 1024, 0, stream>>>(
        ws + OFF_HS, (const u16*)(ws + OFF_WFW_S), bs, ctx_s, out, Wc, bc);
}